// Round 4
// baseline (1149.299 us; speedup 1.0000x reference)
//
#include <hip/hip_runtime.h>
#include <hip/hip_bf16.h>

typedef __attribute__((ext_vector_type(8))) short short8;
typedef __attribute__((ext_vector_type(4))) float f32x4;
typedef __attribute__((ext_vector_type(4))) unsigned int u32x4;
typedef unsigned short u16;
typedef unsigned int u32;

#define NODES 16384
#define CHN 128
#define NEDGE 524288
#define NG 16
#define NPGC 1024
#define NHEAD 4
#define HDIM 32
#define NLAYER 4
#define NSPLIT 2   // KV halves in attention

#if __has_builtin(__builtin_amdgcn_exp2f)
#define EXP2(x) __builtin_amdgcn_exp2f(x)
#else
#define EXP2(x) exp2f(x)
#endif

__device__ __forceinline__ float bf2f(u16 u) {
    union { u32 u; float f; } c; c.u = ((u32)u) << 16; return c.f;
}
__device__ __forceinline__ u16 f2bf(float f) {
    union { float f; u32 u; } c; c.f = f;
    u32 r = c.u + 0x7fffu + ((c.u >> 16) & 1u);
    return (u16)(r >> 16);
}
__device__ __forceinline__ void fsplit(float f, u16& hi, u16& lo) {
    u16 h = f2bf(f);
    hi = h;
    lo = f2bf(f - bf2f(h));
}
// packs bf16(a) into low 16, bf16(b) into high 16
__device__ __forceinline__ u32 cvtpk_bf16(float a, float b) {
    u32 r;
    asm("v_cvt_pk_bf16_f32 %0, %1, %2" : "=v"(r) : "v"(a), "v"(b));
    return r;
}

#define MFMA16(a, b, c) __builtin_amdgcn_mfma_f32_16x16x32_bf16((a), (b), (c), 0, 0, 0)

__device__ __forceinline__ short8 ld_frag(const u16* p) {
    return *reinterpret_cast<const short8*>(p);
}

// ---------------- setup kernels ----------------

struct SplitJobs {
    const float* src[8];
    u16* hi[8];
    u16* lo[8];
    int blk_end[8];   // cumulative block counts (each job n % 256 == 0)
};

__global__ void k_split8(SplitJobs jobs) {
    int b = blockIdx.x;
    int seg = 0;
    while (b >= jobs.blk_end[seg]) ++seg;
    int base = seg ? jobs.blk_end[seg - 1] : 0;
    int i = (b - base) * 256 + threadIdx.x;
    u16 h, l;
    fsplit(jobs.src[seg][i], h, l);
    jobs.hi[seg][i] = h;
    jobs.lo[seg][i] = l;
}

__global__ void k_bnprep(const float* __restrict__ g, const float* __restrict__ b,
                         const float* __restrict__ m, const float* __restrict__ v,
                         float* __restrict__ scale, float* __restrict__ shift) {
    int i = blockIdx.x * 256 + threadIdx.x;
    if (i < NLAYER * 3 * CHN) {
        float s = g[i] * rsqrtf(v[i] + 1e-5f);
        scale[i] = s;
        shift[i] = b[i] - m[i] * s;
    }
}

__global__ void k_zero_u32(u32* __restrict__ p, int n) {
    int i = blockIdx.x * 256 + threadIdx.x;
    if (i < n) p[i] = 0u;
}

__global__ void k_count(const int* __restrict__ dst, u32* __restrict__ counts) {
    int e = blockIdx.x * 256 + threadIdx.x;
    if (e < NEDGE) atomicAdd(&counts[dst[e]], 1u);
}

// single block, 256 threads, 64 elems each
__global__ void k_scan(const u32* __restrict__ counts, u32* __restrict__ offsets,
                       u32* __restrict__ cursor) {
    __shared__ u32 part[256];
    int t = threadIdx.x;
    int base = t * 64;
    u32 s = 0;
    for (int i = 0; i < 64; ++i) s += counts[base + i];
    part[t] = s;
    __syncthreads();
    for (int off = 1; off < 256; off <<= 1) {
        u32 val = (t >= off) ? part[t - off] : 0u;
        __syncthreads();
        part[t] += val;
        __syncthreads();
    }
    u32 run = (t == 0) ? 0u : part[t - 1];
    for (int i = 0; i < 64; ++i) {
        offsets[base + i] = run;
        cursor[base + i] = run;
        run += counts[base + i];
    }
    if (t == 255) offsets[NODES] = run;
}

__global__ void k_fill(const int* __restrict__ src, const int* __restrict__ dst,
                       const float* __restrict__ eattr, u32* __restrict__ cursor,
                       int* __restrict__ csr_src, float* __restrict__ csr_a) {
    int e = blockIdx.x * 256 + threadIdx.x;
    if (e >= NEDGE) return;
    int d = dst[e];
    u32 p = atomicAdd(&cursor[d], 1u);
    csr_src[p] = src[e];
    csr_a[p] = eattr[e];
}

// ------ GINE aggregation: z1 = h + sum_in relu(h[src] + a*ew + eb), bf16 gather ------

__global__ __launch_bounds__(64) void k_agg(
    const u16* __restrict__ h_hi, const float* __restrict__ h_f32,
    const u32* __restrict__ offsets, const int* __restrict__ csr_src,
    const float* __restrict__ csr_a, const float* __restrict__ ew,
    const float* __restrict__ eb, u16* __restrict__ z_hi, u16* __restrict__ z_lo) {
    int node = blockIdx.x;
    int t = threadIdx.x;          // 64 threads, 2 channels each
    int c0 = t * 2;
    float w0 = ew[c0], w1 = ew[c0 + 1];
    float b0 = eb[c0], b1 = eb[c0 + 1];
    u32 beg = offsets[node], end = offsets[node + 1];
    float acc0 = 0.f, acc1 = 0.f;
    for (u32 j = beg; j < end; ++j) {
        int s = csr_src[j];
        float a = csr_a[j];
        u32 u = *reinterpret_cast<const u32*>(h_hi + (size_t)s * CHN + c0);
        float f0 = bf2f((u16)(u & 0xffffu));
        float f1 = bf2f((u16)(u >> 16));
        acc0 += fmaxf(f0 + a * w0 + b0, 0.f);
        acc1 += fmaxf(f1 + a * w1 + b1, 0.f);
    }
    size_t idx = (size_t)node * CHN + c0;
    float z0 = h_f32[idx] + acc0;
    float z1v = h_f32[idx + 1] + acc1;
    u16 h, l;
    fsplit(z0, h, l); z_hi[idx] = h; z_lo[idx] = l;
    fsplit(z1v, h, l); z_hi[idx + 1] = h; z_lo[idx + 1] = l;
}

// ------ split GEMM (16x32 wave tile): acc=(Ah+Al)@(Wh+Wl)^T; epi chain ------

__global__ __launch_bounds__(256) void k_gemm(
    const u16* __restrict__ Ahi, const u16* __restrict__ Alo,
    const u16* __restrict__ Whi, const u16* __restrict__ Wlo,
    const float* __restrict__ bias, const float* __restrict__ resid1,
    const float* __restrict__ bnscale, const float* __restrict__ bnshift,
    const float* __restrict__ resid2, float* __restrict__ out_f32,
    u16* __restrict__ out_hi, u16* __restrict__ out_lo, int K, int Nc, int relu) {
    int tid = threadIdx.x;
    int wave = tid >> 6, lane = tid & 63;
    int lr = lane & 15, lg = lane >> 4;
    int r0 = blockIdx.x * 64 + wave * 16;
    int nb = blockIdx.y * 32;
    f32x4 acc[2] = {};
    size_t arow = (size_t)(r0 + lr) * K + lg * 8;
    for (int ks = 0; ks < K; ks += 32) {
        short8 ah = ld_frag(Ahi + arow + ks);
        short8 al = ld_frag(Alo + arow + ks);
#pragma unroll
        for (int n = 0; n < 2; ++n) {
            size_t wrow = (size_t)(nb + n * 16 + lr) * K + ks + lg * 8;
            short8 wh = ld_frag(Whi + wrow);
            short8 wl = ld_frag(Wlo + wrow);
            acc[n] = MFMA16(ah, wh, acc[n]);
            acc[n] = MFMA16(al, wh, acc[n]);
            acc[n] = MFMA16(ah, wl, acc[n]);
        }
    }
#pragma unroll
    for (int n = 0; n < 2; ++n) {
        int col = nb + n * 16 + lr;
        float bs = bias ? bias[col] : 0.f;
        float sc = bnscale ? bnscale[col] : 1.f;
        float sh = bnshift ? bnshift[col] : 0.f;
#pragma unroll
        for (int r = 0; r < 4; ++r) {
            int row = r0 + lg * 4 + r;
            size_t oidx = (size_t)row * Nc + col;
            float v = acc[n][r] + bs;
            if (resid1) v += resid1[oidx];
            v = v * sc + sh;
            if (resid2) v += resid2[oidx];
            if (relu) v = fmaxf(v, 0.f);
            if (out_f32) out_f32[oidx] = v;
            if (out_hi) {
                u16 hh, ll;
                fsplit(v, hh, ll);
                out_hi[oidx] = hh; out_lo[oidx] = ll;
            }
        }
    }
}

// -------- QKV GEMM with head-split hi/lo store (V transposed, hi-only, pi-permuted) --------

__global__ __launch_bounds__(256) void k_qkv(
    const u16* __restrict__ Ahi, const u16* __restrict__ Alo,
    const u16* __restrict__ Whi, const u16* __restrict__ Wlo,
    const float* __restrict__ bias,
    u16* __restrict__ q_hi, u16* __restrict__ q_lo,
    u16* __restrict__ k_hi, u16* __restrict__ k_lo,
    u16* __restrict__ vt_hi) {
    const int K = 128;
    int tid = threadIdx.x;
    int wave = tid >> 6, lane = tid & 63;
    int lr = lane & 15, lg = lane >> 4;
    int r0 = blockIdx.x * 64 + wave * 16;
    int nb = blockIdx.y * 32;    // grid.y = 12 -> 384 cols
    f32x4 acc[2] = {};
    size_t arow = (size_t)(r0 + lr) * K + lg * 8;
    for (int ks = 0; ks < K; ks += 32) {
        short8 ah = ld_frag(Ahi + arow + ks);
        short8 al = ld_frag(Alo + arow + ks);
#pragma unroll
        for (int n = 0; n < 2; ++n) {
            size_t wrow = (size_t)(nb + n * 16 + lr) * K + ks + lg * 8;
            short8 wh = ld_frag(Whi + wrow);
            short8 wl = ld_frag(Wlo + wrow);
            acc[n] = MFMA16(ah, wh, acc[n]);
            acc[n] = MFMA16(al, wh, acc[n]);
            acc[n] = MFMA16(ah, wl, acc[n]);
        }
    }
#pragma unroll
    for (int n = 0; n < 2; ++n) {
        int col = nb + n * 16 + lr;
        int region = col >> 7;
        int c = col & 127;
        int hh = c >> 5, d = c & 31;
        float bs = bias[col];
#pragma unroll
        for (int r = 0; r < 4; ++r) {
            int row = r0 + lg * 4 + r;
            float v = acc[n][r] + bs;
            int g = row >> 10, p = row & 1023;
            size_t gh = (size_t)(g * NHEAD + hh);
            if (region == 0) {
                u16 vh, vl;
                fsplit(v, vh, vl);
                size_t o = (gh * NPGC + p) * HDIM + d;
                q_hi[o] = vh; q_lo[o] = vl;
            } else if (region == 1) {
                u16 vh, vl;
                fsplit(v, vh, vl);
                size_t o = (gh * NPGC + p) * HDIM + d;
                k_hi[o] = vh; k_lo[o] = vl;
            } else {
                // pi-permute key index within its 128-block: pp = (p&15)*8 + (p&127)/16
                int pp = (p & ~127) | (((p & 15) << 3) | ((p & 127) >> 4));
                vt_hi[(gh * HDIM + d) * NPGC + pp] = f2bf(v);
            }
        }
    }
}

// --- flash attention (KV-split): 4 waves/block, 16 q-rows/wave, KV chunk=128 ---

#define KVB 128
#define PLDS_STRIDE 136   // u16 units; 272B rows keep ds_*_b128 16B-aligned

__global__ __launch_bounds__(256) void k_attn(
    const u16* __restrict__ qhi, const u16* __restrict__ qlo,
    const u16* __restrict__ khi, const u16* __restrict__ klo,
    const u16* __restrict__ vthi,
    float* __restrict__ po, float2* __restrict__ pml) {
    __shared__ __align__(16) u16 plds[4][16][PLDS_STRIDE];
    int tid = threadIdx.x;
    int wave = tid >> 6, lane = tid & 63;
    int lr = lane & 15, lg = lane >> 4;
    int gh = blockIdx.y;                       // g*4 + head
    int q0 = blockIdx.x * 64 + wave * 16;      // row within NPG
    int half = blockIdx.z;
    size_t qbase = (size_t)gh * NPGC * HDIM;
    size_t vbase = (size_t)gh * HDIM * NPGC;
    short8 qh = ld_frag(qhi + qbase + (size_t)(q0 + lr) * HDIM + lg * 8);
    short8 ql = ld_frag(qlo + qbase + (size_t)(q0 + lr) * HDIM + lg * 8);
    const u16* Kh = khi + qbase;
    const u16* Kl = klo + qbase;
    const u16* Vh = vthi + vbase;
    f32x4 o0 = {}, o1 = {};
    float m[4], l[4];
#pragma unroll
    for (int r = 0; r < 4; ++r) { m[r] = -1e30f; l[r] = 0.f; }
    // cl = log2(e)/sqrt(HDIM): softmax over raw scores via exp2((s - m)*cl)
    const float cl = 0.2550348281f;
    const f32x4 zero = {};
    const int kv0 = half * (NPGC / NSPLIT);
    for (int kv = kv0; kv < kv0 + NPGC / NSPLIT; kv += KVB) {
        f32x4 s[8];
#pragma unroll
        for (int f = 0; f < 8; ++f) {
            size_t kr = (size_t)(kv + f * 16 + lr) * HDIM + lg * 8;
            short8 kh = ld_frag(Kh + kr);
            short8 kl = ld_frag(Kl + kr);
            s[f] = MFMA16(ql, kh, MFMA16(qh, kl, MFMA16(qh, kh, zero)));
        }
#pragma unroll
        for (int r = 0; r < 4; ++r) {
            float m01 = fmaxf(s[0][r], s[1][r]);
            float m23 = fmaxf(s[2][r], s[3][r]);
            float m45 = fmaxf(s[4][r], s[5][r]);
            float m67 = fmaxf(s[6][r], s[7][r]);
            float mx = fmaxf(fmaxf(m01, m23), fmaxf(m45, m67));
            mx = fmaxf(mx, __shfl_xor(mx, 1));
            mx = fmaxf(mx, __shfl_xor(mx, 2));
            mx = fmaxf(mx, __shfl_xor(mx, 4));
            mx = fmaxf(mx, __shfl_xor(mx, 8));
            float mn = fmaxf(m[r], mx);
            float mncl = mn * cl;
            float corr = EXP2(m[r] * cl - mncl);
            m[r] = mn;
            float e[8];
#pragma unroll
            for (int f = 0; f < 8; ++f) e[f] = EXP2(fmaf(s[f][r], cl, -mncl));
            float ps = ((e[0] + e[1]) + (e[2] + e[3])) + ((e[4] + e[5]) + (e[6] + e[7]));
            ps += __shfl_xor(ps, 1);
            ps += __shfl_xor(ps, 2);
            ps += __shfl_xor(ps, 4);
            ps += __shfl_xor(ps, 8);
            l[r] = fmaf(l[r], corr, ps);
            o0[r] *= corr; o1[r] *= corr;
            // pack P row (pi-order: lane's 8 cols contiguous at 8*lr) -> 1 b128 write
            u32x4 pw;
            pw[0] = cvtpk_bf16(e[0], e[1]);
            pw[1] = cvtpk_bf16(e[2], e[3]);
            pw[2] = cvtpk_bf16(e[4], e[5]);
            pw[3] = cvtpk_bf16(e[6], e[7]);
            *reinterpret_cast<u32x4*>(&plds[wave][lg * 4 + r][lr * 8]) = pw;
        }
        // PV: A = P (bf16), B = V^T rows in pi order (stored that way by k_qkv)
#pragma unroll
        for (int kk = 0; kk < 4; ++kk) {
            short8 pf = ld_frag(&plds[wave][lr][kk * 32 + lg * 8]);
            size_t vr = kv + kk * 32 + lg * 8;
            short8 vh0 = ld_frag(Vh + (size_t)lr * NPGC + vr);
            short8 vh1 = ld_frag(Vh + (size_t)(16 + lr) * NPGC + vr);
            o0 = MFMA16(pf, vh0, o0);
            o1 = MFMA16(pf, vh1, o1);
        }
    }
    // store raw partials (no 1/l): po[((gh*NPGC+row)*NSPLIT+half)*32 + col]
#pragma unroll
    for (int r = 0; r < 4; ++r) {
        int row = q0 + lg * 4 + r;
        size_t base = ((size_t)(gh * NPGC + row) * NSPLIT + half) * 32;
        po[base + lr] = o0[r];
        po[base + 16 + lr] = o1[r];
        if (lr == 0) pml[(size_t)(gh * NPGC + row) * NSPLIT + half] = make_float2(m[r], l[r]);
    }
}

// ------- merge KV-split partials -> ao hi/lo -------

__global__ __launch_bounds__(256) void k_amerge(
    const float* __restrict__ po, const float2* __restrict__ pml,
    u16* __restrict__ aohi, u16* __restrict__ aolo) {
    const float cl = 0.2550348281f;
    int idx = blockIdx.x * 256 + threadIdx.x;   // over NG*NHEAD*NPGC*32
    int col = idx & 31;
    int rowgh = idx >> 5;                       // gh*NPGC + row
    float2 ml0 = pml[(size_t)rowgh * 2 + 0];
    float2 ml1 = pml[(size_t)rowgh * 2 + 1];
    float M = fmaxf(ml0.x, ml1.x);
    float w0 = EXP2((ml0.x - M) * cl);
    float w1 = EXP2((ml1.x - M) * cl);
    float li = 1.f / (w0 * ml0.y + w1 * ml1.y);
    float o = (w0 * po[((size_t)rowgh * 2 + 0) * 32 + col] +
               w1 * po[((size_t)rowgh * 2 + 1) * 32 + col]) * li;
    int gh = rowgh >> 10, row = rowgh & 1023;
    int g = gh >> 2, hh = gh & 3;
    size_t off = ((size_t)g * NPGC + row) * CHN + hh * HDIM + col;
    u16 h, l2;
    fsplit(o, h, l2);
    aohi[off] = h; aolo[off] = l2;
}

// ---------------- pooling + head MLP ----------------

__global__ __launch_bounds__(128) void k_pool(const float* __restrict__ h,
                                              float* __restrict__ pool) {
    int g = blockIdx.x, c = threadIdx.x;
    const float* p = h + (size_t)g * NPGC * CHN + c;
    float s = 0.f;
    for (int i = 0; i < NPGC; ++i) s += p[(size_t)i * CHN];
    pool[g * CHN + c] = s;
}

__global__ __launch_bounds__(256) void k_head(
    const float* __restrict__ pool, const float* __restrict__ w1,
    const float* __restrict__ b1, const float* __restrict__ w2,
    const float* __restrict__ b2, const float* __restrict__ w3,
    const float* __restrict__ b3, float* __restrict__ out) {
    __shared__ float g1[16][64];
    __shared__ float g2[16][32];
    int t = threadIdx.x;
    for (int idx = t; idx < 16 * 64; idx += 256) {
        int g = idx >> 6, n = idx & 63;
        float s = b1[n];
        for (int k = 0; k < 128; ++k) s += pool[g * 128 + k] * w1[n * 128 + k];
        g1[g][n] = fmaxf(s, 0.f);
    }
    __syncthreads();
    for (int idx = t; idx < 16 * 32; idx += 256) {
        int g = idx >> 5, n = idx & 31;
        float s = b2[n];
        for (int k = 0; k < 64; ++k) s += g1[g][k] * w2[n * 64 + k];
        g2[g][n] = fmaxf(s, 0.f);
    }
    __syncthreads();
    if (t < 16) {
        float s = b3[0];
        for (int k = 0; k < 32; ++k) s += g2[t][k] * w3[k];
        out[t] = s;
    }
}

// ---------------- host ----------------

extern "C" void kernel_launch(void* const* d_in, const int* in_sizes, int n_in,
                              void* d_out, int out_size, void* d_ws, size_t ws_size,
                              hipStream_t stream) {
    (void)in_sizes; (void)n_in; (void)out_size; (void)ws_size;
    const float* x = (const float*)d_in[0];
    const float* edge_attr = (const float*)d_in[1];
    const int* edge_index = (const int*)d_in[2];
    const float* node_w = (const float*)d_in[4];
    const float* node_b = (const float*)d_in[5];
    const float* edge_w = (const float*)d_in[6];
    const float* edge_b = (const float*)d_in[7];
    const float* gine_w1 = (const float*)d_in[8];
    const float* gine_b1 = (const float*)d_in[9];
    const float* gine_w2 = (const float*)d_in[10];
    const float* gine_b2 = (const float*)d_in[11];
    const float* attn_in_w = (const float*)d_in[12];
    const float* attn_in_b = (const float*)d_in[13];
    const float* attn_out_w = (const float*)d_in[14];
    const float* attn_out_b = (const float*)d_in[15];
    const float* mlp_w1 = (const float*)d_in[16];
    const float* mlp_b1 = (const float*)d_in[17];
    const float* mlp_w2 = (const float*)d_in[18];
    const float* mlp_b2 = (const float*)d_in[19];
    const float* bn_g = (const float*)d_in[20];
    const float* bn_bb = (const float*)d_in[21];
    const float* bn_m = (const float*)d_in[22];
    const float* bn_v = (const float*)d_in[23];
    const float* head_w1 = (const float*)d_in[24];
    const float* head_b1 = (const float*)d_in[25];
    const float* head_w2 = (const float*)d_in[26];
    const float* head_b2 = (const float*)d_in[27];
    const float* head_w3 = (const float*)d_in[28];
    const float* head_b3 = (const float*)d_in[29];

    char* ws = (char*)d_ws;
    size_t off = 0;
    auto alloc = [&](size_t bytes) {
        size_t r = off;
        off = (off + bytes + 255) & ~(size_t)255;
        return r;
    };
    const size_t NC = (size_t)NODES * CHN;
    float* h_f32 = (float*)(ws + alloc(NC * 4));
    u16* h_hi = (u16*)(ws + alloc(NC * 2));
    u16* h_lo = (u16*)(ws + alloc(NC * 2));
    u16* x_hi = (u16*)(ws + alloc((size_t)NODES * 64 * 2));
    u16* x_lo = (u16*)(ws + alloc((size_t)NODES * 64 * 2));
    u16* zao_hi = (u16*)(ws + alloc(NC * 2));   // z1 / ao reuse
    u16* zao_lo = (u16*)(ws + alloc(NC * 2));
    u16* tff_hi = (u16*)(ws + alloc(NC * 2 * 2));  // t1 (first half) / ff (full)
    u16* tff_lo = (u16*)(ws + alloc(NC * 2 * 2));
    float* h1_f32 = (float*)(ws + alloc(NC * 4));
    u16* q_hi = (u16*)(ws + alloc(NC * 2));
    u16* q_lo = (u16*)(ws + alloc(NC * 2));
    u16* kk_hi = (u16*)(ws + alloc(NC * 2));
    u16* kk_lo = (u16*)(ws + alloc(NC * 2));
    u16* vt_hi = (u16*)(ws + alloc(NC * 2));
    float* out_f32 = (float*)(ws + alloc(NC * 4));
    u16* out_hi = (u16*)(ws + alloc(NC * 2));
    u16* out_lo = (u16*)(ws + alloc(NC * 2));
    float* po = (float*)(ws + alloc(NC * NSPLIT * 4));         // 16.8 MB partial O
    float2* pml = (float2*)(ws + alloc((size_t)NODES * NHEAD * NSPLIT * 8));
    float* pool = (float*)(ws + alloc(NG * CHN * 4));
    u16* node_w_hi = (u16*)(ws + alloc(CHN * 64 * 2));
    u16* node_w_lo = (u16*)(ws + alloc(CHN * 64 * 2));
    u16* gw1_hi = (u16*)(ws + alloc((size_t)NLAYER * CHN * CHN * 2));
    u16* gw1_lo = (u16*)(ws + alloc((size_t)NLAYER * CHN * CHN * 2));
    u16* gw2_hi = (u16*)(ws + alloc((size_t)NLAYER * CHN * CHN * 2));
    u16* gw2_lo = (u16*)(ws + alloc((size_t)NLAYER * CHN * CHN * 2));
    u16* aiw_hi = (u16*)(ws + alloc((size_t)NLAYER * 3 * CHN * CHN * 2));
    u16* aiw_lo = (u16*)(ws + alloc((size_t)NLAYER * 3 * CHN * CHN * 2));
    u16* aow_hi = (u16*)(ws + alloc((size_t)NLAYER * CHN * CHN * 2));
    u16* aow_lo = (u16*)(ws + alloc((size_t)NLAYER * CHN * CHN * 2));
    u16* mw1_hi = (u16*)(ws + alloc((size_t)NLAYER * 2 * CHN * CHN * 2));
    u16* mw1_lo = (u16*)(ws + alloc((size_t)NLAYER * 2 * CHN * CHN * 2));
    u16* mw2_hi = (u16*)(ws + alloc((size_t)NLAYER * 2 * CHN * CHN * 2));
    u16* mw2_lo = (u16*)(ws + alloc((size_t)NLAYER * 2 * CHN * CHN * 2));
    float* bn_scale = (float*)(ws + alloc(NLAYER * 3 * CHN * 4));
    float* bn_shift = (float*)(ws + alloc(NLAYER * 3 * CHN * 4));
    u32* counts = (u32*)(ws + alloc(NODES * 4));
    u32* offsets = (u32*)(ws + alloc((NODES + 1) * 4));
    u32* cursor = (u32*)(ws + alloc(NODES * 4));
    int* csr_src = (int*)(ws + alloc((size_t)NEDGE * 4));
    float* csr_a = (float*)(ws + alloc((size_t)NEDGE * 4));

    const int* e_src = edge_index;
    const int* e_dst = edge_index + NEDGE;

    // one fused split launch for all 8 fp32->hi/lo conversions
    {
        SplitJobs j;
        const float* srcs[8] = {x, node_w, gine_w1, gine_w2, attn_in_w,
                                attn_out_w, mlp_w1, mlp_w2};
        u16* his[8] = {x_hi, node_w_hi, gw1_hi, gw2_hi, aiw_hi, aow_hi, mw1_hi, mw2_hi};
        u16* los[8] = {x_lo, node_w_lo, gw1_lo, gw2_lo, aiw_lo, aow_lo, mw1_lo, mw2_lo};
        int ns[8] = {NODES * 64, CHN * 64, NLAYER * CHN * CHN, NLAYER * CHN * CHN,
                     NLAYER * 3 * CHN * CHN, NLAYER * CHN * CHN,
                     NLAYER * 2 * CHN * CHN, NLAYER * 2 * CHN * CHN};
        int cum = 0;
        for (int i = 0; i < 8; ++i) {
            j.src[i] = srcs[i]; j.hi[i] = his[i]; j.lo[i] = los[i];
            cum += ns[i] / 256;
            j.blk_end[i] = cum;
        }
        k_split8<<<dim3(cum), dim3(256), 0, stream>>>(j);
    }

    k_bnprep<<<dim3((NLAYER * 3 * CHN + 255) / 256), dim3(256), 0, stream>>>(
        bn_g, bn_bb, bn_m, bn_v, bn_scale, bn_shift);

    k_zero_u32<<<dim3(NODES / 256), dim3(256), 0, stream>>>(counts, NODES);
    k_count<<<dim3(NEDGE / 256), dim3(256), 0, stream>>>(e_dst, counts);
    k_scan<<<dim3(1), dim3(256), 0, stream>>>(counts, offsets, cursor);
    k_fill<<<dim3(NEDGE / 256), dim3(256), 0, stream>>>(e_src, e_dst, edge_attr,
                                                        cursor, csr_src, csr_a);

    auto gemm = [&](const u16* Ah, const u16* Al, const u16* Wh, const u16* Wl,
                    const float* bias, const float* r1, const float* bsc,
                    const float* bsh, const float* r2, float* of, u16* ohi,
                    u16* olo, int K, int Nc, int relu) {
        k_gemm<<<dim3(NODES / 64, Nc / 32), dim3(256), 0, stream>>>(
            Ah, Al, Wh, Wl, bias, r1, bsc, bsh, r2, of, ohi, olo, K, Nc, relu);
    };

    // node projection: h = x @ node_w^T + node_b
    gemm(x_hi, x_lo, node_w_hi, node_w_lo, node_b, nullptr, nullptr, nullptr,
         nullptr, h_f32, h_hi, h_lo, 64, CHN, 0);

    for (int l = 0; l < NLAYER; ++l) {
        size_t wo = (size_t)l * CHN * CHN;
        const float* sc0 = bn_scale + (l * 3 + 0) * CHN;
        const float* sh0 = bn_shift + (l * 3 + 0) * CHN;
        const float* sc1 = bn_scale + (l * 3 + 1) * CHN;
        const float* sh1 = bn_shift + (l * 3 + 1) * CHN;
        const float* sc2 = bn_scale + (l * 3 + 2) * CHN;
        const float* sh2 = bn_shift + (l * 3 + 2) * CHN;

        // GINE aggregate -> z (hi/lo)
        k_agg<<<dim3(NODES), dim3(64), 0, stream>>>(h_hi, h_f32, offsets, csr_src,
                                                    csr_a, edge_w, edge_b,
                                                    zao_hi, zao_lo);
        // gine MLP: t1 = relu(z@w1+b1); h1 = bn(t1@w2+b2 + h)
        gemm(zao_hi, zao_lo, gw1_hi + wo, gw1_lo + wo, gine_b1 + l * CHN,
             nullptr, nullptr, nullptr, nullptr, nullptr, tff_hi, tff_lo,
             CHN, CHN, 1);
        gemm(tff_hi, tff_lo, gw2_hi + wo, gw2_lo + wo, gine_b2 + l * CHN,
             h_f32, sc0, sh0, nullptr, h1_f32, nullptr, nullptr, CHN, CHN, 0);
        // attention
        k_qkv<<<dim3(NODES / 64, 12), dim3(256), 0, stream>>>(
            h_hi, h_lo, aiw_hi + wo * 3, aiw_lo + wo * 3, attn_in_b + l * 3 * CHN,
            q_hi, q_lo, kk_hi, kk_lo, vt_hi);
        k_attn<<<dim3(NPGC / 64, NG * NHEAD, NSPLIT), dim3(256), 0, stream>>>(
            q_hi, q_lo, kk_hi, kk_lo, vt_hi, po, pml);
        k_amerge<<<dim3(NODES * NHEAD * 32 / 256), dim3(256), 0, stream>>>(
            po, pml, zao_hi, zao_lo);
        // out projection: out = bn(ao@W+b + h) + h1
        gemm(zao_hi, zao_lo, aow_hi + wo, aow_lo + wo, attn_out_b + l * CHN,
             h_f32, sc1, sh1, h1_f32, out_f32, out_hi, out_lo, CHN, CHN, 0);
        // FFN: ff = relu(out@w1+b1); h = bn(ff@w2+b2 + out)
        gemm(out_hi, out_lo, mw1_hi + wo * 2, mw1_lo + wo * 2, mlp_b1 + l * 2 * CHN,
             nullptr, nullptr, nullptr, nullptr, nullptr, tff_hi, tff_lo,
             CHN, 2 * CHN, 1);
        gemm(tff_hi, tff_lo, mw2_hi + wo * 2, mw2_lo + wo * 2, mlp_b2 + l * CHN,
             out_f32, sc2, sh2, nullptr, h_f32, h_hi, h_lo, 2 * CHN, CHN, 0);
    }

    k_pool<<<dim3(NG), dim3(CHN), 0, stream>>>(h_f32, pool);
    k_head<<<dim3(1), dim3(256), 0, stream>>>(pool, head_w1, head_b1, head_w2,
                                              head_b2, head_w3, head_b3,
                                              (float*)d_out);
}

// Round 5
// 1033.756 us; speedup vs baseline: 1.1118x; 1.1118x over previous
//
#include <hip/hip_runtime.h>
#include <hip/hip_bf16.h>

typedef __attribute__((ext_vector_type(8))) short short8;
typedef __attribute__((ext_vector_type(4))) float f32x4;
typedef __attribute__((ext_vector_type(2))) unsigned int u32x2;
typedef unsigned short u16;
typedef unsigned int u32;
typedef unsigned long long u64;

#define NODES 16384
#define CHN 128
#define NEDGE 524288
#define NG 16
#define NPGC 1024
#define NHEAD 4
#define HDIM 32
#define NLAYER 4

#if __has_builtin(__builtin_amdgcn_exp2f)
#define EXP2(x) __builtin_amdgcn_exp2f(x)
#else
#define EXP2(x) exp2f(x)
#endif

__device__ __forceinline__ float bf2f(u16 u) {
    union { u32 u; float f; } c; c.u = ((u32)u) << 16; return c.f;
}
__device__ __forceinline__ u16 f2bf(float f) {
    union { float f; u32 u; } c; c.f = f;
    u32 r = c.u + 0x7fffu + ((c.u >> 16) & 1u);
    return (u16)(r >> 16);
}
__device__ __forceinline__ void fsplit(float f, u16& hi, u16& lo) {
    u16 h = f2bf(f);
    hi = h;
    lo = f2bf(f - bf2f(h));
}
// packs bf16(a) into low 16, bf16(b) into high 16
__device__ __forceinline__ u32 cvtpk_bf16(float a, float b) {
    u32 r;
    asm("v_cvt_pk_bf16_f32 %0, %1, %2" : "=v"(r) : "v"(a), "v"(b));
    return r;
}

#define MFMA16(a, b, c) __builtin_amdgcn_mfma_f32_16x16x32_bf16((a), (b), (c), 0, 0, 0)

__device__ __forceinline__ short8 ld_frag(const u16* p) {
    return *reinterpret_cast<const short8*>(p);
}

// ---------------- setup kernels ----------------

struct SplitJobs {
    const float* src[8];
    u16* hi[8];
    u16* lo[8];
    int blk_end[8];   // cumulative block counts (each job n % 256 == 0)
};

__global__ void k_split8(SplitJobs jobs) {
    int b = blockIdx.x;
    int seg = 0;
    while (b >= jobs.blk_end[seg]) ++seg;
    int base = seg ? jobs.blk_end[seg - 1] : 0;
    int i = (b - base) * 256 + threadIdx.x;
    u16 h, l;
    fsplit(jobs.src[seg][i], h, l);
    jobs.hi[seg][i] = h;
    jobs.lo[seg][i] = l;
}

__global__ void k_bnprep(const float* __restrict__ g, const float* __restrict__ b,
                         const float* __restrict__ m, const float* __restrict__ v,
                         float* __restrict__ scale, float* __restrict__ shift) {
    int i = blockIdx.x * 256 + threadIdx.x;
    if (i < NLAYER * 3 * CHN) {
        float s = g[i] * rsqrtf(v[i] + 1e-5f);
        scale[i] = s;
        shift[i] = b[i] - m[i] * s;
    }
}

__global__ void k_zero_u32(u32* __restrict__ p, int n) {
    int i = blockIdx.x * 256 + threadIdx.x;
    if (i < n) p[i] = 0u;
}

__global__ void k_count(const int* __restrict__ dst, u32* __restrict__ counts) {
    int e = blockIdx.x * 256 + threadIdx.x;
    if (e < NEDGE) atomicAdd(&counts[dst[e]], 1u);
}

// single block, 256 threads, 64 elems each
__global__ void k_scan(const u32* __restrict__ counts, u32* __restrict__ offsets,
                       u32* __restrict__ cursor) {
    __shared__ u32 part[256];
    int t = threadIdx.x;
    int base = t * 64;
    u32 s = 0;
    for (int i = 0; i < 64; ++i) s += counts[base + i];
    part[t] = s;
    __syncthreads();
    for (int off = 1; off < 256; off <<= 1) {
        u32 val = (t >= off) ? part[t - off] : 0u;
        __syncthreads();
        part[t] += val;
        __syncthreads();
    }
    u32 run = (t == 0) ? 0u : part[t - 1];
    for (int i = 0; i < 64; ++i) {
        offsets[base + i] = run;
        cursor[base + i] = run;
        run += counts[base + i];
    }
    if (t == 255) offsets[NODES] = run;
}

__global__ void k_fill(const int* __restrict__ src, const int* __restrict__ dst,
                       const float* __restrict__ eattr, u32* __restrict__ cursor,
                       int* __restrict__ csr_src, float* __restrict__ csr_a) {
    int e = blockIdx.x * 256 + threadIdx.x;
    if (e >= NEDGE) return;
    int d = dst[e];
    u32 p = atomicAdd(&cursor[d], 1u);
    csr_src[p] = src[e];
    csr_a[p] = eattr[e];
}

// ------ GINE aggregation: z1 = h + sum_in relu(h[src] + a*ew + eb), bf16 gather ------

__global__ __launch_bounds__(64) void k_agg(
    const u16* __restrict__ h_hi, const float* __restrict__ h_f32,
    const u32* __restrict__ offsets, const int* __restrict__ csr_src,
    const float* __restrict__ csr_a, const float* __restrict__ ew,
    const float* __restrict__ eb, u16* __restrict__ z_hi, u16* __restrict__ z_lo) {
    int node = blockIdx.x;
    int t = threadIdx.x;          // 64 threads, 2 channels each
    int c0 = t * 2;
    float w0 = ew[c0], w1 = ew[c0 + 1];
    float b0 = eb[c0], b1 = eb[c0 + 1];
    u32 beg = offsets[node], end = offsets[node + 1];
    float acc0 = 0.f, acc1 = 0.f;
    for (u32 j = beg; j < end; ++j) {
        int s = csr_src[j];
        float a = csr_a[j];
        u32 u = *reinterpret_cast<const u32*>(h_hi + (size_t)s * CHN + c0);
        float f0 = bf2f((u16)(u & 0xffffu));
        float f1 = bf2f((u16)(u >> 16));
        acc0 += fmaxf(f0 + a * w0 + b0, 0.f);
        acc1 += fmaxf(f1 + a * w1 + b1, 0.f);
    }
    size_t idx = (size_t)node * CHN + c0;
    float z0 = h_f32[idx] + acc0;
    float z1v = h_f32[idx + 1] + acc1;
    u16 h, l;
    fsplit(z0, h, l); z_hi[idx] = h; z_lo[idx] = l;
    fsplit(z1v, h, l); z_hi[idx + 1] = h; z_lo[idx + 1] = l;
}

// ------ split GEMM (16x32 wave tile): acc=(Ah+Al)@(Wh+Wl)^T; epi chain ------

__global__ __launch_bounds__(256) void k_gemm(
    const u16* __restrict__ Ahi, const u16* __restrict__ Alo,
    const u16* __restrict__ Whi, const u16* __restrict__ Wlo,
    const float* __restrict__ bias, const float* __restrict__ resid1,
    const float* __restrict__ bnscale, const float* __restrict__ bnshift,
    const float* __restrict__ resid2, float* __restrict__ out_f32,
    u16* __restrict__ out_hi, u16* __restrict__ out_lo, int K, int Nc, int relu) {
    int tid = threadIdx.x;
    int wave = tid >> 6, lane = tid & 63;
    int lr = lane & 15, lg = lane >> 4;
    int r0 = blockIdx.x * 64 + wave * 16;
    int nb = blockIdx.y * 32;
    f32x4 acc[2] = {};
    size_t arow = (size_t)(r0 + lr) * K + lg * 8;
    for (int ks = 0; ks < K; ks += 32) {
        short8 ah = ld_frag(Ahi + arow + ks);
        short8 al = ld_frag(Alo + arow + ks);
#pragma unroll
        for (int n = 0; n < 2; ++n) {
            size_t wrow = (size_t)(nb + n * 16 + lr) * K + ks + lg * 8;
            short8 wh = ld_frag(Whi + wrow);
            short8 wl = ld_frag(Wlo + wrow);
            acc[n] = MFMA16(ah, wh, acc[n]);
            acc[n] = MFMA16(al, wh, acc[n]);
            acc[n] = MFMA16(ah, wl, acc[n]);
        }
    }
#pragma unroll
    for (int n = 0; n < 2; ++n) {
        int col = nb + n * 16 + lr;
        float bs = bias ? bias[col] : 0.f;
        float sc = bnscale ? bnscale[col] : 1.f;
        float sh = bnshift ? bnshift[col] : 0.f;
#pragma unroll
        for (int r = 0; r < 4; ++r) {
            int row = r0 + lg * 4 + r;
            size_t oidx = (size_t)row * Nc + col;
            float v = acc[n][r] + bs;
            if (resid1) v += resid1[oidx];
            v = v * sc + sh;
            if (resid2) v += resid2[oidx];
            if (relu) v = fmaxf(v, 0.f);
            if (out_f32) out_f32[oidx] = v;
            if (out_hi) {
                u16 hh, ll;
                fsplit(v, hh, ll);
                out_hi[oidx] = hh; out_lo[oidx] = ll;
            }
        }
    }
}

// ---- fused GINE MLP: h1 = bn(relu(z@W1+b1)@W2 + b2 + h); t1 staged in LDS ----

__global__ __launch_bounds__(256) void k_gine(
    const u16* __restrict__ zhi, const u16* __restrict__ zlo,
    const u16* __restrict__ w1hi, const u16* __restrict__ w1lo,
    const float* __restrict__ b1,
    const u16* __restrict__ w2hi, const u16* __restrict__ w2lo,
    const float* __restrict__ b2, const float* __restrict__ resid,
    const float* __restrict__ bnsc, const float* __restrict__ bnsh,
    float* __restrict__ h1out) {
    __shared__ __align__(16) u16 t_hi[64][136];
    __shared__ __align__(16) u16 t_lo[64][136];
    int tid = threadIdx.x;
    int wave = tid >> 6, lane = tid & 63;
    int lr = lane & 15, lg = lane >> 4;
    int r0 = blockIdx.x * 64 + wave * 16;
    {
        f32x4 acc[8] = {};
        size_t arow = (size_t)(r0 + lr) * CHN + lg * 8;
        for (int ks = 0; ks < CHN; ks += 32) {
            short8 ah = ld_frag(zhi + arow + ks);
            short8 al = ld_frag(zlo + arow + ks);
#pragma unroll
            for (int n = 0; n < 8; ++n) {
                size_t wrow = (size_t)(n * 16 + lr) * CHN + ks + lg * 8;
                short8 wh = ld_frag(w1hi + wrow);
                short8 wl = ld_frag(w1lo + wrow);
                acc[n] = MFMA16(ah, wh, acc[n]);
                acc[n] = MFMA16(al, wh, acc[n]);
                acc[n] = MFMA16(ah, wl, acc[n]);
            }
        }
#pragma unroll
        for (int n = 0; n < 8; ++n) {
            float bs = b1[n * 16 + lr];
#pragma unroll
            for (int r = 0; r < 4; ++r) {
                float v = fmaxf(acc[n][r] + bs, 0.f);
                u16 hh, ll;
                fsplit(v, hh, ll);
                int row = wave * 16 + lg * 4 + r;
                t_hi[row][n * 16 + lr] = hh;
                t_lo[row][n * 16 + lr] = ll;
            }
        }
    }
    __syncthreads();
    {
        f32x4 acc[8] = {};
        for (int ks = 0; ks < CHN; ks += 32) {
            short8 ah = ld_frag(&t_hi[wave * 16 + lr][ks + lg * 8]);
            short8 al = ld_frag(&t_lo[wave * 16 + lr][ks + lg * 8]);
#pragma unroll
            for (int n = 0; n < 8; ++n) {
                size_t wrow = (size_t)(n * 16 + lr) * CHN + ks + lg * 8;
                short8 wh = ld_frag(w2hi + wrow);
                short8 wl = ld_frag(w2lo + wrow);
                acc[n] = MFMA16(ah, wh, acc[n]);
                acc[n] = MFMA16(al, wh, acc[n]);
                acc[n] = MFMA16(ah, wl, acc[n]);
            }
        }
#pragma unroll
        for (int n = 0; n < 8; ++n) {
            int col = n * 16 + lr;
            float bs = b2[col], sc = bnsc[col], sh = bnsh[col];
#pragma unroll
            for (int r = 0; r < 4; ++r) {
                int row = r0 + lg * 4 + r;
                size_t oidx = (size_t)row * CHN + col;
                float v = acc[n][r] + bs + resid[oidx];
                h1out[oidx] = v * sc + sh;
            }
        }
    }
}

// ---- fused FFN: h = bn(relu(out@W1+b1)@W2 + b2 + out); 32 rows/block, 2 waves ----

__global__ __launch_bounds__(128) void k_ffn(
    const u16* __restrict__ ahi, const u16* __restrict__ alo,
    const u16* __restrict__ w1hi, const u16* __restrict__ w1lo,
    const float* __restrict__ b1,
    const u16* __restrict__ w2hi, const u16* __restrict__ w2lo,
    const float* __restrict__ b2, const float* __restrict__ resid,
    const float* __restrict__ bnsc, const float* __restrict__ bnsh,
    float* __restrict__ h_f32, u16* __restrict__ h_hi, u16* __restrict__ h_lo) {
    __shared__ __align__(16) u16 t_hi[32][264];
    __shared__ __align__(16) u16 t_lo[32][264];
    int tid = threadIdx.x;
    int wave = tid >> 6, lane = tid & 63;
    int lr = lane & 15, lg = lane >> 4;
    int r0 = blockIdx.x * 32 + wave * 16;
    {
        f32x4 acc[16] = {};
        size_t arow = (size_t)(r0 + lr) * CHN + lg * 8;
        for (int ks = 0; ks < CHN; ks += 32) {
            short8 ah = ld_frag(ahi + arow + ks);
            short8 al = ld_frag(alo + arow + ks);
#pragma unroll
            for (int n = 0; n < 16; ++n) {
                size_t wrow = (size_t)(n * 16 + lr) * CHN + ks + lg * 8;
                short8 wh = ld_frag(w1hi + wrow);
                short8 wl = ld_frag(w1lo + wrow);
                acc[n] = MFMA16(ah, wh, acc[n]);
                acc[n] = MFMA16(al, wh, acc[n]);
                acc[n] = MFMA16(ah, wl, acc[n]);
            }
        }
#pragma unroll
        for (int n = 0; n < 16; ++n) {
            float bs = b1[n * 16 + lr];
#pragma unroll
            for (int r = 0; r < 4; ++r) {
                float v = fmaxf(acc[n][r] + bs, 0.f);
                u16 hh, ll;
                fsplit(v, hh, ll);
                int row = wave * 16 + lg * 4 + r;
                t_hi[row][n * 16 + lr] = hh;
                t_lo[row][n * 16 + lr] = ll;
            }
        }
    }
    __syncthreads();
    {
        f32x4 acc[8] = {};
        for (int ks = 0; ks < 2 * CHN; ks += 32) {
            short8 ah = ld_frag(&t_hi[wave * 16 + lr][ks + lg * 8]);
            short8 al = ld_frag(&t_lo[wave * 16 + lr][ks + lg * 8]);
#pragma unroll
            for (int n = 0; n < 8; ++n) {
                size_t wrow = (size_t)(n * 16 + lr) * 2 * CHN + ks + lg * 8;
                short8 wh = ld_frag(w2hi + wrow);
                short8 wl = ld_frag(w2lo + wrow);
                acc[n] = MFMA16(ah, wh, acc[n]);
                acc[n] = MFMA16(al, wh, acc[n]);
                acc[n] = MFMA16(ah, wl, acc[n]);
            }
        }
#pragma unroll
        for (int n = 0; n < 8; ++n) {
            int col = n * 16 + lr;
            float bs = b2[col], sc = bnsc[col], sh = bnsh[col];
#pragma unroll
            for (int r = 0; r < 4; ++r) {
                int row = r0 + lg * 4 + r;
                size_t oidx = (size_t)row * CHN + col;
                float v = acc[n][r] + bs + resid[oidx];
                v = v * sc + sh;
                h_f32[oidx] = v;
                u16 hh, ll;
                fsplit(v, hh, ll);
                h_hi[oidx] = hh; h_lo[oidx] = ll;
            }
        }
    }
}

// -------- QKV GEMM with head-split hi/lo store (V transposed, hi-only) --------

__global__ __launch_bounds__(256) void k_qkv(
    const u16* __restrict__ Ahi, const u16* __restrict__ Alo,
    const u16* __restrict__ Whi, const u16* __restrict__ Wlo,
    const float* __restrict__ bias,
    u16* __restrict__ q_hi, u16* __restrict__ q_lo,
    u16* __restrict__ k_hi, u16* __restrict__ k_lo,
    u16* __restrict__ vt_hi) {
    const int K = 128;
    int tid = threadIdx.x;
    int wave = tid >> 6, lane = tid & 63;
    int lr = lane & 15, lg = lane >> 4;
    int r0 = blockIdx.x * 64 + wave * 16;
    int nb = blockIdx.y * 32;    // grid.y = 12 -> 384 cols
    f32x4 acc[2] = {};
    size_t arow = (size_t)(r0 + lr) * K + lg * 8;
    for (int ks = 0; ks < K; ks += 32) {
        short8 ah = ld_frag(Ahi + arow + ks);
        short8 al = ld_frag(Alo + arow + ks);
#pragma unroll
        for (int n = 0; n < 2; ++n) {
            size_t wrow = (size_t)(nb + n * 16 + lr) * K + ks + lg * 8;
            short8 wh = ld_frag(Whi + wrow);
            short8 wl = ld_frag(Wlo + wrow);
            acc[n] = MFMA16(ah, wh, acc[n]);
            acc[n] = MFMA16(al, wh, acc[n]);
            acc[n] = MFMA16(ah, wl, acc[n]);
        }
    }
#pragma unroll
    for (int n = 0; n < 2; ++n) {
        int col = nb + n * 16 + lr;
        int region = col >> 7;
        int c = col & 127;
        int hh = c >> 5, d = c & 31;
        float bs = bias[col];
#pragma unroll
        for (int r = 0; r < 4; ++r) {
            int row = r0 + lg * 4 + r;
            float v = acc[n][r] + bs;
            int g = row >> 10, p = row & 1023;
            size_t gh = (size_t)(g * NHEAD + hh);
            if (region == 0) {
                u16 vh, vl;
                fsplit(v, vh, vl);
                size_t o = (gh * NPGC + p) * HDIM + d;
                q_hi[o] = vh; q_lo[o] = vl;
            } else if (region == 1) {
                u16 vh, vl;
                fsplit(v, vh, vl);
                size_t o = (gh * NPGC + p) * HDIM + d;
                k_hi[o] = vh; k_lo[o] = vl;
            } else {
                vt_hi[(gh * HDIM + d) * NPGC + p] = f2bf(v);
            }
        }
    }
}

// --- flash attention, swapped QK^T: lane holds full 128-key score slice for one q row ---
// S^T = mfma(K, Q): C[kidx][q] -> lane(lr,lg) holds kidx = kv + f*16 + lg*4 + r, q = lr.
// Softmax reduce over k is in-lane (32 values) + 2 shuffles (xor 16/32 over lg groups).
// P lands in natural key order -> PV is mfma(V^T, P) with natural V^T layout.

__global__ __launch_bounds__(256) void k_attn(
    const u16* __restrict__ qhi, const u16* __restrict__ qlo,
    const u16* __restrict__ khi, const u16* __restrict__ klo,
    const u16* __restrict__ vthi,
    u16* __restrict__ aohi, u16* __restrict__ aolo) {
    __shared__ __align__(16) u16 plds[4][16][136];
    int tid = threadIdx.x;
    int wave = tid >> 6, lane = tid & 63;
    int lr = lane & 15, lg = lane >> 4;
    int gh = blockIdx.y;                       // g*4 + head
    int q0 = blockIdx.x * 64 + wave * 16;      // row within NPG
    size_t base = (size_t)gh * NPGC * HDIM;
    size_t vbase = (size_t)gh * HDIM * NPGC;
    short8 qh = ld_frag(qhi + base + (size_t)(q0 + lr) * HDIM + lg * 8);
    short8 ql = ld_frag(qlo + base + (size_t)(q0 + lr) * HDIM + lg * 8);
    const u16* Kh = khi + base;
    const u16* Kl = klo + base;
    const u16* Vh = vthi + vbase;
    f32x4 o0 = {}, o1 = {};
    float m = -1e30f, l = 0.f;
    const float cl = 0.2550348281f;   // log2(e)/sqrt(HDIM)
    const f32x4 zero = {};
    for (int kv = 0; kv < NPGC; kv += 128) {
        f32x4 s[8];
#pragma unroll
        for (int f = 0; f < 8; ++f) {
            size_t kr = (size_t)(kv + f * 16 + lr) * HDIM + lg * 8;
            short8 kh = ld_frag(Kh + kr);
            short8 kl = ld_frag(Kl + kr);
            s[f] = MFMA16(kh, ql, MFMA16(kl, qh, MFMA16(kh, qh, zero)));
        }
        // in-lane max over 32 values + 2 shuffles across lg groups
        f32x4 mm = s[0];
#pragma unroll
        for (int f = 1; f < 8; ++f)
#pragma unroll
            for (int i = 0; i < 4; ++i) mm[i] = fmaxf(mm[i], s[f][i]);
        float mx = fmaxf(fmaxf(mm[0], mm[1]), fmaxf(mm[2], mm[3]));
        mx = fmaxf(mx, __shfl_xor(mx, 16));
        mx = fmaxf(mx, __shfl_xor(mx, 32));
        float mn = fmaxf(m, mx);
        float mncl = mn * cl;
        float corr = EXP2((m - mn) * cl);
        m = mn;
#pragma unroll
        for (int f = 0; f < 8; ++f)
#pragma unroll
            for (int i = 0; i < 4; ++i) s[f][i] = EXP2(fmaf(s[f][i], cl, -mncl));
        f32x4 sum4 = s[0];
#pragma unroll
        for (int f = 1; f < 8; ++f)
#pragma unroll
            for (int i = 0; i < 4; ++i) sum4[i] += s[f][i];
        float ps = (sum4[0] + sum4[1]) + (sum4[2] + sum4[3]);
        ps += __shfl_xor(ps, 16);
        ps += __shfl_xor(ps, 32);
        l = fmaf(l, corr, ps);
#pragma unroll
        for (int i = 0; i < 4; ++i) { o0[i] *= corr; o1[i] *= corr; }
        // P write: natural key order, row = q (lr), 8B per f
#pragma unroll
        for (int f = 0; f < 8; ++f) {
            u32x2 wv;
            wv[0] = cvtpk_bf16(s[f][0], s[f][1]);
            wv[1] = cvtpk_bf16(s[f][2], s[f][3]);
            *reinterpret_cast<u32x2*>(&plds[wave][lr][f * 16 + lg * 4]) = wv;
        }
        // PV: O^T[d][q] += V^T[d][k] * P[q][k]   (per-wave LDS tile, in-order DS ops)
#pragma unroll
        for (int kk = 0; kk < 4; ++kk) {
            short8 pf = ld_frag(&plds[wave][lr][kk * 32 + lg * 8]);
            size_t vr = (size_t)kv + kk * 32 + lg * 8;
            short8 vh0 = ld_frag(Vh + (size_t)lr * NPGC + vr);
            short8 vh1 = ld_frag(Vh + (size_t)(16 + lr) * NPGC + vr);
            o0 = MFMA16(vh0, pf, o0);
            o1 = MFMA16(vh1, pf, o1);
        }
    }
    // lane (lr,lg): q = q0+lr, d = lg*4 + i (o0) / 16 + lg*4 + i (o1)
    float inv = 1.f / l;
    int g = gh >> 2, hh = gh & 3;
    size_t node = (size_t)g * NPGC + q0 + lr;
    size_t obase = node * CHN + hh * HDIM;
    union { u16 u[4]; u64 v; } p0h, p0l, p1h, p1l;
#pragma unroll
    for (int i = 0; i < 4; ++i) {
        u16 a, b;
        fsplit(o0[i] * inv, a, b); p0h.u[i] = a; p0l.u[i] = b;
        fsplit(o1[i] * inv, a, b); p1h.u[i] = a; p1l.u[i] = b;
    }
    *reinterpret_cast<u64*>(aohi + obase + lg * 4) = p0h.v;
    *reinterpret_cast<u64*>(aolo + obase + lg * 4) = p0l.v;
    *reinterpret_cast<u64*>(aohi + obase + 16 + lg * 4) = p1h.v;
    *reinterpret_cast<u64*>(aolo + obase + 16 + lg * 4) = p1l.v;
}

// ---------------- pooling + head MLP ----------------

__global__ __launch_bounds__(128) void k_pool(const float* __restrict__ h,
                                              float* __restrict__ pool) {
    int g = blockIdx.x, c = threadIdx.x;
    const float* p = h + (size_t)g * NPGC * CHN + c;
    float s = 0.f;
    for (int i = 0; i < NPGC; ++i) s += p[(size_t)i * CHN];
    pool[g * CHN + c] = s;
}

__global__ __launch_bounds__(256) void k_head(
    const float* __restrict__ pool, const float* __restrict__ w1,
    const float* __restrict__ b1, const float* __restrict__ w2,
    const float* __restrict__ b2, const float* __restrict__ w3,
    const float* __restrict__ b3, float* __restrict__ out) {
    __shared__ float g1[16][64];
    __shared__ float g2[16][32];
    int t = threadIdx.x;
    for (int idx = t; idx < 16 * 64; idx += 256) {
        int g = idx >> 6, n = idx & 63;
        float s = b1[n];
        for (int k = 0; k < 128; ++k) s += pool[g * 128 + k] * w1[n * 128 + k];
        g1[g][n] = fmaxf(s, 0.f);
    }
    __syncthreads();
    for (int idx = t; idx < 16 * 32; idx += 256) {
        int g = idx >> 5, n = idx & 31;
        float s = b2[n];
        for (int k = 0; k < 64; ++k) s += g1[g][k] * w2[n * 64 + k];
        g2[g][n] = fmaxf(s, 0.f);
    }
    __syncthreads();
    if (t < 16) {
        float s = b3[0];
        for (int k = 0; k < 32; ++k) s += g2[t][k] * w3[k];
        out[t] = s;
    }
}

// ---------------- host ----------------

extern "C" void kernel_launch(void* const* d_in, const int* in_sizes, int n_in,
                              void* d_out, int out_size, void* d_ws, size_t ws_size,
                              hipStream_t stream) {
    (void)in_sizes; (void)n_in; (void)out_size; (void)ws_size;
    const float* x = (const float*)d_in[0];
    const float* edge_attr = (const float*)d_in[1];
    const int* edge_index = (const int*)d_in[2];
    const float* node_w = (const float*)d_in[4];
    const float* node_b = (const float*)d_in[5];
    const float* edge_w = (const float*)d_in[6];
    const float* edge_b = (const float*)d_in[7];
    const float* gine_w1 = (const float*)d_in[8];
    const float* gine_b1 = (const float*)d_in[9];
    const float* gine_w2 = (const float*)d_in[10];
    const float* gine_b2 = (const float*)d_in[11];
    const float* attn_in_w = (const float*)d_in[12];
    const float* attn_in_b = (const float*)d_in[13];
    const float* attn_out_w = (const float*)d_in[14];
    const float* attn_out_b = (const float*)d_in[15];
    const float* mlp_w1 = (const float*)d_in[16];
    const float* mlp_b1 = (const float*)d_in[17];
    const float* mlp_w2 = (const float*)d_in[18];
    const float* mlp_b2 = (const float*)d_in[19];
    const float* bn_g = (const float*)d_in[20];
    const float* bn_bb = (const float*)d_in[21];
    const float* bn_m = (const float*)d_in[22];
    const float* bn_v = (const float*)d_in[23];
    const float* head_w1 = (const float*)d_in[24];
    const float* head_b1 = (const float*)d_in[25];
    const float* head_w2 = (const float*)d_in[26];
    const float* head_b2 = (const float*)d_in[27];
    const float* head_w3 = (const float*)d_in[28];
    const float* head_b3 = (const float*)d_in[29];

    char* ws = (char*)d_ws;
    size_t off = 0;
    auto alloc = [&](size_t bytes) {
        size_t r = off;
        off = (off + bytes + 255) & ~(size_t)255;
        return r;
    };
    const size_t NC = (size_t)NODES * CHN;
    float* h_f32 = (float*)(ws + alloc(NC * 4));
    u16* h_hi = (u16*)(ws + alloc(NC * 2));
    u16* h_lo = (u16*)(ws + alloc(NC * 2));
    u16* x_hi = (u16*)(ws + alloc((size_t)NODES * 64 * 2));
    u16* x_lo = (u16*)(ws + alloc((size_t)NODES * 64 * 2));
    u16* zao_hi = (u16*)(ws + alloc(NC * 2));   // z1 / ao reuse
    u16* zao_lo = (u16*)(ws + alloc(NC * 2));
    float* h1_f32 = (float*)(ws + alloc(NC * 4));
    u16* q_hi = (u16*)(ws + alloc(NC * 2));
    u16* q_lo = (u16*)(ws + alloc(NC * 2));
    u16* kk_hi = (u16*)(ws + alloc(NC * 2));
    u16* kk_lo = (u16*)(ws + alloc(NC * 2));
    u16* vt_hi = (u16*)(ws + alloc(NC * 2));
    float* out_f32 = (float*)(ws + alloc(NC * 4));
    u16* out_hi = (u16*)(ws + alloc(NC * 2));
    u16* out_lo = (u16*)(ws + alloc(NC * 2));
    float* pool = (float*)(ws + alloc(NG * CHN * 4));
    u16* node_w_hi = (u16*)(ws + alloc(CHN * 64 * 2));
    u16* node_w_lo = (u16*)(ws + alloc(CHN * 64 * 2));
    u16* gw1_hi = (u16*)(ws + alloc((size_t)NLAYER * CHN * CHN * 2));
    u16* gw1_lo = (u16*)(ws + alloc((size_t)NLAYER * CHN * CHN * 2));
    u16* gw2_hi = (u16*)(ws + alloc((size_t)NLAYER * CHN * CHN * 2));
    u16* gw2_lo = (u16*)(ws + alloc((size_t)NLAYER * CHN * CHN * 2));
    u16* aiw_hi = (u16*)(ws + alloc((size_t)NLAYER * 3 * CHN * CHN * 2));
    u16* aiw_lo = (u16*)(ws + alloc((size_t)NLAYER * 3 * CHN * CHN * 2));
    u16* aow_hi = (u16*)(ws + alloc((size_t)NLAYER * CHN * CHN * 2));
    u16* aow_lo = (u16*)(ws + alloc((size_t)NLAYER * CHN * CHN * 2));
    u16* mw1_hi = (u16*)(ws + alloc((size_t)NLAYER * 2 * CHN * CHN * 2));
    u16* mw1_lo = (u16*)(ws + alloc((size_t)NLAYER * 2 * CHN * CHN * 2));
    u16* mw2_hi = (u16*)(ws + alloc((size_t)NLAYER * 2 * CHN * CHN * 2));
    u16* mw2_lo = (u16*)(ws + alloc((size_t)NLAYER * 2 * CHN * CHN * 2));
    float* bn_scale = (float*)(ws + alloc(NLAYER * 3 * CHN * 4));
    float* bn_shift = (float*)(ws + alloc(NLAYER * 3 * CHN * 4));
    u32* counts = (u32*)(ws + alloc(NODES * 4));
    u32* offsets = (u32*)(ws + alloc((NODES + 1) * 4));
    u32* cursor = (u32*)(ws + alloc(NODES * 4));
    int* csr_src = (int*)(ws + alloc((size_t)NEDGE * 4));
    float* csr_a = (float*)(ws + alloc((size_t)NEDGE * 4));

    const int* e_src = edge_index;
    const int* e_dst = edge_index + NEDGE;

    // one fused split launch for all 8 fp32->hi/lo conversions
    {
        SplitJobs j;
        const float* srcs[8] = {x, node_w, gine_w1, gine_w2, attn_in_w,
                                attn_out_w, mlp_w1, mlp_w2};
        u16* his[8] = {x_hi, node_w_hi, gw1_hi, gw2_hi, aiw_hi, aow_hi, mw1_hi, mw2_hi};
        u16* los[8] = {x_lo, node_w_lo, gw1_lo, gw2_lo, aiw_lo, aow_lo, mw1_lo, mw2_lo};
        int ns[8] = {NODES * 64, CHN * 64, NLAYER * CHN * CHN, NLAYER * CHN * CHN,
                     NLAYER * 3 * CHN * CHN, NLAYER * CHN * CHN,
                     NLAYER * 2 * CHN * CHN, NLAYER * 2 * CHN * CHN};
        int cum = 0;
        for (int i = 0; i < 8; ++i) {
            j.src[i] = srcs[i]; j.hi[i] = his[i]; j.lo[i] = los[i];
            cum += ns[i] / 256;
            j.blk_end[i] = cum;
        }
        k_split8<<<dim3(cum), dim3(256), 0, stream>>>(j);
    }

    k_bnprep<<<dim3((NLAYER * 3 * CHN + 255) / 256), dim3(256), 0, stream>>>(
        bn_g, bn_bb, bn_m, bn_v, bn_scale, bn_shift);

    k_zero_u32<<<dim3(NODES / 256), dim3(256), 0, stream>>>(counts, NODES);
    k_count<<<dim3(NEDGE / 256), dim3(256), 0, stream>>>(e_dst, counts);
    k_scan<<<dim3(1), dim3(256), 0, stream>>>(counts, offsets, cursor);
    k_fill<<<dim3(NEDGE / 256), dim3(256), 0, stream>>>(e_src, e_dst, edge_attr,
                                                        cursor, csr_src, csr_a);

    // node projection: h = x @ node_w^T + node_b
    k_gemm<<<dim3(NODES / 64, CHN / 32), dim3(256), 0, stream>>>(
        x_hi, x_lo, node_w_hi, node_w_lo, node_b, nullptr, nullptr, nullptr,
        nullptr, h_f32, h_hi, h_lo, 64, CHN, 0);

    for (int l = 0; l < NLAYER; ++l) {
        size_t wo = (size_t)l * CHN * CHN;
        const float* sc0 = bn_scale + (l * 3 + 0) * CHN;
        const float* sh0 = bn_shift + (l * 3 + 0) * CHN;
        const float* sc1 = bn_scale + (l * 3 + 1) * CHN;
        const float* sh1 = bn_shift + (l * 3 + 1) * CHN;
        const float* sc2 = bn_scale + (l * 3 + 2) * CHN;
        const float* sh2 = bn_shift + (l * 3 + 2) * CHN;

        // GINE aggregate -> z (hi/lo)
        k_agg<<<dim3(NODES), dim3(64), 0, stream>>>(h_hi, h_f32, offsets, csr_src,
                                                    csr_a, edge_w, edge_b,
                                                    zao_hi, zao_lo);
        // fused GINE MLP: h1 = bn(relu(z@w1+b1)@w2+b2 + h)
        k_gine<<<dim3(NODES / 64), dim3(256), 0, stream>>>(
            zao_hi, zao_lo, gw1_hi + wo, gw1_lo + wo, gine_b1 + l * CHN,
            gw2_hi + wo, gw2_lo + wo, gine_b2 + l * CHN, h_f32, sc0, sh0, h1_f32);
        // attention
        k_qkv<<<dim3(NODES / 64, 12), dim3(256), 0, stream>>>(
            h_hi, h_lo, aiw_hi + wo * 3, aiw_lo + wo * 3, attn_in_b + l * 3 * CHN,
            q_hi, q_lo, kk_hi, kk_lo, vt_hi);
        k_attn<<<dim3(NPGC / 64, NG * NHEAD), dim3(256), 0, stream>>>(
            q_hi, q_lo, kk_hi, kk_lo, vt_hi, zao_hi, zao_lo);
        // out projection: out = bn(ao@W+b + h) + h1
        k_gemm<<<dim3(NODES / 64, CHN / 32), dim3(256), 0, stream>>>(
            zao_hi, zao_lo, aow_hi + wo, aow_lo + wo, attn_out_b + l * CHN,
            h_f32, sc1, sh1, h1_f32, out_f32, out_hi, out_lo, CHN, CHN, 0);
        // fused FFN: h = bn(relu(out@w1+b1)@w2+b2 + out)
        k_ffn<<<dim3(NODES / 32), dim3(128), 0, stream>>>(
            out_hi, out_lo, mw1_hi + wo * 2, mw1_lo + wo * 2, mlp_b1 + l * 2 * CHN,
            mw2_hi + wo * 2, mw2_lo + wo * 2, mlp_b2 + l * CHN, out_f32, sc2, sh2,
            h_f32, h_hi, h_lo);
    }

    k_pool<<<dim3(NG), dim3(CHN), 0, stream>>>(h_f32, pool);
    k_head<<<dim3(1), dim3(256), 0, stream>>>(pool, head_w1, head_b1, head_w2,
                                              head_b2, head_w3, head_b3,
                                              (float*)d_out);
}

// Round 6
// 957.181 us; speedup vs baseline: 1.2007x; 1.0800x over previous
//
#include <hip/hip_runtime.h>
#include <hip/hip_bf16.h>

typedef __attribute__((ext_vector_type(8))) short short8;
typedef __attribute__((ext_vector_type(4))) float f32x4;
typedef __attribute__((ext_vector_type(2))) unsigned int u32x2;
typedef unsigned short u16;
typedef unsigned int u32;
typedef unsigned long long u64;

#define NODES 16384
#define CHN 128
#define NEDGE 524288
#define NG 16
#define NPGC 1024
#define NHEAD 4
#define HDIM 32
#define NLAYER 4

#if __has_builtin(__builtin_amdgcn_exp2f)
#define EXP2(x) __builtin_amdgcn_exp2f(x)
#else
#define EXP2(x) exp2f(x)
#endif

__device__ __forceinline__ float bf2f(u16 u) {
    union { u32 u; float f; } c; c.u = ((u32)u) << 16; return c.f;
}
__device__ __forceinline__ u16 f2bf(float f) {
    union { float f; u32 u; } c; c.f = f;
    u32 r = c.u + 0x7fffu + ((c.u >> 16) & 1u);
    return (u16)(r >> 16);
}
__device__ __forceinline__ void fsplit(float f, u16& hi, u16& lo) {
    u16 h = f2bf(f);
    hi = h;
    lo = f2bf(f - bf2f(h));
}
__device__ __forceinline__ u32 cvtpk_bf16(float a, float b) {
    u32 r;
    asm("v_cvt_pk_bf16_f32 %0, %1, %2" : "=v"(r) : "v"(a), "v"(b));
    return r;
}

#define MFMA16(a, b, c) __builtin_amdgcn_mfma_f32_16x16x32_bf16((a), (b), (c), 0, 0, 0)

__device__ __forceinline__ short8 ld_frag(const u16* p) {
    return *reinterpret_cast<const short8*>(p);
}

// ---------------- setup kernels ----------------

struct SplitJobs {
    const float* src[8];
    u16* hi[8];
    u16* lo[8];
    int blk_end[8];
};

__global__ void k_split8(SplitJobs jobs) {
    int b = blockIdx.x;
    int seg = 0;
    while (b >= jobs.blk_end[seg]) ++seg;
    int base = seg ? jobs.blk_end[seg - 1] : 0;
    int i = (b - base) * 256 + threadIdx.x;
    u16 h, l;
    fsplit(jobs.src[seg][i], h, l);
    jobs.hi[seg][i] = h;
    jobs.lo[seg][i] = l;
}

__global__ void k_bnprep(const float* __restrict__ g, const float* __restrict__ b,
                         const float* __restrict__ m, const float* __restrict__ v,
                         float* __restrict__ scale, float* __restrict__ shift) {
    int i = blockIdx.x * 256 + threadIdx.x;
    if (i < NLAYER * 3 * CHN) {
        float s = g[i] * rsqrtf(v[i] + 1e-5f);
        scale[i] = s;
        shift[i] = b[i] - m[i] * s;
    }
}

__global__ void k_zero_u32(u32* __restrict__ p, int n) {
    int i = blockIdx.x * 256 + threadIdx.x;
    if (i < n) p[i] = 0u;
}

__global__ void k_count(const int* __restrict__ dst, u32* __restrict__ counts) {
    int e = blockIdx.x * 256 + threadIdx.x;
    if (e < NEDGE) atomicAdd(&counts[dst[e]], 1u);
}

__global__ void k_scan(const u32* __restrict__ counts, u32* __restrict__ offsets,
                       u32* __restrict__ cursor) {
    __shared__ u32 part[256];
    int t = threadIdx.x;
    int base = t * 64;
    u32 s = 0;
    for (int i = 0; i < 64; ++i) s += counts[base + i];
    part[t] = s;
    __syncthreads();
    for (int off = 1; off < 256; off <<= 1) {
        u32 val = (t >= off) ? part[t - off] : 0u;
        __syncthreads();
        part[t] += val;
        __syncthreads();
    }
    u32 run = (t == 0) ? 0u : part[t - 1];
    for (int i = 0; i < 64; ++i) {
        offsets[base + i] = run;
        cursor[base + i] = run;
        run += counts[base + i];
    }
    if (t == 255) offsets[NODES] = run;
}

__global__ void k_fill(const int* __restrict__ src, const int* __restrict__ dst,
                       const float* __restrict__ eattr, u32* __restrict__ cursor,
                       int* __restrict__ csr_src, float* __restrict__ csr_a) {
    int e = blockIdx.x * 256 + threadIdx.x;
    if (e >= NEDGE) return;
    int d = dst[e];
    u32 p = atomicAdd(&cursor[d], 1u);
    csr_src[p] = src[e];
    csr_a[p] = eattr[e];
}

// ------ GINE aggregation, software-pipelined gather ------

__global__ __launch_bounds__(64) void k_agg(
    const u16* __restrict__ h_hi, const float* __restrict__ h_f32,
    const u32* __restrict__ offsets, const int* __restrict__ csr_src,
    const float* __restrict__ csr_a, const float* __restrict__ ew,
    const float* __restrict__ eb, u16* __restrict__ z_hi, u16* __restrict__ z_lo) {
    int node = blockIdx.x;
    int t = threadIdx.x;
    int c0 = t * 2;
    float w0 = ew[c0], w1 = ew[c0 + 1];
    float b0 = eb[c0], b1 = eb[c0 + 1];
    u32 beg = offsets[node], end = offsets[node + 1];
    float acc0 = 0.f, acc1 = 0.f;
    u32 n = end - beg;
    if (n) {
        // 2-deep pipeline: idx prefetch 2 ahead, gather 1 ahead
        int sa = csr_src[beg];
        float aa = csr_a[beg];
        u32 ua = *reinterpret_cast<const u32*>(h_hi + (size_t)sa * CHN + c0);
        u32 j1 = (n > 1) ? beg + 1 : beg;
        int sb = csr_src[j1];
        float ab = csr_a[j1];
        for (u32 i = 0; i < n; ++i) {
            u32 jn = beg + i + 2;
            jn = jn < end ? jn : end - 1;
            int sc2 = csr_src[jn];
            float ac = csr_a[jn];
            u32 ub = *reinterpret_cast<const u32*>(h_hi + (size_t)sb * CHN + c0);
            float f0 = bf2f((u16)(ua & 0xffffu));
            float f1 = bf2f((u16)(ua >> 16));
            acc0 += fmaxf(f0 + aa * w0 + b0, 0.f);
            acc1 += fmaxf(f1 + aa * w1 + b1, 0.f);
            ua = ub; aa = ab;
            sb = sc2; ab = ac;
        }
    }
    size_t idx = (size_t)node * CHN + c0;
    float z0 = h_f32[idx] + acc0;
    float z1v = h_f32[idx + 1] + acc1;
    u16 h, l;
    fsplit(z0, h, l); z_hi[idx] = h; z_lo[idx] = l;
    fsplit(z1v, h, l); z_hi[idx + 1] = h; z_lo[idx + 1] = l;
}

// ------ split GEMM (16x32 wave tile) — used for node projection ------

__global__ __launch_bounds__(256) void k_gemm(
    const u16* __restrict__ Ahi, const u16* __restrict__ Alo,
    const u16* __restrict__ Whi, const u16* __restrict__ Wlo,
    const float* __restrict__ bias, float* __restrict__ out_f32,
    u16* __restrict__ out_hi, u16* __restrict__ out_lo, int K, int Nc) {
    int tid = threadIdx.x;
    int wave = tid >> 6, lane = tid & 63;
    int lr = lane & 15, lg = lane >> 4;
    int r0 = blockIdx.x * 64 + wave * 16;
    int nb = blockIdx.y * 32;
    f32x4 acc[2] = {};
    size_t arow = (size_t)(r0 + lr) * K + lg * 8;
    for (int ks = 0; ks < K; ks += 32) {
        short8 ah = ld_frag(Ahi + arow + ks);
        short8 al = ld_frag(Alo + arow + ks);
#pragma unroll
        for (int n = 0; n < 2; ++n) {
            size_t wrow = (size_t)(nb + n * 16 + lr) * K + ks + lg * 8;
            short8 wh = ld_frag(Whi + wrow);
            short8 wl = ld_frag(Wlo + wrow);
            acc[n] = MFMA16(ah, wh, acc[n]);
            acc[n] = MFMA16(al, wh, acc[n]);
            acc[n] = MFMA16(ah, wl, acc[n]);
        }
    }
#pragma unroll
    for (int n = 0; n < 2; ++n) {
        int col = nb + n * 16 + lr;
        float bs = bias[col];
#pragma unroll
        for (int r = 0; r < 4; ++r) {
            int row = r0 + lg * 4 + r;
            size_t oidx = (size_t)row * Nc + col;
            float v = acc[n][r] + bs;
            out_f32[oidx] = v;
            u16 hh, ll;
            fsplit(v, hh, ll);
            out_hi[oidx] = hh; out_lo[oidx] = ll;
        }
    }
}

// ---- fused GINE MLP: h1 = bn(relu(z@W1+b1)@W2 + b2 + h) ----

__global__ __launch_bounds__(256) void k_gine(
    const u16* __restrict__ zhi, const u16* __restrict__ zlo,
    const u16* __restrict__ w1hi, const u16* __restrict__ w1lo,
    const float* __restrict__ b1,
    const u16* __restrict__ w2hi, const u16* __restrict__ w2lo,
    const float* __restrict__ b2, const float* __restrict__ resid,
    const float* __restrict__ bnsc, const float* __restrict__ bnsh,
    float* __restrict__ h1out) {
    __shared__ __align__(16) u16 t_hi[64][136];
    __shared__ __align__(16) u16 t_lo[64][136];
    int tid = threadIdx.x;
    int wave = tid >> 6, lane = tid & 63;
    int lr = lane & 15, lg = lane >> 4;
    int r0 = blockIdx.x * 64 + wave * 16;
    {
        f32x4 acc[8] = {};
        size_t arow = (size_t)(r0 + lr) * CHN + lg * 8;
        for (int ks = 0; ks < CHN; ks += 32) {
            short8 ah = ld_frag(zhi + arow + ks);
            short8 al = ld_frag(zlo + arow + ks);
#pragma unroll
            for (int n = 0; n < 8; ++n) {
                size_t wrow = (size_t)(n * 16 + lr) * CHN + ks + lg * 8;
                short8 wh = ld_frag(w1hi + wrow);
                short8 wl = ld_frag(w1lo + wrow);
                acc[n] = MFMA16(ah, wh, acc[n]);
                acc[n] = MFMA16(al, wh, acc[n]);
                acc[n] = MFMA16(ah, wl, acc[n]);
            }
        }
#pragma unroll
        for (int n = 0; n < 8; ++n) {
            float bs = b1[n * 16 + lr];
#pragma unroll
            for (int r = 0; r < 4; ++r) {
                float v = fmaxf(acc[n][r] + bs, 0.f);
                u16 hh, ll;
                fsplit(v, hh, ll);
                int row = wave * 16 + lg * 4 + r;
                t_hi[row][n * 16 + lr] = hh;
                t_lo[row][n * 16 + lr] = ll;
            }
        }
    }
    __syncthreads();
    {
        f32x4 acc[8] = {};
        for (int ks = 0; ks < CHN; ks += 32) {
            short8 ah = ld_frag(&t_hi[wave * 16 + lr][ks + lg * 8]);
            short8 al = ld_frag(&t_lo[wave * 16 + lr][ks + lg * 8]);
#pragma unroll
            for (int n = 0; n < 8; ++n) {
                size_t wrow = (size_t)(n * 16 + lr) * CHN + ks + lg * 8;
                short8 wh = ld_frag(w2hi + wrow);
                short8 wl = ld_frag(w2lo + wrow);
                acc[n] = MFMA16(ah, wh, acc[n]);
                acc[n] = MFMA16(al, wh, acc[n]);
                acc[n] = MFMA16(ah, wl, acc[n]);
            }
        }
#pragma unroll
        for (int n = 0; n < 8; ++n) {
            int col = n * 16 + lr;
            float bs = b2[col], sc = bnsc[col], sh = bnsh[col];
#pragma unroll
            for (int r = 0; r < 4; ++r) {
                int row = r0 + lg * 4 + r;
                size_t oidx = (size_t)row * CHN + col;
                float v = acc[n][r] + bs + resid[oidx];
                h1out[oidx] = v * sc + sh;
            }
        }
    }
}

// ---- fused out-proj + FFN: out = bn1(ao@AW+ab + h) + h1; h = bn2(relu(out@W1+b1)@W2+b2 + out)
// 32 rows/block, 4 waves: half = wave>>1 selects 16 rows, sub = wave&1 selects col half.

__global__ __launch_bounds__(256) void k_outffn(
    const u16* __restrict__ aoh, const u16* __restrict__ aol,
    const u16* __restrict__ awh, const u16* __restrict__ awl,
    const float* __restrict__ ab, const float* __restrict__ hres,
    const float* __restrict__ sc1, const float* __restrict__ sh1,
    const float* __restrict__ h1res,
    const u16* __restrict__ w1h, const u16* __restrict__ w1l,
    const float* __restrict__ b1,
    const u16* __restrict__ w2h, const u16* __restrict__ w2l,
    const float* __restrict__ b2,
    const float* __restrict__ sc2, const float* __restrict__ sh2,
    float* __restrict__ hf, u16* __restrict__ hhi, u16* __restrict__ hlo) {
    __shared__ __align__(16) u16 o_hi[32][136];
    __shared__ __align__(16) u16 o_lo[32][136];
    __shared__ __align__(16) u16 t_hi[32][264];
    __shared__ __align__(16) u16 t_lo[32][264];
    int tid = threadIdx.x;
    int wave = tid >> 6, lane = tid & 63;
    int lr = lane & 15, lg = lane >> 4;
    int half = wave >> 1, sub = wave & 1;
    int r0 = blockIdx.x * 32 + half * 16;
    int rl0 = half * 16;
    // stage A: out-proj, 16 rows x 64 cols
    {
        f32x4 acc[4] = {};
        size_t arow = (size_t)(r0 + lr) * CHN + lg * 8;
        for (int ks = 0; ks < CHN; ks += 32) {
            short8 ah = ld_frag(aoh + arow + ks);
            short8 al = ld_frag(aol + arow + ks);
#pragma unroll
            for (int n = 0; n < 4; ++n) {
                size_t wrow = (size_t)(sub * 64 + n * 16 + lr) * CHN + ks + lg * 8;
                short8 wh = ld_frag(awh + wrow);
                short8 wl = ld_frag(awl + wrow);
                acc[n] = MFMA16(ah, wh, acc[n]);
                acc[n] = MFMA16(al, wh, acc[n]);
                acc[n] = MFMA16(ah, wl, acc[n]);
            }
        }
#pragma unroll
        for (int n = 0; n < 4; ++n) {
            int col = sub * 64 + n * 16 + lr;
            float bs = ab[col], sc = sc1[col], sh = sh1[col];
#pragma unroll
            for (int r = 0; r < 4; ++r) {
                int row = r0 + lg * 4 + r;
                int rl = rl0 + lg * 4 + r;
                size_t oidx = (size_t)row * CHN + col;
                float v = (acc[n][r] + bs + hres[oidx]) * sc + sh + h1res[oidx];
                u16 hh, ll;
                fsplit(v, hh, ll);
                o_hi[rl][col] = hh; o_lo[rl][col] = ll;
            }
        }
    }
    __syncthreads();
    // stage B: FFN up, 16 rows x 128 cols (of 256)
    {
        f32x4 acc[8] = {};
        for (int ks = 0; ks < CHN; ks += 32) {
            short8 ah = ld_frag(&o_hi[rl0 + lr][ks + lg * 8]);
            short8 al = ld_frag(&o_lo[rl0 + lr][ks + lg * 8]);
#pragma unroll
            for (int n = 0; n < 8; ++n) {
                size_t wrow = (size_t)(sub * 128 + n * 16 + lr) * CHN + ks + lg * 8;
                short8 wh = ld_frag(w1h + wrow);
                short8 wl = ld_frag(w1l + wrow);
                acc[n] = MFMA16(ah, wh, acc[n]);
                acc[n] = MFMA16(al, wh, acc[n]);
                acc[n] = MFMA16(ah, wl, acc[n]);
            }
        }
#pragma unroll
        for (int n = 0; n < 8; ++n) {
            int col = sub * 128 + n * 16 + lr;
            float bs = b1[col];
#pragma unroll
            for (int r = 0; r < 4; ++r) {
                float v = fmaxf(acc[n][r] + bs, 0.f);
                u16 hh, ll;
                fsplit(v, hh, ll);
                int rl = rl0 + lg * 4 + r;
                t_hi[rl][col] = hh; t_lo[rl][col] = ll;
            }
        }
    }
    __syncthreads();
    // stage C: FFN down, K=256, 16 rows x 64 cols
    {
        f32x4 acc[4] = {};
        for (int ks = 0; ks < 2 * CHN; ks += 32) {
            short8 ah = ld_frag(&t_hi[rl0 + lr][ks + lg * 8]);
            short8 al = ld_frag(&t_lo[rl0 + lr][ks + lg * 8]);
#pragma unroll
            for (int n = 0; n < 4; ++n) {
                size_t wrow = (size_t)(sub * 64 + n * 16 + lr) * 2 * CHN + ks + lg * 8;
                short8 wh = ld_frag(w2h + wrow);
                short8 wl = ld_frag(w2l + wrow);
                acc[n] = MFMA16(ah, wh, acc[n]);
                acc[n] = MFMA16(al, wh, acc[n]);
                acc[n] = MFMA16(ah, wl, acc[n]);
            }
        }
#pragma unroll
        for (int n = 0; n < 4; ++n) {
            int col = sub * 64 + n * 16 + lr;
            float bs = b2[col], sc = sc2[col], sh = sh2[col];
#pragma unroll
            for (int r = 0; r < 4; ++r) {
                int row = r0 + lg * 4 + r;
                int rl = rl0 + lg * 4 + r;
                size_t oidx = (size_t)row * CHN + col;
                float ores = bf2f(o_hi[rl][col]) + bf2f(o_lo[rl][col]);
                float v = (acc[n][r] + bs + ores) * sc + sh;
                hf[oidx] = v;
                u16 hh, ll;
                fsplit(v, hh, ll);
                hhi[oidx] = hh; hlo[oidx] = ll;
            }
        }
    }
}

// -------- QKV GEMM with head-split hi/lo store (V transposed, hi-only) --------

__global__ __launch_bounds__(256) void k_qkv(
    const u16* __restrict__ Ahi, const u16* __restrict__ Alo,
    const u16* __restrict__ Whi, const u16* __restrict__ Wlo,
    const float* __restrict__ bias,
    u16* __restrict__ q_hi, u16* __restrict__ q_lo,
    u16* __restrict__ k_hi, u16* __restrict__ k_lo,
    u16* __restrict__ vt_hi) {
    const int K = 128;
    int tid = threadIdx.x;
    int wave = tid >> 6, lane = tid & 63;
    int lr = lane & 15, lg = lane >> 4;
    int r0 = blockIdx.x * 64 + wave * 16;
    int nb = blockIdx.y * 32;
    f32x4 acc[2] = {};
    size_t arow = (size_t)(r0 + lr) * K + lg * 8;
    for (int ks = 0; ks < K; ks += 32) {
        short8 ah = ld_frag(Ahi + arow + ks);
        short8 al = ld_frag(Alo + arow + ks);
#pragma unroll
        for (int n = 0; n < 2; ++n) {
            size_t wrow = (size_t)(nb + n * 16 + lr) * K + ks + lg * 8;
            short8 wh = ld_frag(Whi + wrow);
            short8 wl = ld_frag(Wlo + wrow);
            acc[n] = MFMA16(ah, wh, acc[n]);
            acc[n] = MFMA16(al, wh, acc[n]);
            acc[n] = MFMA16(ah, wl, acc[n]);
        }
    }
#pragma unroll
    for (int n = 0; n < 2; ++n) {
        int col = nb + n * 16 + lr;
        int region = col >> 7;
        int c = col & 127;
        int hh = c >> 5, d = c & 31;
        float bs = bias[col];
#pragma unroll
        for (int r = 0; r < 4; ++r) {
            int row = r0 + lg * 4 + r;
            float v = acc[n][r] + bs;
            int g = row >> 10, p = row & 1023;
            size_t gh = (size_t)(g * NHEAD + hh);
            if (region == 0) {
                u16 vh, vl;
                fsplit(v, vh, vl);
                size_t o = (gh * NPGC + p) * HDIM + d;
                q_hi[o] = vh; q_lo[o] = vl;
            } else if (region == 1) {
                u16 vh, vl;
                fsplit(v, vh, vl);
                size_t o = (gh * NPGC + p) * HDIM + d;
                k_hi[o] = vh; k_lo[o] = vl;
            } else {
                vt_hi[(gh * HDIM + d) * NPGC + p] = f2bf(v);
            }
        }
    }
}

// --- flash attention, swapped QK^T, DUAL-STREAM: each wave does 2 q-tiles over shared K/V.
// Schedule per chunk: QK_A,QK_B -> SM_A (overlaps QK_B drain) -> PV_A -> SM_B (overlaps
// PV_A drain) -> PV_B. K and V fragments loaded once for both streams.

__global__ __launch_bounds__(128) void k_attn(
    const u16* __restrict__ qhi, const u16* __restrict__ qlo,
    const u16* __restrict__ khi, const u16* __restrict__ klo,
    const u16* __restrict__ vthi,
    u16* __restrict__ aohi, u16* __restrict__ aolo) {
    __shared__ __align__(16) u16 plds[2][16][136];
    int tid = threadIdx.x;
    int wave = tid >> 6, lane = tid & 63;
    int lr = lane & 15, lg = lane >> 4;
    int gh = blockIdx.y;
    int qA = blockIdx.x * 64 + wave * 32;
    int qB = qA + 16;
    size_t base = (size_t)gh * NPGC * HDIM;
    size_t vbase = (size_t)gh * HDIM * NPGC;
    short8 qhA = ld_frag(qhi + base + (size_t)(qA + lr) * HDIM + lg * 8);
    short8 qlA = ld_frag(qlo + base + (size_t)(qA + lr) * HDIM + lg * 8);
    short8 qhB = ld_frag(qhi + base + (size_t)(qB + lr) * HDIM + lg * 8);
    short8 qlB = ld_frag(qlo + base + (size_t)(qB + lr) * HDIM + lg * 8);
    const u16* Kh = khi + base;
    const u16* Kl = klo + base;
    const u16* Vh = vthi + vbase;
    f32x4 o0A = {}, o1A = {}, o0B = {}, o1B = {};
    float mA = -1e30f, lA = 0.f, mB = -1e30f, lB = 0.f;
    const float cl = 0.2550348281f;   // log2(e)/sqrt(HDIM)
    const f32x4 zero = {};
    for (int kv = 0; kv < NPGC; kv += 128) {
        f32x4 sA[8], sB[8];
#pragma unroll
        for (int f = 0; f < 8; ++f) {
            size_t kr = (size_t)(kv + f * 16 + lr) * HDIM + lg * 8;
            short8 kh = ld_frag(Kh + kr);
            short8 kl2 = ld_frag(Kl + kr);
            sA[f] = MFMA16(kh, qlA, MFMA16(kl2, qhA, MFMA16(kh, qhA, zero)));
            sB[f] = MFMA16(kh, qlB, MFMA16(kl2, qhB, MFMA16(kh, qhB, zero)));
        }
        // ---- softmax A (overlaps QK_B MFMA drain) ----
        {
            f32x4 mm = sA[0];
#pragma unroll
            for (int f = 1; f < 8; ++f)
#pragma unroll
                for (int i = 0; i < 4; ++i) mm[i] = fmaxf(mm[i], sA[f][i]);
            float mx = fmaxf(fmaxf(mm[0], mm[1]), fmaxf(mm[2], mm[3]));
            mx = fmaxf(mx, __shfl_xor(mx, 16));
            mx = fmaxf(mx, __shfl_xor(mx, 32));
            float mn = fmaxf(mA, mx);
            float mncl = mn * cl;
            float corr = EXP2((mA - mn) * cl);
            mA = mn;
#pragma unroll
            for (int f = 0; f < 8; ++f)
#pragma unroll
                for (int i = 0; i < 4; ++i) sA[f][i] = EXP2(fmaf(sA[f][i], cl, -mncl));
            f32x4 s4 = sA[0];
#pragma unroll
            for (int f = 1; f < 8; ++f)
#pragma unroll
                for (int i = 0; i < 4; ++i) s4[i] += sA[f][i];
            float ps = (s4[0] + s4[1]) + (s4[2] + s4[3]);
            ps += __shfl_xor(ps, 16);
            ps += __shfl_xor(ps, 32);
            lA = fmaf(lA, corr, ps);
#pragma unroll
            for (int i = 0; i < 4; ++i) { o0A[i] *= corr; o1A[i] *= corr; }
#pragma unroll
            for (int f = 0; f < 8; ++f) {
                u32x2 wv;
                wv[0] = cvtpk_bf16(sA[f][0], sA[f][1]);
                wv[1] = cvtpk_bf16(sA[f][2], sA[f][3]);
                *reinterpret_cast<u32x2*>(&plds[wave][lr][f * 16 + lg * 4]) = wv;
            }
        }
        // ---- PV A (V frags kept for B) ----
        short8 vs0[4], vs1[4];
#pragma unroll
        for (int kk = 0; kk < 4; ++kk) {
            short8 pf = ld_frag(&plds[wave][lr][kk * 32 + lg * 8]);
            vs0[kk] = ld_frag(Vh + (size_t)lr * NPGC + kv + kk * 32 + lg * 8);
            vs1[kk] = ld_frag(Vh + (size_t)(16 + lr) * NPGC + kv + kk * 32 + lg * 8);
            o0A = MFMA16(vs0[kk], pf, o0A);
            o1A = MFMA16(vs1[kk], pf, o1A);
        }
        // ---- softmax B (overlaps PV_A MFMA drain) ----
        {
            f32x4 mm = sB[0];
#pragma unroll
            for (int f = 1; f < 8; ++f)
#pragma unroll
                for (int i = 0; i < 4; ++i) mm[i] = fmaxf(mm[i], sB[f][i]);
            float mx = fmaxf(fmaxf(mm[0], mm[1]), fmaxf(mm[2], mm[3]));
            mx = fmaxf(mx, __shfl_xor(mx, 16));
            mx = fmaxf(mx, __shfl_xor(mx, 32));
            float mn = fmaxf(mB, mx);
            float mncl = mn * cl;
            float corr = EXP2((mB - mn) * cl);
            mB = mn;
#pragma unroll
            for (int f = 0; f < 8; ++f)
#pragma unroll
                for (int i = 0; i < 4; ++i) sB[f][i] = EXP2(fmaf(sB[f][i], cl, -mncl));
            f32x4 s4 = sB[0];
#pragma unroll
            for (int f = 1; f < 8; ++f)
#pragma unroll
                for (int i = 0; i < 4; ++i) s4[i] += sB[f][i];
            float ps = (s4[0] + s4[1]) + (s4[2] + s4[3]);
            ps += __shfl_xor(ps, 16);
            ps += __shfl_xor(ps, 32);
            lB = fmaf(lB, corr, ps);
#pragma unroll
            for (int i = 0; i < 4; ++i) { o0B[i] *= corr; o1B[i] *= corr; }
            // same-wave DS ordering: PV_A reads above complete before these writes land
#pragma unroll
            for (int f = 0; f < 8; ++f) {
                u32x2 wv;
                wv[0] = cvtpk_bf16(sB[f][0], sB[f][1]);
                wv[1] = cvtpk_bf16(sB[f][2], sB[f][3]);
                *reinterpret_cast<u32x2*>(&plds[wave][lr][f * 16 + lg * 4]) = wv;
            }
        }
        // ---- PV B ----
#pragma unroll
        for (int kk = 0; kk < 4; ++kk) {
            short8 pf = ld_frag(&plds[wave][lr][kk * 32 + lg * 8]);
            o0B = MFMA16(vs0[kk], pf, o0B);
            o1B = MFMA16(vs1[kk], pf, o1B);
        }
    }
    int g = gh >> 2, hh = gh & 3;
    {
        float inv = 1.f / lA;
        size_t obase = ((size_t)g * NPGC + qA + lr) * CHN + hh * HDIM;
        union { u16 u[4]; u64 v; } p0h, p0l, p1h, p1l;
#pragma unroll
        for (int i = 0; i < 4; ++i) {
            u16 a, b;
            fsplit(o0A[i] * inv, a, b); p0h.u[i] = a; p0l.u[i] = b;
            fsplit(o1A[i] * inv, a, b); p1h.u[i] = a; p1l.u[i] = b;
        }
        *reinterpret_cast<u64*>(aohi + obase + lg * 4) = p0h.v;
        *reinterpret_cast<u64*>(aolo + obase + lg * 4) = p0l.v;
        *reinterpret_cast<u64*>(aohi + obase + 16 + lg * 4) = p1h.v;
        *reinterpret_cast<u64*>(aolo + obase + 16 + lg * 4) = p1l.v;
    }
    {
        float inv = 1.f / lB;
        size_t obase = ((size_t)g * NPGC + qB + lr) * CHN + hh * HDIM;
        union { u16 u[4]; u64 v; } p0h, p0l, p1h, p1l;
#pragma unroll
        for (int i = 0; i < 4; ++i) {
            u16 a, b;
            fsplit(o0B[i] * inv, a, b); p0h.u[i] = a; p0l.u[i] = b;
            fsplit(o1B[i] * inv, a, b); p1h.u[i] = a; p1l.u[i] = b;
        }
        *reinterpret_cast<u64*>(aohi + obase + lg * 4) = p0h.v;
        *reinterpret_cast<u64*>(aolo + obase + lg * 4) = p0l.v;
        *reinterpret_cast<u64*>(aohi + obase + 16 + lg * 4) = p1h.v;
        *reinterpret_cast<u64*>(aolo + obase + 16 + lg * 4) = p1l.v;
    }
}

// ---------------- pooling + head MLP ----------------

__global__ __launch_bounds__(128) void k_pool(const float* __restrict__ h,
                                              float* __restrict__ pool) {
    int g = blockIdx.x, c = threadIdx.x;
    const float* p = h + (size_t)g * NPGC * CHN + c;
    float s = 0.f;
    for (int i = 0; i < NPGC; ++i) s += p[(size_t)i * CHN];
    pool[g * CHN + c] = s;
}

__global__ __launch_bounds__(256) void k_head(
    const float* __restrict__ pool, const float* __restrict__ w1,
    const float* __restrict__ b1, const float* __restrict__ w2,
    const float* __restrict__ b2, const float* __restrict__ w3,
    const float* __restrict__ b3, float* __restrict__ out) {
    __shared__ float g1[16][64];
    __shared__ float g2[16][32];
    int t = threadIdx.x;
    for (int idx = t; idx < 16 * 64; idx += 256) {
        int g = idx >> 6, n = idx & 63;
        float s = b1[n];
        for (int k = 0; k < 128; ++k) s += pool[g * 128 + k] * w1[n * 128 + k];
        g1[g][n] = fmaxf(s, 0.f);
    }
    __syncthreads();
    for (int idx = t; idx < 16 * 32; idx += 256) {
        int g = idx >> 5, n = idx & 31;
        float s = b2[n];
        for (int k = 0; k < 64; ++k) s += g1[g][k] * w2[n * 64 + k];
        g2[g][n] = fmaxf(s, 0.f);
    }
    __syncthreads();
    if (t < 16) {
        float s = b3[0];
        for (int k = 0; k < 32; ++k) s += g2[t][k] * w3[k];
        out[t] = s;
    }
}

// ---------------- host ----------------

extern "C" void kernel_launch(void* const* d_in, const int* in_sizes, int n_in,
                              void* d_out, int out_size, void* d_ws, size_t ws_size,
                              hipStream_t stream) {
    (void)in_sizes; (void)n_in; (void)out_size; (void)ws_size;
    const float* x = (const float*)d_in[0];
    const float* edge_attr = (const float*)d_in[1];
    const int* edge_index = (const int*)d_in[2];
    const float* node_w = (const float*)d_in[4];
    const float* node_b = (const float*)d_in[5];
    const float* edge_w = (const float*)d_in[6];
    const float* edge_b = (const float*)d_in[7];
    const float* gine_w1 = (const float*)d_in[8];
    const float* gine_b1 = (const float*)d_in[9];
    const float* gine_w2 = (const float*)d_in[10];
    const float* gine_b2 = (const float*)d_in[11];
    const float* attn_in_w = (const float*)d_in[12];
    const float* attn_in_b = (const float*)d_in[13];
    const float* attn_out_w = (const float*)d_in[14];
    const float* attn_out_b = (const float*)d_in[15];
    const float* mlp_w1 = (const float*)d_in[16];
    const float* mlp_b1 = (const float*)d_in[17];
    const float* mlp_w2 = (const float*)d_in[18];
    const float* mlp_b2 = (const float*)d_in[19];
    const float* bn_g = (const float*)d_in[20];
    const float* bn_bb = (const float*)d_in[21];
    const float* bn_m = (const float*)d_in[22];
    const float* bn_v = (const float*)d_in[23];
    const float* head_w1 = (const float*)d_in[24];
    const float* head_b1 = (const float*)d_in[25];
    const float* head_w2 = (const float*)d_in[26];
    const float* head_b2 = (const float*)d_in[27];
    const float* head_w3 = (const float*)d_in[28];
    const float* head_b3 = (const float*)d_in[29];

    char* ws = (char*)d_ws;
    size_t off = 0;
    auto alloc = [&](size_t bytes) {
        size_t r = off;
        off = (off + bytes + 255) & ~(size_t)255;
        return r;
    };
    const size_t NC = (size_t)NODES * CHN;
    float* h_f32 = (float*)(ws + alloc(NC * 4));
    u16* h_hi = (u16*)(ws + alloc(NC * 2));
    u16* h_lo = (u16*)(ws + alloc(NC * 2));
    u16* x_hi = (u16*)(ws + alloc((size_t)NODES * 64 * 2));
    u16* x_lo = (u16*)(ws + alloc((size_t)NODES * 64 * 2));
    u16* zao_hi = (u16*)(ws + alloc(NC * 2));
    u16* zao_lo = (u16*)(ws + alloc(NC * 2));
    float* h1_f32 = (float*)(ws + alloc(NC * 4));
    u16* q_hi = (u16*)(ws + alloc(NC * 2));
    u16* q_lo = (u16*)(ws + alloc(NC * 2));
    u16* kk_hi = (u16*)(ws + alloc(NC * 2));
    u16* kk_lo = (u16*)(ws + alloc(NC * 2));
    u16* vt_hi = (u16*)(ws + alloc(NC * 2));
    float* pool = (float*)(ws + alloc(NG * CHN * 4));
    u16* node_w_hi = (u16*)(ws + alloc(CHN * 64 * 2));
    u16* node_w_lo = (u16*)(ws + alloc(CHN * 64 * 2));
    u16* gw1_hi = (u16*)(ws + alloc((size_t)NLAYER * CHN * CHN * 2));
    u16* gw1_lo = (u16*)(ws + alloc((size_t)NLAYER * CHN * CHN * 2));
    u16* gw2_hi = (u16*)(ws + alloc((size_t)NLAYER * CHN * CHN * 2));
    u16* gw2_lo = (u16*)(ws + alloc((size_t)NLAYER * CHN * CHN * 2));
    u16* aiw_hi = (u16*)(ws + alloc((size_t)NLAYER * 3 * CHN * CHN * 2));
    u16* aiw_lo = (u16*)(ws + alloc((size_t)NLAYER * 3 * CHN * CHN * 2));
    u16* aow_hi = (u16*)(ws + alloc((size_t)NLAYER * CHN * CHN * 2));
    u16* aow_lo = (u16*)(ws + alloc((size_t)NLAYER * CHN * CHN * 2));
    u16* mw1_hi = (u16*)(ws + alloc((size_t)NLAYER * 2 * CHN * CHN * 2));
    u16* mw1_lo = (u16*)(ws + alloc((size_t)NLAYER * 2 * CHN * CHN * 2));
    u16* mw2_hi = (u16*)(ws + alloc((size_t)NLAYER * 2 * CHN * CHN * 2));
    u16* mw2_lo = (u16*)(ws + alloc((size_t)NLAYER * 2 * CHN * CHN * 2));
    float* bn_scale = (float*)(ws + alloc(NLAYER * 3 * CHN * 4));
    float* bn_shift = (float*)(ws + alloc(NLAYER * 3 * CHN * 4));
    u32* counts = (u32*)(ws + alloc(NODES * 4));
    u32* offsets = (u32*)(ws + alloc((NODES + 1) * 4));
    u32* cursor = (u32*)(ws + alloc(NODES * 4));
    int* csr_src = (int*)(ws + alloc((size_t)NEDGE * 4));
    float* csr_a = (float*)(ws + alloc((size_t)NEDGE * 4));

    const int* e_src = edge_index;
    const int* e_dst = edge_index + NEDGE;

    {
        SplitJobs j;
        const float* srcs[8] = {x, node_w, gine_w1, gine_w2, attn_in_w,
                                attn_out_w, mlp_w1, mlp_w2};
        u16* his[8] = {x_hi, node_w_hi, gw1_hi, gw2_hi, aiw_hi, aow_hi, mw1_hi, mw2_hi};
        u16* los[8] = {x_lo, node_w_lo, gw1_lo, gw2_lo, aiw_lo, aow_lo, mw1_lo, mw2_lo};
        int ns[8] = {NODES * 64, CHN * 64, NLAYER * CHN * CHN, NLAYER * CHN * CHN,
                     NLAYER * 3 * CHN * CHN, NLAYER * CHN * CHN,
                     NLAYER * 2 * CHN * CHN, NLAYER * 2 * CHN * CHN};
        int cum = 0;
        for (int i = 0; i < 8; ++i) {
            j.src[i] = srcs[i]; j.hi[i] = his[i]; j.lo[i] = los[i];
            cum += ns[i] / 256;
            j.blk_end[i] = cum;
        }
        k_split8<<<dim3(cum), dim3(256), 0, stream>>>(j);
    }

    k_bnprep<<<dim3((NLAYER * 3 * CHN + 255) / 256), dim3(256), 0, stream>>>(
        bn_g, bn_bb, bn_m, bn_v, bn_scale, bn_shift);

    k_zero_u32<<<dim3(NODES / 256), dim3(256), 0, stream>>>(counts, NODES);
    k_count<<<dim3(NEDGE / 256), dim3(256), 0, stream>>>(e_dst, counts);
    k_scan<<<dim3(1), dim3(256), 0, stream>>>(counts, offsets, cursor);
    k_fill<<<dim3(NEDGE / 256), dim3(256), 0, stream>>>(e_src, e_dst, edge_attr,
                                                        cursor, csr_src, csr_a);

    // node projection: h = x @ node_w^T + node_b
    k_gemm<<<dim3(NODES / 64, CHN / 32), dim3(256), 0, stream>>>(
        x_hi, x_lo, node_w_hi, node_w_lo, node_b, h_f32, h_hi, h_lo, 64, CHN);

    for (int l = 0; l < NLAYER; ++l) {
        size_t wo = (size_t)l * CHN * CHN;
        const float* sc0 = bn_scale + (l * 3 + 0) * CHN;
        const float* sh0 = bn_shift + (l * 3 + 0) * CHN;
        const float* sc1 = bn_scale + (l * 3 + 1) * CHN;
        const float* sh1 = bn_shift + (l * 3 + 1) * CHN;
        const float* sc2 = bn_scale + (l * 3 + 2) * CHN;
        const float* sh2 = bn_shift + (l * 3 + 2) * CHN;

        k_agg<<<dim3(NODES), dim3(64), 0, stream>>>(h_hi, h_f32, offsets, csr_src,
                                                    csr_a, edge_w, edge_b,
                                                    zao_hi, zao_lo);
        k_gine<<<dim3(NODES / 64), dim3(256), 0, stream>>>(
            zao_hi, zao_lo, gw1_hi + wo, gw1_lo + wo, gine_b1 + l * CHN,
            gw2_hi + wo, gw2_lo + wo, gine_b2 + l * CHN, h_f32, sc0, sh0, h1_f32);
        k_qkv<<<dim3(NODES / 64, 12), dim3(256), 0, stream>>>(
            h_hi, h_lo, aiw_hi + wo * 3, aiw_lo + wo * 3, attn_in_b + l * 3 * CHN,
            q_hi, q_lo, kk_hi, kk_lo, vt_hi);
        k_attn<<<dim3(NPGC / 64, NG * NHEAD), dim3(128), 0, stream>>>(
            q_hi, q_lo, kk_hi, kk_lo, vt_hi, zao_hi, zao_lo);
        k_outffn<<<dim3(NODES / 32), dim3(256), 0, stream>>>(
            zao_hi, zao_lo, aow_hi + wo, aow_lo + wo, attn_out_b + l * CHN,
            h_f32, sc1, sh1, h1_f32,
            mw1_hi + wo * 2, mw1_lo + wo * 2, mlp_b1 + l * 2 * CHN,
            mw2_hi + wo * 2, mw2_lo + wo * 2, mlp_b2 + l * CHN, sc2, sh2,
            h_f32, h_hi, h_lo);
    }

    k_pool<<<dim3(NG), dim3(CHN), 0, stream>>>(h_f32, pool);
    k_head<<<dim3(1), dim3(256), 0, stream>>>(pool, head_w1, head_b1, head_w2,
                                              head_b2, head_w3, head_b3,
                                              (float*)d_out);
}

// Round 7
// 939.390 us; speedup vs baseline: 1.2235x; 1.0189x over previous
//
#include <hip/hip_runtime.h>
#include <hip/hip_bf16.h>

typedef __attribute__((ext_vector_type(8))) short short8;
typedef __attribute__((ext_vector_type(4))) float f32x4;
typedef __attribute__((ext_vector_type(2))) unsigned int u32x2;
typedef unsigned short u16;
typedef unsigned int u32;
typedef unsigned long long u64;

#define NODES 16384
#define CHN 128
#define NEDGE 524288
#define NG 16
#define NPGC 1024
#define NHEAD 4
#define HDIM 32
#define NLAYER 4

#if __has_builtin(__builtin_amdgcn_exp2f)
#define EXP2(x) __builtin_amdgcn_exp2f(x)
#else
#define EXP2(x) exp2f(x)
#endif

__device__ __forceinline__ float bf2f(u16 u) {
    union { u32 u; float f; } c; c.u = ((u32)u) << 16; return c.f;
}
__device__ __forceinline__ u16 f2bf(float f) {
    union { float f; u32 u; } c; c.f = f;
    u32 r = c.u + 0x7fffu + ((c.u >> 16) & 1u);
    return (u16)(r >> 16);
}
__device__ __forceinline__ void fsplit(float f, u16& hi, u16& lo) {
    u16 h = f2bf(f);
    hi = h;
    lo = f2bf(f - bf2f(h));
}
__device__ __forceinline__ u32 cvtpk_bf16(float a, float b) {
    u32 r;
    asm("v_cvt_pk_bf16_f32 %0, %1, %2" : "=v"(r) : "v"(a), "v"(b));
    return r;
}

#define MFMA16(a, b, c) __builtin_amdgcn_mfma_f32_16x16x32_bf16((a), (b), (c), 0, 0, 0)

__device__ __forceinline__ short8 ld_frag(const u16* p) {
    return *reinterpret_cast<const short8*>(p);
}

// ---------------- setup kernels ----------------

struct SplitJobs {
    const float* src[8];
    u16* hi[8];
    u16* lo[8];
    int blk_end[8];
};

__global__ void k_split8(SplitJobs jobs) {
    int b = blockIdx.x;
    int seg = 0;
    while (b >= jobs.blk_end[seg]) ++seg;
    int base = seg ? jobs.blk_end[seg - 1] : 0;
    int i = (b - base) * 256 + threadIdx.x;
    u16 h, l;
    fsplit(jobs.src[seg][i], h, l);
    jobs.hi[seg][i] = h;
    jobs.lo[seg][i] = l;
}

__global__ void k_bnprep(const float* __restrict__ g, const float* __restrict__ b,
                         const float* __restrict__ m, const float* __restrict__ v,
                         float* __restrict__ scale, float* __restrict__ shift) {
    int i = blockIdx.x * 256 + threadIdx.x;
    if (i < NLAYER * 3 * CHN) {
        float s = g[i] * rsqrtf(v[i] + 1e-5f);
        scale[i] = s;
        shift[i] = b[i] - m[i] * s;
    }
}

__global__ void k_zero_u32(u32* __restrict__ p, int n) {
    int i = blockIdx.x * 256 + threadIdx.x;
    if (i < n) p[i] = 0u;
}

__global__ void k_count(const int* __restrict__ dst, u32* __restrict__ counts) {
    int e = blockIdx.x * 256 + threadIdx.x;
    if (e < NEDGE) atomicAdd(&counts[dst[e]], 1u);
}

__global__ void k_scan(const u32* __restrict__ counts, u32* __restrict__ offsets,
                       u32* __restrict__ cursor) {
    __shared__ u32 part[256];
    int t = threadIdx.x;
    int base = t * 64;
    u32 s = 0;
    for (int i = 0; i < 64; ++i) s += counts[base + i];
    part[t] = s;
    __syncthreads();
    for (int off = 1; off < 256; off <<= 1) {
        u32 val = (t >= off) ? part[t - off] : 0u;
        __syncthreads();
        part[t] += val;
        __syncthreads();
    }
    u32 run = (t == 0) ? 0u : part[t - 1];
    for (int i = 0; i < 64; ++i) {
        offsets[base + i] = run;
        cursor[base + i] = run;
        run += counts[base + i];
    }
    if (t == 255) offsets[NODES] = run;
}

__global__ void k_fill(const int* __restrict__ src, const int* __restrict__ dst,
                       const float* __restrict__ eattr, u32* __restrict__ cursor,
                       int* __restrict__ csr_src, float* __restrict__ csr_a) {
    int e = blockIdx.x * 256 + threadIdx.x;
    if (e >= NEDGE) return;
    int d = dst[e];
    u32 p = atomicAdd(&cursor[d], 1u);
    csr_src[p] = src[e];
    csr_a[p] = eattr[e];
}

// ------ GINE aggregation, software-pipelined gather ------

__global__ __launch_bounds__(64) void k_agg(
    const u16* __restrict__ h_hi, const float* __restrict__ h_f32,
    const u32* __restrict__ offsets, const int* __restrict__ csr_src,
    const float* __restrict__ csr_a, const float* __restrict__ ew,
    const float* __restrict__ eb, u16* __restrict__ z_hi, u16* __restrict__ z_lo) {
    int node = blockIdx.x;
    int t = threadIdx.x;
    int c0 = t * 2;
    float w0 = ew[c0], w1 = ew[c0 + 1];
    float b0 = eb[c0], b1 = eb[c0 + 1];
    u32 beg = offsets[node], end = offsets[node + 1];
    float acc0 = 0.f, acc1 = 0.f;
    u32 n = end - beg;
    if (n) {
        int sa = csr_src[beg];
        float aa = csr_a[beg];
        u32 ua = *reinterpret_cast<const u32*>(h_hi + (size_t)sa * CHN + c0);
        u32 j1 = (n > 1) ? beg + 1 : beg;
        int sb = csr_src[j1];
        float ab = csr_a[j1];
        for (u32 i = 0; i < n; ++i) {
            u32 jn = beg + i + 2;
            jn = jn < end ? jn : end - 1;
            int sc2 = csr_src[jn];
            float ac = csr_a[jn];
            u32 ub = *reinterpret_cast<const u32*>(h_hi + (size_t)sb * CHN + c0);
            float f0 = bf2f((u16)(ua & 0xffffu));
            float f1 = bf2f((u16)(ua >> 16));
            acc0 += fmaxf(f0 + aa * w0 + b0, 0.f);
            acc1 += fmaxf(f1 + aa * w1 + b1, 0.f);
            ua = ub; aa = ab;
            sb = sc2; ab = ac;
        }
    }
    size_t idx = (size_t)node * CHN + c0;
    float z0 = h_f32[idx] + acc0;
    float z1v = h_f32[idx + 1] + acc1;
    u16 h, l;
    fsplit(z0, h, l); z_hi[idx] = h; z_lo[idx] = l;
    fsplit(z1v, h, l); z_hi[idx + 1] = h; z_lo[idx + 1] = l;
}

// ------ split GEMM (16x32 wave tile) — used for node projection ------

__global__ __launch_bounds__(256) void k_gemm(
    const u16* __restrict__ Ahi, const u16* __restrict__ Alo,
    const u16* __restrict__ Whi, const u16* __restrict__ Wlo,
    const float* __restrict__ bias, float* __restrict__ out_f32,
    u16* __restrict__ out_hi, u16* __restrict__ out_lo, int K, int Nc) {
    int tid = threadIdx.x;
    int wave = tid >> 6, lane = tid & 63;
    int lr = lane & 15, lg = lane >> 4;
    int r0 = blockIdx.x * 64 + wave * 16;
    int nb = blockIdx.y * 32;
    f32x4 acc[2] = {};
    size_t arow = (size_t)(r0 + lr) * K + lg * 8;
    for (int ks = 0; ks < K; ks += 32) {
        short8 ah = ld_frag(Ahi + arow + ks);
        short8 al = ld_frag(Alo + arow + ks);
#pragma unroll
        for (int n = 0; n < 2; ++n) {
            size_t wrow = (size_t)(nb + n * 16 + lr) * K + ks + lg * 8;
            short8 wh = ld_frag(Whi + wrow);
            short8 wl = ld_frag(Wlo + wrow);
            acc[n] = MFMA16(ah, wh, acc[n]);
            acc[n] = MFMA16(al, wh, acc[n]);
            acc[n] = MFMA16(ah, wl, acc[n]);
        }
    }
#pragma unroll
    for (int n = 0; n < 2; ++n) {
        int col = nb + n * 16 + lr;
        float bs = bias[col];
#pragma unroll
        for (int r = 0; r < 4; ++r) {
            int row = r0 + lg * 4 + r;
            size_t oidx = (size_t)row * Nc + col;
            float v = acc[n][r] + bs;
            out_f32[oidx] = v;
            u16 hh, ll;
            fsplit(v, hh, ll);
            out_hi[oidx] = hh; out_lo[oidx] = ll;
        }
    }
}

// ---- fused GINE MLP: h1 = bn(relu(z@W1+b1)@W2 + b2 + h) ----

__global__ __launch_bounds__(256) void k_gine(
    const u16* __restrict__ zhi, const u16* __restrict__ zlo,
    const u16* __restrict__ w1hi, const u16* __restrict__ w1lo,
    const float* __restrict__ b1,
    const u16* __restrict__ w2hi, const u16* __restrict__ w2lo,
    const float* __restrict__ b2, const float* __restrict__ resid,
    const float* __restrict__ bnsc, const float* __restrict__ bnsh,
    float* __restrict__ h1out) {
    __shared__ __align__(16) u16 t_hi[64][136];
    __shared__ __align__(16) u16 t_lo[64][136];
    int tid = threadIdx.x;
    int wave = tid >> 6, lane = tid & 63;
    int lr = lane & 15, lg = lane >> 4;
    int r0 = blockIdx.x * 64 + wave * 16;
    {
        f32x4 acc[8] = {};
        size_t arow = (size_t)(r0 + lr) * CHN + lg * 8;
        for (int ks = 0; ks < CHN; ks += 32) {
            short8 ah = ld_frag(zhi + arow + ks);
            short8 al = ld_frag(zlo + arow + ks);
#pragma unroll
            for (int n = 0; n < 8; ++n) {
                size_t wrow = (size_t)(n * 16 + lr) * CHN + ks + lg * 8;
                short8 wh = ld_frag(w1hi + wrow);
                short8 wl = ld_frag(w1lo + wrow);
                acc[n] = MFMA16(ah, wh, acc[n]);
                acc[n] = MFMA16(al, wh, acc[n]);
                acc[n] = MFMA16(ah, wl, acc[n]);
            }
        }
#pragma unroll
        for (int n = 0; n < 8; ++n) {
            float bs = b1[n * 16 + lr];
#pragma unroll
            for (int r = 0; r < 4; ++r) {
                float v = fmaxf(acc[n][r] + bs, 0.f);
                u16 hh, ll;
                fsplit(v, hh, ll);
                int row = wave * 16 + lg * 4 + r;
                t_hi[row][n * 16 + lr] = hh;
                t_lo[row][n * 16 + lr] = ll;
            }
        }
    }
    __syncthreads();
    {
        f32x4 acc[8] = {};
        for (int ks = 0; ks < CHN; ks += 32) {
            short8 ah = ld_frag(&t_hi[wave * 16 + lr][ks + lg * 8]);
            short8 al = ld_frag(&t_lo[wave * 16 + lr][ks + lg * 8]);
#pragma unroll
            for (int n = 0; n < 8; ++n) {
                size_t wrow = (size_t)(n * 16 + lr) * CHN + ks + lg * 8;
                short8 wh = ld_frag(w2hi + wrow);
                short8 wl = ld_frag(w2lo + wrow);
                acc[n] = MFMA16(ah, wh, acc[n]);
                acc[n] = MFMA16(al, wh, acc[n]);
                acc[n] = MFMA16(ah, wl, acc[n]);
            }
        }
#pragma unroll
        for (int n = 0; n < 8; ++n) {
            int col = n * 16 + lr;
            float bs = b2[col], sc = bnsc[col], sh = bnsh[col];
#pragma unroll
            for (int r = 0; r < 4; ++r) {
                int row = r0 + lg * 4 + r;
                size_t oidx = (size_t)row * CHN + col;
                float v = acc[n][r] + bs + resid[oidx];
                h1out[oidx] = v * sc + sh;
            }
        }
    }
}

// ---- fused out-proj + FFN ----

__global__ __launch_bounds__(256) void k_outffn(
    const u16* __restrict__ aoh, const u16* __restrict__ aol,
    const u16* __restrict__ awh, const u16* __restrict__ awl,
    const float* __restrict__ ab, const float* __restrict__ hres,
    const float* __restrict__ sc1, const float* __restrict__ sh1,
    const float* __restrict__ h1res,
    const u16* __restrict__ w1h, const u16* __restrict__ w1l,
    const float* __restrict__ b1,
    const u16* __restrict__ w2h, const u16* __restrict__ w2l,
    const float* __restrict__ b2,
    const float* __restrict__ sc2, const float* __restrict__ sh2,
    float* __restrict__ hf, u16* __restrict__ hhi, u16* __restrict__ hlo) {
    __shared__ __align__(16) u16 o_hi[32][136];
    __shared__ __align__(16) u16 o_lo[32][136];
    __shared__ __align__(16) u16 t_hi[32][264];
    __shared__ __align__(16) u16 t_lo[32][264];
    int tid = threadIdx.x;
    int wave = tid >> 6, lane = tid & 63;
    int lr = lane & 15, lg = lane >> 4;
    int half = wave >> 1, sub = wave & 1;
    int r0 = blockIdx.x * 32 + half * 16;
    int rl0 = half * 16;
    {
        f32x4 acc[4] = {};
        size_t arow = (size_t)(r0 + lr) * CHN + lg * 8;
        for (int ks = 0; ks < CHN; ks += 32) {
            short8 ah = ld_frag(aoh + arow + ks);
            short8 al = ld_frag(aol + arow + ks);
#pragma unroll
            for (int n = 0; n < 4; ++n) {
                size_t wrow = (size_t)(sub * 64 + n * 16 + lr) * CHN + ks + lg * 8;
                short8 wh = ld_frag(awh + wrow);
                short8 wl = ld_frag(awl + wrow);
                acc[n] = MFMA16(ah, wh, acc[n]);
                acc[n] = MFMA16(al, wh, acc[n]);
                acc[n] = MFMA16(ah, wl, acc[n]);
            }
        }
#pragma unroll
        for (int n = 0; n < 4; ++n) {
            int col = sub * 64 + n * 16 + lr;
            float bs = ab[col], sc = sc1[col], sh = sh1[col];
#pragma unroll
            for (int r = 0; r < 4; ++r) {
                int row = r0 + lg * 4 + r;
                int rl = rl0 + lg * 4 + r;
                size_t oidx = (size_t)row * CHN + col;
                float v = (acc[n][r] + bs + hres[oidx]) * sc + sh + h1res[oidx];
                u16 hh, ll;
                fsplit(v, hh, ll);
                o_hi[rl][col] = hh; o_lo[rl][col] = ll;
            }
        }
    }
    __syncthreads();
    {
        f32x4 acc[8] = {};
        for (int ks = 0; ks < CHN; ks += 32) {
            short8 ah = ld_frag(&o_hi[rl0 + lr][ks + lg * 8]);
            short8 al = ld_frag(&o_lo[rl0 + lr][ks + lg * 8]);
#pragma unroll
            for (int n = 0; n < 8; ++n) {
                size_t wrow = (size_t)(sub * 128 + n * 16 + lr) * CHN + ks + lg * 8;
                short8 wh = ld_frag(w1h + wrow);
                short8 wl = ld_frag(w1l + wrow);
                acc[n] = MFMA16(ah, wh, acc[n]);
                acc[n] = MFMA16(al, wh, acc[n]);
                acc[n] = MFMA16(ah, wl, acc[n]);
            }
        }
#pragma unroll
        for (int n = 0; n < 8; ++n) {
            int col = sub * 128 + n * 16 + lr;
            float bs = b1[col];
#pragma unroll
            for (int r = 0; r < 4; ++r) {
                float v = fmaxf(acc[n][r] + bs, 0.f);
                u16 hh, ll;
                fsplit(v, hh, ll);
                int rl = rl0 + lg * 4 + r;
                t_hi[rl][col] = hh; t_lo[rl][col] = ll;
            }
        }
    }
    __syncthreads();
    {
        f32x4 acc[4] = {};
        for (int ks = 0; ks < 2 * CHN; ks += 32) {
            short8 ah = ld_frag(&t_hi[rl0 + lr][ks + lg * 8]);
            short8 al = ld_frag(&t_lo[rl0 + lr][ks + lg * 8]);
#pragma unroll
            for (int n = 0; n < 4; ++n) {
                size_t wrow = (size_t)(sub * 64 + n * 16 + lr) * 2 * CHN + ks + lg * 8;
                short8 wh = ld_frag(w2h + wrow);
                short8 wl = ld_frag(w2l + wrow);
                acc[n] = MFMA16(ah, wh, acc[n]);
                acc[n] = MFMA16(al, wh, acc[n]);
                acc[n] = MFMA16(ah, wl, acc[n]);
            }
        }
#pragma unroll
        for (int n = 0; n < 4; ++n) {
            int col = sub * 64 + n * 16 + lr;
            float bs = b2[col], sc = sc2[col], sh = sh2[col];
#pragma unroll
            for (int r = 0; r < 4; ++r) {
                int row = r0 + lg * 4 + r;
                int rl = rl0 + lg * 4 + r;
                size_t oidx = (size_t)row * CHN + col;
                float ores = bf2f(o_hi[rl][col]) + bf2f(o_lo[rl][col]);
                float v = (acc[n][r] + bs + ores) * sc + sh;
                hf[oidx] = v;
                u16 hh, ll;
                fsplit(v, hh, ll);
                hhi[oidx] = hh; hlo[oidx] = ll;
            }
        }
    }
}

// -------- QKV GEMM with head-split hi/lo store (V transposed, hi-only) --------

__global__ __launch_bounds__(256) void k_qkv(
    const u16* __restrict__ Ahi, const u16* __restrict__ Alo,
    const u16* __restrict__ Whi, const u16* __restrict__ Wlo,
    const float* __restrict__ bias,
    u16* __restrict__ q_hi, u16* __restrict__ q_lo,
    u16* __restrict__ k_hi, u16* __restrict__ k_lo,
    u16* __restrict__ vt_hi) {
    const int K = 128;
    int tid = threadIdx.x;
    int wave = tid >> 6, lane = tid & 63;
    int lr = lane & 15, lg = lane >> 4;
    int r0 = blockIdx.x * 64 + wave * 16;
    int nb = blockIdx.y * 32;
    f32x4 acc[2] = {};
    size_t arow = (size_t)(r0 + lr) * K + lg * 8;
    for (int ks = 0; ks < K; ks += 32) {
        short8 ah = ld_frag(Ahi + arow + ks);
        short8 al = ld_frag(Alo + arow + ks);
#pragma unroll
        for (int n = 0; n < 2; ++n) {
            size_t wrow = (size_t)(nb + n * 16 + lr) * K + ks + lg * 8;
            short8 wh = ld_frag(Whi + wrow);
            short8 wl = ld_frag(Wlo + wrow);
            acc[n] = MFMA16(ah, wh, acc[n]);
            acc[n] = MFMA16(al, wh, acc[n]);
            acc[n] = MFMA16(ah, wl, acc[n]);
        }
    }
#pragma unroll
    for (int n = 0; n < 2; ++n) {
        int col = nb + n * 16 + lr;
        int region = col >> 7;
        int c = col & 127;
        int hh = c >> 5, d = c & 31;
        float bs = bias[col];
#pragma unroll
        for (int r = 0; r < 4; ++r) {
            int row = r0 + lg * 4 + r;
            float v = acc[n][r] + bs;
            int g = row >> 10, p = row & 1023;
            size_t gh = (size_t)(g * NHEAD + hh);
            if (region == 0) {
                u16 vh, vl;
                fsplit(v, vh, vl);
                size_t o = (gh * NPGC + p) * HDIM + d;
                q_hi[o] = vh; q_lo[o] = vl;
            } else if (region == 1) {
                u16 vh, vl;
                fsplit(v, vh, vl);
                size_t o = (gh * NPGC + p) * HDIM + d;
                k_hi[o] = vh; k_lo[o] = vl;
            } else {
                vt_hi[(gh * HDIM + d) * NPGC + p] = f2bf(v);
            }
        }
    }
}

// --- flash attention, swapped QK^T, dual-stream, XCD-swizzled flat grid ---
// Flat block id = gh + 64*bx  =>  id % 8 == gh % 8: all 16 q-blocks of one
// gh-group land on the same XCD, so that group's K/V (~192 KB) stays L2-resident.

__global__ __launch_bounds__(128) void k_attn(
    const u16* __restrict__ qhi, const u16* __restrict__ qlo,
    const u16* __restrict__ khi, const u16* __restrict__ klo,
    const u16* __restrict__ vthi,
    u16* __restrict__ aohi, u16* __restrict__ aolo) {
    __shared__ __align__(16) u16 plds[2][16][136];
    int tid = threadIdx.x;
    int wave = tid >> 6, lane = tid & 63;
    int lr = lane & 15, lg = lane >> 4;
    int id = blockIdx.x;
    int gh = id & 63;           // g*4 + head
    int bx = id >> 6;           // q-block within the group
    int qA = bx * 64 + wave * 32;
    int qB = qA + 16;
    size_t base = (size_t)gh * NPGC * HDIM;
    size_t vbase = (size_t)gh * HDIM * NPGC;
    short8 qhA = ld_frag(qhi + base + (size_t)(qA + lr) * HDIM + lg * 8);
    short8 qlA = ld_frag(qlo + base + (size_t)(qA + lr) * HDIM + lg * 8);
    short8 qhB = ld_frag(qhi + base + (size_t)(qB + lr) * HDIM + lg * 8);
    short8 qlB = ld_frag(qlo + base + (size_t)(qB + lr) * HDIM + lg * 8);
    const u16* Kh = khi + base;
    const u16* Kl = klo + base;
    const u16* Vh = vthi + vbase;
    f32x4 o0A = {}, o1A = {}, o0B = {}, o1B = {};
    float mA = -1e30f, lA = 0.f, mB = -1e30f, lB = 0.f;
    const float cl = 0.2550348281f;   // log2(e)/sqrt(HDIM)
    const f32x4 zero = {};
    for (int kv = 0; kv < NPGC; kv += 128) {
        f32x4 sA[8], sB[8];
#pragma unroll
        for (int f = 0; f < 8; ++f) {
            size_t kr = (size_t)(kv + f * 16 + lr) * HDIM + lg * 8;
            short8 kh = ld_frag(Kh + kr);
            short8 kl2 = ld_frag(Kl + kr);
            sA[f] = MFMA16(kh, qlA, MFMA16(kl2, qhA, MFMA16(kh, qhA, zero)));
            sB[f] = MFMA16(kh, qlB, MFMA16(kl2, qhB, MFMA16(kh, qhB, zero)));
        }
        // ---- softmax A (overlaps QK_B drain) ----
        {
            f32x4 mm = sA[0];
#pragma unroll
            for (int f = 1; f < 8; ++f)
#pragma unroll
                for (int i = 0; i < 4; ++i) mm[i] = fmaxf(mm[i], sA[f][i]);
            float mx = fmaxf(fmaxf(mm[0], mm[1]), fmaxf(mm[2], mm[3]));
            mx = fmaxf(mx, __shfl_xor(mx, 16));
            mx = fmaxf(mx, __shfl_xor(mx, 32));
            float mn = fmaxf(mA, mx);
            float mncl = mn * cl;
            float corr = EXP2((mA - mn) * cl);
            mA = mn;
#pragma unroll
            for (int f = 0; f < 8; ++f)
#pragma unroll
                for (int i = 0; i < 4; ++i) sA[f][i] = EXP2(fmaf(sA[f][i], cl, -mncl));
            f32x4 s4 = sA[0];
#pragma unroll
            for (int f = 1; f < 8; ++f)
#pragma unroll
                for (int i = 0; i < 4; ++i) s4[i] += sA[f][i];
            float ps = (s4[0] + s4[1]) + (s4[2] + s4[3]);
            ps += __shfl_xor(ps, 16);
            ps += __shfl_xor(ps, 32);
            lA = fmaf(lA, corr, ps);
#pragma unroll
            for (int i = 0; i < 4; ++i) { o0A[i] *= corr; o1A[i] *= corr; }
#pragma unroll
            for (int f = 0; f < 8; ++f) {
                u32x2 wv;
                wv[0] = cvtpk_bf16(sA[f][0], sA[f][1]);
                wv[1] = cvtpk_bf16(sA[f][2], sA[f][3]);
                *reinterpret_cast<u32x2*>(&plds[wave][lr][f * 16 + lg * 4]) = wv;
            }
        }
        // ---- PV A (V frags kept for B) ----
        short8 vs0[4], vs1[4];
#pragma unroll
        for (int kk = 0; kk < 4; ++kk) {
            short8 pf = ld_frag(&plds[wave][lr][kk * 32 + lg * 8]);
            vs0[kk] = ld_frag(Vh + (size_t)lr * NPGC + kv + kk * 32 + lg * 8);
            vs1[kk] = ld_frag(Vh + (size_t)(16 + lr) * NPGC + kv + kk * 32 + lg * 8);
            o0A = MFMA16(vs0[kk], pf, o0A);
            o1A = MFMA16(vs1[kk], pf, o1A);
        }
        // ---- softmax B (overlaps PV_A drain) ----
        {
            f32x4 mm = sB[0];
#pragma unroll
            for (int f = 1; f < 8; ++f)
#pragma unroll
                for (int i = 0; i < 4; ++i) mm[i] = fmaxf(mm[i], sB[f][i]);
            float mx = fmaxf(fmaxf(mm[0], mm[1]), fmaxf(mm[2], mm[3]));
            mx = fmaxf(mx, __shfl_xor(mx, 16));
            mx = fmaxf(mx, __shfl_xor(mx, 32));
            float mn = fmaxf(mB, mx);
            float mncl = mn * cl;
            float corr = EXP2((mB - mn) * cl);
            mB = mn;
#pragma unroll
            for (int f = 0; f < 8; ++f)
#pragma unroll
                for (int i = 0; i < 4; ++i) sB[f][i] = EXP2(fmaf(sB[f][i], cl, -mncl));
            f32x4 s4 = sB[0];
#pragma unroll
            for (int f = 1; f < 8; ++f)
#pragma unroll
                for (int i = 0; i < 4; ++i) s4[i] += sB[f][i];
            float ps = (s4[0] + s4[1]) + (s4[2] + s4[3]);
            ps += __shfl_xor(ps, 16);
            ps += __shfl_xor(ps, 32);
            lB = fmaf(lB, corr, ps);
#pragma unroll
            for (int i = 0; i < 4; ++i) { o0B[i] *= corr; o1B[i] *= corr; }
#pragma unroll
            for (int f = 0; f < 8; ++f) {
                u32x2 wv;
                wv[0] = cvtpk_bf16(sB[f][0], sB[f][1]);
                wv[1] = cvtpk_bf16(sB[f][2], sB[f][3]);
                *reinterpret_cast<u32x2*>(&plds[wave][lr][f * 16 + lg * 4]) = wv;
            }
        }
        // ---- PV B ----
#pragma unroll
        for (int kk = 0; kk < 4; ++kk) {
            short8 pf = ld_frag(&plds[wave][lr][kk * 32 + lg * 8]);
            o0B = MFMA16(vs0[kk], pf, o0B);
            o1B = MFMA16(vs1[kk], pf, o1B);
        }
    }
    int g = gh >> 2, hh = gh & 3;
    {
        float inv = 1.f / lA;
        size_t obase = ((size_t)g * NPGC + qA + lr) * CHN + hh * HDIM;
        union { u16 u[4]; u64 v; } p0h, p0l, p1h, p1l;
#pragma unroll
        for (int i = 0; i < 4; ++i) {
            u16 a, b;
            fsplit(o0A[i] * inv, a, b); p0h.u[i] = a; p0l.u[i] = b;
            fsplit(o1A[i] * inv, a, b); p1h.u[i] = a; p1l.u[i] = b;
        }
        *reinterpret_cast<u64*>(aohi + obase + lg * 4) = p0h.v;
        *reinterpret_cast<u64*>(aolo + obase + lg * 4) = p0l.v;
        *reinterpret_cast<u64*>(aohi + obase + 16 + lg * 4) = p1h.v;
        *reinterpret_cast<u64*>(aolo + obase + 16 + lg * 4) = p1l.v;
    }
    {
        float inv = 1.f / lB;
        size_t obase = ((size_t)g * NPGC + qB + lr) * CHN + hh * HDIM;
        union { u16 u[4]; u64 v; } p0h, p0l, p1h, p1l;
#pragma unroll
        for (int i = 0; i < 4; ++i) {
            u16 a, b;
            fsplit(o0B[i] * inv, a, b); p0h.u[i] = a; p0l.u[i] = b;
            fsplit(o1B[i] * inv, a, b); p1h.u[i] = a; p1l.u[i] = b;
        }
        *reinterpret_cast<u64*>(aohi + obase + lg * 4) = p0h.v;
        *reinterpret_cast<u64*>(aolo + obase + lg * 4) = p0l.v;
        *reinterpret_cast<u64*>(aohi + obase + 16 + lg * 4) = p1h.v;
        *reinterpret_cast<u64*>(aolo + obase + 16 + lg * 4) = p1l.v;
    }
}

// ---------------- pooling + head MLP ----------------

// grid (NG, 8): each block sums 128 rows, atomicAdd into pool (pre-zeroed)
__global__ __launch_bounds__(128) void k_pool(const float* __restrict__ h,
                                              float* __restrict__ pool) {
    int g = blockIdx.x, sl = blockIdx.y, c = threadIdx.x;
    const float* p = h + ((size_t)g * NPGC + sl * 128) * CHN + c;
    float s = 0.f;
    for (int i = 0; i < 128; ++i) s += p[(size_t)i * CHN];
    atomicAdd(&pool[g * CHN + c], s);
}

__global__ __launch_bounds__(256) void k_head(
    const float* __restrict__ pool, const float* __restrict__ w1,
    const float* __restrict__ b1, const float* __restrict__ w2,
    const float* __restrict__ b2, const float* __restrict__ w3,
    const float* __restrict__ b3, float* __restrict__ out) {
    __shared__ float g1[16][64];
    __shared__ float g2[16][32];
    int t = threadIdx.x;
    for (int idx = t; idx < 16 * 64; idx += 256) {
        int g = idx >> 6, n = idx & 63;
        float s = b1[n];
        for (int k = 0; k < 128; ++k) s += pool[g * 128 + k] * w1[n * 128 + k];
        g1[g][n] = fmaxf(s, 0.f);
    }
    __syncthreads();
    for (int idx = t; idx < 16 * 32; idx += 256) {
        int g = idx >> 5, n = idx & 31;
        float s = b2[n];
        for (int k = 0; k < 64; ++k) s += g1[g][k] * w2[n * 64 + k];
        g2[g][n] = fmaxf(s, 0.f);
    }
    __syncthreads();
    if (t < 16) {
        float s = b3[0];
        for (int k = 0; k < 32; ++k) s += g2[t][k] * w3[k];
        out[t] = s;
    }
}

// ---------------- host ----------------

extern "C" void kernel_launch(void* const* d_in, const int* in_sizes, int n_in,
                              void* d_out, int out_size, void* d_ws, size_t ws_size,
                              hipStream_t stream) {
    (void)in_sizes; (void)n_in; (void)out_size; (void)ws_size;
    const float* x = (const float*)d_in[0];
    const float* edge_attr = (const float*)d_in[1];
    const int* edge_index = (const int*)d_in[2];
    const float* node_w = (const float*)d_in[4];
    const float* node_b = (const float*)d_in[5];
    const float* edge_w = (const float*)d_in[6];
    const float* edge_b = (const float*)d_in[7];
    const float* gine_w1 = (const float*)d_in[8];
    const float* gine_b1 = (const float*)d_in[9];
    const float* gine_w2 = (const float*)d_in[10];
    const float* gine_b2 = (const float*)d_in[11];
    const float* attn_in_w = (const float*)d_in[12];
    const float* attn_in_b = (const float*)d_in[13];
    const float* attn_out_w = (const float*)d_in[14];
    const float* attn_out_b = (const float*)d_in[15];
    const float* mlp_w1 = (const float*)d_in[16];
    const float* mlp_b1 = (const float*)d_in[17];
    const float* mlp_w2 = (const float*)d_in[18];
    const float* mlp_b2 = (const float*)d_in[19];
    const float* bn_g = (const float*)d_in[20];
    const float* bn_bb = (const float*)d_in[21];
    const float* bn_m = (const float*)d_in[22];
    const float* bn_v = (const float*)d_in[23];
    const float* head_w1 = (const float*)d_in[24];
    const float* head_b1 = (const float*)d_in[25];
    const float* head_w2 = (const float*)d_in[26];
    const float* head_b2 = (const float*)d_in[27];
    const float* head_w3 = (const float*)d_in[28];
    const float* head_b3 = (const float*)d_in[29];

    char* ws = (char*)d_ws;
    size_t off = 0;
    auto alloc = [&](size_t bytes) {
        size_t r = off;
        off = (off + bytes + 255) & ~(size_t)255;
        return r;
    };
    const size_t NC = (size_t)NODES * CHN;
    float* h_f32 = (float*)(ws + alloc(NC * 4));
    u16* h_hi = (u16*)(ws + alloc(NC * 2));
    u16* h_lo = (u16*)(ws + alloc(NC * 2));
    u16* x_hi = (u16*)(ws + alloc((size_t)NODES * 64 * 2));
    u16* x_lo = (u16*)(ws + alloc((size_t)NODES * 64 * 2));
    u16* zao_hi = (u16*)(ws + alloc(NC * 2));
    u16* zao_lo = (u16*)(ws + alloc(NC * 2));
    float* h1_f32 = (float*)(ws + alloc(NC * 4));
    u16* q_hi = (u16*)(ws + alloc(NC * 2));
    u16* q_lo = (u16*)(ws + alloc(NC * 2));
    u16* kk_hi = (u16*)(ws + alloc(NC * 2));
    u16* kk_lo = (u16*)(ws + alloc(NC * 2));
    u16* vt_hi = (u16*)(ws + alloc(NC * 2));
    float* pool = (float*)(ws + alloc(NG * CHN * 4));
    u16* node_w_hi = (u16*)(ws + alloc(CHN * 64 * 2));
    u16* node_w_lo = (u16*)(ws + alloc(CHN * 64 * 2));
    u16* gw1_hi = (u16*)(ws + alloc((size_t)NLAYER * CHN * CHN * 2));
    u16* gw1_lo = (u16*)(ws + alloc((size_t)NLAYER * CHN * CHN * 2));
    u16* gw2_hi = (u16*)(ws + alloc((size_t)NLAYER * CHN * CHN * 2));
    u16* gw2_lo = (u16*)(ws + alloc((size_t)NLAYER * CHN * CHN * 2));
    u16* aiw_hi = (u16*)(ws + alloc((size_t)NLAYER * 3 * CHN * CHN * 2));
    u16* aiw_lo = (u16*)(ws + alloc((size_t)NLAYER * 3 * CHN * CHN * 2));
    u16* aow_hi = (u16*)(ws + alloc((size_t)NLAYER * CHN * CHN * 2));
    u16* aow_lo = (u16*)(ws + alloc((size_t)NLAYER * CHN * CHN * 2));
    u16* mw1_hi = (u16*)(ws + alloc((size_t)NLAYER * 2 * CHN * CHN * 2));
    u16* mw1_lo = (u16*)(ws + alloc((size_t)NLAYER * 2 * CHN * CHN * 2));
    u16* mw2_hi = (u16*)(ws + alloc((size_t)NLAYER * 2 * CHN * CHN * 2));
    u16* mw2_lo = (u16*)(ws + alloc((size_t)NLAYER * 2 * CHN * CHN * 2));
    float* bn_scale = (float*)(ws + alloc(NLAYER * 3 * CHN * 4));
    float* bn_shift = (float*)(ws + alloc(NLAYER * 3 * CHN * 4));
    u32* counts = (u32*)(ws + alloc(NODES * 4));
    u32* offsets = (u32*)(ws + alloc((NODES + 1) * 4));
    u32* cursor = (u32*)(ws + alloc(NODES * 4));
    int* csr_src = (int*)(ws + alloc((size_t)NEDGE * 4));
    float* csr_a = (float*)(ws + alloc((size_t)NEDGE * 4));

    const int* e_src = edge_index;
    const int* e_dst = edge_index + NEDGE;

    {
        SplitJobs j;
        const float* srcs[8] = {x, node_w, gine_w1, gine_w2, attn_in_w,
                                attn_out_w, mlp_w1, mlp_w2};
        u16* his[8] = {x_hi, node_w_hi, gw1_hi, gw2_hi, aiw_hi, aow_hi, mw1_hi, mw2_hi};
        u16* los[8] = {x_lo, node_w_lo, gw1_lo, gw2_lo, aiw_lo, aow_lo, mw1_lo, mw2_lo};
        int ns[8] = {NODES * 64, CHN * 64, NLAYER * CHN * CHN, NLAYER * CHN * CHN,
                     NLAYER * 3 * CHN * CHN, NLAYER * CHN * CHN,
                     NLAYER * 2 * CHN * CHN, NLAYER * 2 * CHN * CHN};
        int cum = 0;
        for (int i = 0; i < 8; ++i) {
            j.src[i] = srcs[i]; j.hi[i] = his[i]; j.lo[i] = los[i];
            cum += ns[i] / 256;
            j.blk_end[i] = cum;
        }
        k_split8<<<dim3(cum), dim3(256), 0, stream>>>(j);
    }

    k_bnprep<<<dim3((NLAYER * 3 * CHN + 255) / 256), dim3(256), 0, stream>>>(
        bn_g, bn_bb, bn_m, bn_v, bn_scale, bn_shift);

    k_zero_u32<<<dim3(NODES / 256), dim3(256), 0, stream>>>(counts, NODES);
    k_count<<<dim3(NEDGE / 256), dim3(256), 0, stream>>>(e_dst, counts);
    k_scan<<<dim3(1), dim3(256), 0, stream>>>(counts, offsets, cursor);
    k_fill<<<dim3(NEDGE / 256), dim3(256), 0, stream>>>(e_src, e_dst, edge_attr,
                                                        cursor, csr_src, csr_a);

    // node projection: h = x @ node_w^T + node_b
    k_gemm<<<dim3(NODES / 64, CHN / 32), dim3(256), 0, stream>>>(
        x_hi, x_lo, node_w_hi, node_w_lo, node_b, h_f32, h_hi, h_lo, 64, CHN);

    for (int l = 0; l < NLAYER; ++l) {
        size_t wo = (size_t)l * CHN * CHN;
        const float* sc0 = bn_scale + (l * 3 + 0) * CHN;
        const float* sh0 = bn_shift + (l * 3 + 0) * CHN;
        const float* sc1 = bn_scale + (l * 3 + 1) * CHN;
        const float* sh1 = bn_shift + (l * 3 + 1) * CHN;
        const float* sc2 = bn_scale + (l * 3 + 2) * CHN;
        const float* sh2 = bn_shift + (l * 3 + 2) * CHN;

        k_agg<<<dim3(NODES), dim3(64), 0, stream>>>(h_hi, h_f32, offsets, csr_src,
                                                    csr_a, edge_w, edge_b,
                                                    zao_hi, zao_lo);
        k_gine<<<dim3(NODES / 64), dim3(256), 0, stream>>>(
            zao_hi, zao_lo, gw1_hi + wo, gw1_lo + wo, gine_b1 + l * CHN,
            gw2_hi + wo, gw2_lo + wo, gine_b2 + l * CHN, h_f32, sc0, sh0, h1_f32);
        k_qkv<<<dim3(NODES / 64, 12), dim3(256), 0, stream>>>(
            h_hi, h_lo, aiw_hi + wo * 3, aiw_lo + wo * 3, attn_in_b + l * 3 * CHN,
            q_hi, q_lo, kk_hi, kk_lo, vt_hi);
        k_attn<<<dim3(16 * NG * NHEAD), dim3(128), 0, stream>>>(
            q_hi, q_lo, kk_hi, kk_lo, vt_hi, zao_hi, zao_lo);
        k_outffn<<<dim3(NODES / 32), dim3(256), 0, stream>>>(
            zao_hi, zao_lo, aow_hi + wo, aow_lo + wo, attn_out_b + l * CHN,
            h_f32, sc1, sh1, h1_f32,
            mw1_hi + wo * 2, mw1_lo + wo * 2, mlp_b1 + l * 2 * CHN,
            mw2_hi + wo * 2, mw2_lo + wo * 2, mlp_b2 + l * CHN, sc2, sh2,
            h_f32, h_hi, h_lo);
    }

    k_zero_u32<<<dim3(NG * CHN / 256), dim3(256), 0, stream>>>((u32*)pool, NG * CHN);
    k_pool<<<dim3(NG, 8), dim3(128), 0, stream>>>(h_f32, pool);
    k_head<<<dim3(1), dim3(256), 0, stream>>>(pool, head_w1, head_b1, head_w2,
                                              head_b2, head_w3, head_b3,
                                              (float*)d_out);
}

// Round 9
// 929.101 us; speedup vs baseline: 1.2370x; 1.0111x over previous
//
#include <hip/hip_runtime.h>
#include <hip/hip_bf16.h>

typedef __attribute__((ext_vector_type(8))) short short8;
typedef __attribute__((ext_vector_type(4))) float f32x4;
typedef __attribute__((ext_vector_type(2))) unsigned int u32x2;
typedef unsigned short u16;
typedef unsigned int u32;
typedef unsigned long long u64;

#define NODES 16384
#define CHN 128
#define NEDGE 524288
#define NG 16
#define NPGC 1024
#define NHEAD 4
#define HDIM 32
#define NLAYER 4
#define CL 0.2550348281f   // log2(e)/sqrt(HDIM), folded into Q at QKV store

#if __has_builtin(__builtin_amdgcn_exp2f)
#define EXP2(x) __builtin_amdgcn_exp2f(x)
#else
#define EXP2(x) exp2f(x)
#endif

__device__ __forceinline__ float bf2f(u16 u) {
    union { u32 u; float f; } c; c.u = ((u32)u) << 16; return c.f;
}
__device__ __forceinline__ u16 f2bf(float f) {
    union { float f; u32 u; } c; c.f = f;
    u32 r = c.u + 0x7fffu + ((c.u >> 16) & 1u);
    return (u16)(r >> 16);
}
__device__ __forceinline__ void fsplit(float f, u16& hi, u16& lo) {
    u16 h = f2bf(f);
    hi = h;
    lo = f2bf(f - bf2f(h));
}
__device__ __forceinline__ u32 cvtpk_bf16(float a, float b) {
    u32 r;
    asm("v_cvt_pk_bf16_f32 %0, %1, %2" : "=v"(r) : "v"(a), "v"(b));
    return r;
}

#define MFMA16(a, b, c) __builtin_amdgcn_mfma_f32_16x16x32_bf16((a), (b), (c), 0, 0, 0)

__device__ __forceinline__ short8 ld_frag(const u16* p) {
    return *reinterpret_cast<const short8*>(p);
}

// ---------------- setup kernels ----------------

struct SplitJobs {
    const float* src[8];
    u16* hi[8];
    u16* lo[8];
    int blk_end[8];
};

__global__ void k_split8(SplitJobs jobs) {
    int b = blockIdx.x;
    int seg = 0;
    while (b >= jobs.blk_end[seg]) ++seg;
    int base = seg ? jobs.blk_end[seg - 1] : 0;
    int i = (b - base) * 256 + threadIdx.x;
    u16 h, l;
    fsplit(jobs.src[seg][i], h, l);
    jobs.hi[seg][i] = h;
    jobs.lo[seg][i] = l;
}

__global__ void k_bnprep(const float* __restrict__ g, const float* __restrict__ b,
                         const float* __restrict__ m, const float* __restrict__ v,
                         float* __restrict__ scale, float* __restrict__ shift) {
    int i = blockIdx.x * 256 + threadIdx.x;
    if (i < NLAYER * 3 * CHN) {
        float s = g[i] * rsqrtf(v[i] + 1e-5f);
        scale[i] = s;
        shift[i] = b[i] - m[i] * s;
    }
}

__global__ void k_zero_u32(u32* __restrict__ p, int n) {
    int i = blockIdx.x * 256 + threadIdx.x;
    if (i < n) p[i] = 0u;
}

__global__ void k_count(const int* __restrict__ dst, u32* __restrict__ counts) {
    int e = blockIdx.x * 256 + threadIdx.x;
    if (e < NEDGE) atomicAdd(&counts[dst[e]], 1u);
}

__global__ void k_scan(const u32* __restrict__ counts, u32* __restrict__ offsets,
                       u32* __restrict__ cursor) {
    __shared__ u32 part[256];
    int t = threadIdx.x;
    int base = t * 64;
    u32 s = 0;
    for (int i = 0; i < 64; ++i) s += counts[base + i];
    part[t] = s;
    __syncthreads();
    for (int off = 1; off < 256; off <<= 1) {
        u32 val = (t >= off) ? part[t - off] : 0u;
        __syncthreads();
        part[t] += val;
        __syncthreads();
    }
    u32 run = (t == 0) ? 0u : part[t - 1];
    for (int i = 0; i < 64; ++i) {
        offsets[base + i] = run;
        cursor[base + i] = run;
        run += counts[base + i];
    }
    if (t == 255) offsets[NODES] = run;
}

__global__ void k_fill(const int* __restrict__ src, const int* __restrict__ dst,
                       const float* __restrict__ eattr, u32* __restrict__ cursor,
                       int* __restrict__ csr_src, float* __restrict__ csr_a) {
    int e = blockIdx.x * 256 + threadIdx.x;
    if (e >= NEDGE) return;
    int d = dst[e];
    u32 p = atomicAdd(&cursor[d], 1u);
    csr_src[p] = src[e];
    csr_a[p] = eattr[e];
}

// ------ GINE aggregation, software-pipelined gather ------

__global__ __launch_bounds__(64) void k_agg(
    const u16* __restrict__ h_hi, const float* __restrict__ h_f32,
    const u32* __restrict__ offsets, const int* __restrict__ csr_src,
    const float* __restrict__ csr_a, const float* __restrict__ ew,
    const float* __restrict__ eb, u16* __restrict__ z_hi, u16* __restrict__ z_lo) {
    int node = blockIdx.x;
    int t = threadIdx.x;
    int c0 = t * 2;
    float w0 = ew[c0], w1 = ew[c0 + 1];
    float b0 = eb[c0], b1 = eb[c0 + 1];
    u32 beg = offsets[node], end = offsets[node + 1];
    float acc0 = 0.f, acc1 = 0.f;
    u32 n = end - beg;
    if (n) {
        int sa = csr_src[beg];
        float aa = csr_a[beg];
        u32 ua = *reinterpret_cast<const u32*>(h_hi + (size_t)sa * CHN + c0);
        u32 j1 = (n > 1) ? beg + 1 : beg;
        int sb = csr_src[j1];
        float ab = csr_a[j1];
        for (u32 i = 0; i < n; ++i) {
            u32 jn = beg + i + 2;
            jn = jn < end ? jn : end - 1;
            int sc2 = csr_src[jn];
            float ac = csr_a[jn];
            u32 ub = *reinterpret_cast<const u32*>(h_hi + (size_t)sb * CHN + c0);
            float f0 = bf2f((u16)(ua & 0xffffu));
            float f1 = bf2f((u16)(ua >> 16));
            acc0 += fmaxf(f0 + aa * w0 + b0, 0.f);
            acc1 += fmaxf(f1 + aa * w1 + b1, 0.f);
            ua = ub; aa = ab;
            sb = sc2; ab = ac;
        }
    }
    size_t idx = (size_t)node * CHN + c0;
    float z0 = h_f32[idx] + acc0;
    float z1v = h_f32[idx + 1] + acc1;
    u16 h, l;
    fsplit(z0, h, l); z_hi[idx] = h; z_lo[idx] = l;
    fsplit(z1v, h, l); z_hi[idx + 1] = h; z_lo[idx + 1] = l;
}

// ------ split GEMM (16x32 wave tile) — used for node projection ------

__global__ __launch_bounds__(256) void k_gemm(
    const u16* __restrict__ Ahi, const u16* __restrict__ Alo,
    const u16* __restrict__ Whi, const u16* __restrict__ Wlo,
    const float* __restrict__ bias, float* __restrict__ out_f32,
    u16* __restrict__ out_hi, u16* __restrict__ out_lo, int K, int Nc) {
    int tid = threadIdx.x;
    int wave = tid >> 6, lane = tid & 63;
    int lr = lane & 15, lg = lane >> 4;
    int r0 = blockIdx.x * 64 + wave * 16;
    int nb = blockIdx.y * 32;
    f32x4 acc[2] = {};
    size_t arow = (size_t)(r0 + lr) * K + lg * 8;
    for (int ks = 0; ks < K; ks += 32) {
        short8 ah = ld_frag(Ahi + arow + ks);
        short8 al = ld_frag(Alo + arow + ks);
#pragma unroll
        for (int n = 0; n < 2; ++n) {
            size_t wrow = (size_t)(nb + n * 16 + lr) * K + ks + lg * 8;
            short8 wh = ld_frag(Whi + wrow);
            short8 wl = ld_frag(Wlo + wrow);
            acc[n] = MFMA16(ah, wh, acc[n]);
            acc[n] = MFMA16(al, wh, acc[n]);
            acc[n] = MFMA16(ah, wl, acc[n]);
        }
    }
#pragma unroll
    for (int n = 0; n < 2; ++n) {
        int col = nb + n * 16 + lr;
        float bs = bias[col];
#pragma unroll
        for (int r = 0; r < 4; ++r) {
            int row = r0 + lg * 4 + r;
            size_t oidx = (size_t)row * Nc + col;
            float v = acc[n][r] + bs;
            out_f32[oidx] = v;
            u16 hh, ll;
            fsplit(v, hh, ll);
            out_hi[oidx] = hh; out_lo[oidx] = ll;
        }
    }
}

// ---- fused GINE MLP: h1 = bn(relu(z@W1+b1)@W2 + b2 + h) ----
// 16 rows/block, 4 waves col-split (32 cols each) -> grid NODES/16 = 1024 blocks.

__global__ __launch_bounds__(256) void k_gine(
    const u16* __restrict__ zhi, const u16* __restrict__ zlo,
    const u16* __restrict__ w1hi, const u16* __restrict__ w1lo,
    const float* __restrict__ b1,
    const u16* __restrict__ w2hi, const u16* __restrict__ w2lo,
    const float* __restrict__ b2, const float* __restrict__ resid,
    const float* __restrict__ bnsc, const float* __restrict__ bnsh,
    float* __restrict__ h1out) {
    __shared__ __align__(16) u16 t_hi[16][136];
    __shared__ __align__(16) u16 t_lo[16][136];
    int tid = threadIdx.x;
    int wave = tid >> 6, lane = tid & 63;
    int lr = lane & 15, lg = lane >> 4;
    int r0 = blockIdx.x * 16;
    int cb = wave * 32;
    {
        f32x4 acc[2] = {};
        size_t arow = (size_t)(r0 + lr) * CHN + lg * 8;
        for (int ks = 0; ks < CHN; ks += 32) {
            short8 ah = ld_frag(zhi + arow + ks);
            short8 al = ld_frag(zlo + arow + ks);
#pragma unroll
            for (int n = 0; n < 2; ++n) {
                size_t wrow = (size_t)(cb + n * 16 + lr) * CHN + ks + lg * 8;
                short8 wh = ld_frag(w1hi + wrow);
                short8 wl = ld_frag(w1lo + wrow);
                acc[n] = MFMA16(ah, wh, acc[n]);
                acc[n] = MFMA16(al, wh, acc[n]);
                acc[n] = MFMA16(ah, wl, acc[n]);
            }
        }
#pragma unroll
        for (int n = 0; n < 2; ++n) {
            int col = cb + n * 16 + lr;
            float bs = b1[col];
#pragma unroll
            for (int r = 0; r < 4; ++r) {
                float v = fmaxf(acc[n][r] + bs, 0.f);
                u16 hh, ll;
                fsplit(v, hh, ll);
                t_hi[lg * 4 + r][col] = hh;
                t_lo[lg * 4 + r][col] = ll;
            }
        }
    }
    __syncthreads();
    {
        f32x4 acc[2] = {};
        for (int ks = 0; ks < CHN; ks += 32) {
            short8 ah = ld_frag(&t_hi[lr][ks + lg * 8]);
            short8 al = ld_frag(&t_lo[lr][ks + lg * 8]);
#pragma unroll
            for (int n = 0; n < 2; ++n) {
                size_t wrow = (size_t)(cb + n * 16 + lr) * CHN + ks + lg * 8;
                short8 wh = ld_frag(w2hi + wrow);
                short8 wl = ld_frag(w2lo + wrow);
                acc[n] = MFMA16(ah, wh, acc[n]);
                acc[n] = MFMA16(al, wh, acc[n]);
                acc[n] = MFMA16(ah, wl, acc[n]);
            }
        }
#pragma unroll
        for (int n = 0; n < 2; ++n) {
            int col = cb + n * 16 + lr;
            float bs = b2[col], sc = bnsc[col], sh = bnsh[col];
#pragma unroll
            for (int r = 0; r < 4; ++r) {
                int row = r0 + lg * 4 + r;
                size_t oidx = (size_t)row * CHN + col;
                float v = acc[n][r] + bs + resid[oidx];
                h1out[oidx] = v * sc + sh;
            }
        }
    }
}

// ---- fused out-proj + FFN, 16 rows/block, 4 waves col-split -> grid 1024 ----

__global__ __launch_bounds__(256) void k_outffn(
    const u16* __restrict__ aoh, const u16* __restrict__ aol,
    const u16* __restrict__ awh, const u16* __restrict__ awl,
    const float* __restrict__ ab, const float* __restrict__ hres,
    const float* __restrict__ sc1, const float* __restrict__ sh1,
    const float* __restrict__ h1res,
    const u16* __restrict__ w1h, const u16* __restrict__ w1l,
    const float* __restrict__ b1,
    const u16* __restrict__ w2h, const u16* __restrict__ w2l,
    const float* __restrict__ b2,
    const float* __restrict__ sc2, const float* __restrict__ sh2,
    float* __restrict__ hf, u16* __restrict__ hhi, u16* __restrict__ hlo) {
    __shared__ __align__(16) u16 o_hi[16][136];
    __shared__ __align__(16) u16 o_lo[16][136];
    __shared__ __align__(16) u16 t_hi[16][264];
    __shared__ __align__(16) u16 t_lo[16][264];
    int tid = threadIdx.x;
    int wave = tid >> 6, lane = tid & 63;
    int lr = lane & 15, lg = lane >> 4;
    int r0 = blockIdx.x * 16;
    int cb = wave * 32;
    // stage A: out-proj, 16 rows x 32 cols per wave
    {
        f32x4 acc[2] = {};
        size_t arow = (size_t)(r0 + lr) * CHN + lg * 8;
        for (int ks = 0; ks < CHN; ks += 32) {
            short8 ah = ld_frag(aoh + arow + ks);
            short8 al = ld_frag(aol + arow + ks);
#pragma unroll
            for (int n = 0; n < 2; ++n) {
                size_t wrow = (size_t)(cb + n * 16 + lr) * CHN + ks + lg * 8;
                short8 wh = ld_frag(awh + wrow);
                short8 wl = ld_frag(awl + wrow);
                acc[n] = MFMA16(ah, wh, acc[n]);
                acc[n] = MFMA16(al, wh, acc[n]);
                acc[n] = MFMA16(ah, wl, acc[n]);
            }
        }
#pragma unroll
        for (int n = 0; n < 2; ++n) {
            int col = cb + n * 16 + lr;
            float bs = ab[col], sc = sc1[col], sh = sh1[col];
#pragma unroll
            for (int r = 0; r < 4; ++r) {
                int row = r0 + lg * 4 + r;
                int rl = lg * 4 + r;
                size_t oidx = (size_t)row * CHN + col;
                float v = (acc[n][r] + bs + hres[oidx]) * sc + sh + h1res[oidx];
                u16 hh, ll;
                fsplit(v, hh, ll);
                o_hi[rl][col] = hh; o_lo[rl][col] = ll;
            }
        }
    }
    __syncthreads();
    // stage B: FFN up, 16 rows x 64 cols per wave (of 256)
    {
        f32x4 acc[4] = {};
        int cbB = wave * 64;
        for (int ks = 0; ks < CHN; ks += 32) {
            short8 ah = ld_frag(&o_hi[lr][ks + lg * 8]);
            short8 al = ld_frag(&o_lo[lr][ks + lg * 8]);
#pragma unroll
            for (int n = 0; n < 4; ++n) {
                size_t wrow = (size_t)(cbB + n * 16 + lr) * CHN + ks + lg * 8;
                short8 wh = ld_frag(w1h + wrow);
                short8 wl = ld_frag(w1l + wrow);
                acc[n] = MFMA16(ah, wh, acc[n]);
                acc[n] = MFMA16(al, wh, acc[n]);
                acc[n] = MFMA16(ah, wl, acc[n]);
            }
        }
#pragma unroll
        for (int n = 0; n < 4; ++n) {
            int col = cbB + n * 16 + lr;
            float bs = b1[col];
#pragma unroll
            for (int r = 0; r < 4; ++r) {
                float v = fmaxf(acc[n][r] + bs, 0.f);
                u16 hh, ll;
                fsplit(v, hh, ll);
                t_hi[lg * 4 + r][col] = hh;
                t_lo[lg * 4 + r][col] = ll;
            }
        }
    }
    __syncthreads();
    // stage C: FFN down, K=256, 16 rows x 32 cols per wave
    {
        f32x4 acc[2] = {};
        for (int ks = 0; ks < 2 * CHN; ks += 32) {
            short8 ah = ld_frag(&t_hi[lr][ks + lg * 8]);
            short8 al = ld_frag(&t_lo[lr][ks + lg * 8]);
#pragma unroll
            for (int n = 0; n < 2; ++n) {
                size_t wrow = (size_t)(cb + n * 16 + lr) * 2 * CHN + ks + lg * 8;
                short8 wh = ld_frag(w2h + wrow);
                short8 wl = ld_frag(w2l + wrow);
                acc[n] = MFMA16(ah, wh, acc[n]);
                acc[n] = MFMA16(al, wh, acc[n]);
                acc[n] = MFMA16(ah, wl, acc[n]);
            }
        }
#pragma unroll
        for (int n = 0; n < 2; ++n) {
            int col = cb + n * 16 + lr;
            float bs = b2[col], sc = sc2[col], sh = sh2[col];
#pragma unroll
            for (int r = 0; r < 4; ++r) {
                int row = r0 + lg * 4 + r;
                int rl = lg * 4 + r;
                size_t oidx = (size_t)row * CHN + col;
                float ores = bf2f(o_hi[rl][col]) + bf2f(o_lo[rl][col]);
                float v = (acc[n][r] + bs + ores) * sc + sh;
                hf[oidx] = v;
                u16 hh, ll;
                fsplit(v, hh, ll);
                hhi[oidx] = hh; hlo[oidx] = ll;
            }
        }
    }
}

// -------- QKV GEMM; Q is pre-scaled by CL = log2(e)/sqrt(HDIM) --------

__global__ __launch_bounds__(256) void k_qkv(
    const u16* __restrict__ Ahi, const u16* __restrict__ Alo,
    const u16* __restrict__ Whi, const u16* __restrict__ Wlo,
    const float* __restrict__ bias,
    u16* __restrict__ q_hi, u16* __restrict__ q_lo,
    u16* __restrict__ k_hi, u16* __restrict__ k_lo,
    u16* __restrict__ vt_hi) {
    const int K = 128;
    int tid = threadIdx.x;
    int wave = tid >> 6, lane = tid & 63;
    int lr = lane & 15, lg = lane >> 4;
    int r0 = blockIdx.x * 64 + wave * 16;
    int nb = blockIdx.y * 32;
    f32x4 acc[2] = {};
    size_t arow = (size_t)(r0 + lr) * K + lg * 8;
    for (int ks = 0; ks < K; ks += 32) {
        short8 ah = ld_frag(Ahi + arow + ks);
        short8 al = ld_frag(Alo + arow + ks);
#pragma unroll
        for (int n = 0; n < 2; ++n) {
            size_t wrow = (size_t)(nb + n * 16 + lr) * K + ks + lg * 8;
            short8 wh = ld_frag(Whi + wrow);
            short8 wl = ld_frag(Wlo + wrow);
            acc[n] = MFMA16(ah, wh, acc[n]);
            acc[n] = MFMA16(al, wh, acc[n]);
            acc[n] = MFMA16(ah, wl, acc[n]);
        }
    }
#pragma unroll
    for (int n = 0; n < 2; ++n) {
        int col = nb + n * 16 + lr;
        int region = col >> 7;
        int c = col & 127;
        int hh = c >> 5, d = c & 31;
        float bs = bias[col];
#pragma unroll
        for (int r = 0; r < 4; ++r) {
            int row = r0 + lg * 4 + r;
            float v = acc[n][r] + bs;
            int g = row >> 10, p = row & 1023;
            size_t gh = (size_t)(g * NHEAD + hh);
            if (region == 0) {
                u16 vh, vl;
                fsplit(v * CL, vh, vl);   // fold softmax scale into Q
                size_t o = (gh * NPGC + p) * HDIM + d;
                q_hi[o] = vh; q_lo[o] = vl;
            } else if (region == 1) {
                u16 vh, vl;
                fsplit(v, vh, vl);
                size_t o = (gh * NPGC + p) * HDIM + d;
                k_hi[o] = vh; k_lo[o] = vl;
            } else {
                vt_hi[(gh * HDIM + d) * NPGC + p] = f2bf(v);
            }
        }
    }
}

// --- flash attention: swapped QK^T, dual-stream, XCD-swizzled, online-max softmax ---
// Scores arrive pre-scaled (Q carries CL), so P = exp2(s - m) with running max m.

__global__ __launch_bounds__(128) void k_attn(
    const u16* __restrict__ qhi, const u16* __restrict__ qlo,
    const u16* __restrict__ khi, const u16* __restrict__ klo,
    const u16* __restrict__ vthi,
    u16* __restrict__ aohi, u16* __restrict__ aolo) {
    __shared__ __align__(16) u16 plds[2][16][136];
    int tid = threadIdx.x;
    int wave = tid >> 6, lane = tid & 63;
    int lr = lane & 15, lg = lane >> 4;
    int id = blockIdx.x;
    int gh = id & 63;           // g*4 + head; id%8==gh%8 -> per-gh XCD locality
    int bx = id >> 6;
    int qA = bx * 64 + wave * 32;
    int qB = qA + 16;
    size_t base = (size_t)gh * NPGC * HDIM;
    size_t vbase = (size_t)gh * HDIM * NPGC;
    short8 qhA = ld_frag(qhi + base + (size_t)(qA + lr) * HDIM + lg * 8);
    short8 qlA = ld_frag(qlo + base + (size_t)(qA + lr) * HDIM + lg * 8);
    short8 qhB = ld_frag(qhi + base + (size_t)(qB + lr) * HDIM + lg * 8);
    short8 qlB = ld_frag(qlo + base + (size_t)(qB + lr) * HDIM + lg * 8);
    const u16* Kh = khi + base;
    const u16* Kl = klo + base;
    const u16* Vh = vthi + vbase;
    f32x4 o0A = {}, o1A = {}, o0B = {}, o1B = {};
    float mA = -1e30f, lA = 0.f, mB = -1e30f, lB = 0.f;
    const f32x4 zero = {};
    for (int kv = 0; kv < NPGC; kv += 128) {
        f32x4 sA[8], sB[8];
#pragma unroll
        for (int f = 0; f < 8; ++f) {
            size_t kr = (size_t)(kv + f * 16 + lr) * HDIM + lg * 8;
            short8 kh = ld_frag(Kh + kr);
            short8 kl2 = ld_frag(Kl + kr);
            sA[f] = MFMA16(kh, qlA, MFMA16(kl2, qhA, MFMA16(kh, qhA, zero)));
            sB[f] = MFMA16(kh, qlB, MFMA16(kl2, qhB, MFMA16(kh, qhB, zero)));
        }
        // ---- softmax A (overlaps QK_B drain) ----
        {
            f32x4 mm = sA[0];
#pragma unroll
            for (int f = 1; f < 8; ++f)
#pragma unroll
                for (int i = 0; i < 4; ++i) mm[i] = fmaxf(mm[i], sA[f][i]);
            float mx = fmaxf(fmaxf(mm[0], mm[1]), fmaxf(mm[2], mm[3]));
            mx = fmaxf(mx, __shfl_xor(mx, 16));
            mx = fmaxf(mx, __shfl_xor(mx, 32));
            float mn = fmaxf(mA, mx);
            float corr = EXP2(mA - mn);
            mA = mn;
#pragma unroll
            for (int f = 0; f < 8; ++f)
#pragma unroll
                for (int i = 0; i < 4; ++i) sA[f][i] = EXP2(sA[f][i] - mn);
            f32x4 s4 = sA[0];
#pragma unroll
            for (int f = 1; f < 8; ++f)
#pragma unroll
                for (int i = 0; i < 4; ++i) s4[i] += sA[f][i];
            float ps = (s4[0] + s4[1]) + (s4[2] + s4[3]);
            ps += __shfl_xor(ps, 16);
            ps += __shfl_xor(ps, 32);
            lA = fmaf(lA, corr, ps);
#pragma unroll
            for (int i = 0; i < 4; ++i) { o0A[i] *= corr; o1A[i] *= corr; }
#pragma unroll
            for (int f = 0; f < 8; ++f) {
                u32x2 wv;
                wv[0] = cvtpk_bf16(sA[f][0], sA[f][1]);
                wv[1] = cvtpk_bf16(sA[f][2], sA[f][3]);
                *reinterpret_cast<u32x2*>(&plds[wave][lr][f * 16 + lg * 4]) = wv;
            }
        }
        // ---- PV A (V frags kept for B) ----
        short8 vs0[4], vs1[4];
#pragma unroll
        for (int kk = 0; kk < 4; ++kk) {
            short8 pf = ld_frag(&plds[wave][lr][kk * 32 + lg * 8]);
            vs0[kk] = ld_frag(Vh + (size_t)lr * NPGC + kv + kk * 32 + lg * 8);
            vs1[kk] = ld_frag(Vh + (size_t)(16 + lr) * NPGC + kv + kk * 32 + lg * 8);
            o0A = MFMA16(vs0[kk], pf, o0A);
            o1A = MFMA16(vs1[kk], pf, o1A);
        }
        // ---- softmax B (overlaps PV_A drain) ----
        {
            f32x4 mm = sB[0];
#pragma unroll
            for (int f = 1; f < 8; ++f)
#pragma unroll
                for (int i = 0; i < 4; ++i) mm[i] = fmaxf(mm[i], sB[f][i]);
            float mx = fmaxf(fmaxf(mm[0], mm[1]), fmaxf(mm[2], mm[3]));
            mx = fmaxf(mx, __shfl_xor(mx, 16));
            mx = fmaxf(mx, __shfl_xor(mx, 32));
            float mn = fmaxf(mB, mx);
            float corr = EXP2(mB - mn);
            mB = mn;
#pragma unroll
            for (int f = 0; f < 8; ++f)
#pragma unroll
                for (int i = 0; i < 4; ++i) sB[f][i] = EXP2(sB[f][i] - mn);
            f32x4 s4 = sB[0];
#pragma unroll
            for (int f = 1; f < 8; ++f)
#pragma unroll
                for (int i = 0; i < 4; ++i) s4[i] += sB[f][i];
            float ps = (s4[0] + s4[1]) + (s4[2] + s4[3]);
            ps += __shfl_xor(ps, 16);
            ps += __shfl_xor(ps, 32);
            lB = fmaf(lB, corr, ps);
#pragma unroll
            for (int i = 0; i < 4; ++i) { o0B[i] *= corr; o1B[i] *= corr; }
            // same-wave DS ordering: PV_A reads complete before these writes land
#pragma unroll
            for (int f = 0; f < 8; ++f) {
                u32x2 wv;
                wv[0] = cvtpk_bf16(sB[f][0], sB[f][1]);
                wv[1] = cvtpk_bf16(sB[f][2], sB[f][3]);
                *reinterpret_cast<u32x2*>(&plds[wave][lr][f * 16 + lg * 4]) = wv;
            }
        }
        // ---- PV B ----
#pragma unroll
        for (int kk = 0; kk < 4; ++kk) {
            short8 pf = ld_frag(&plds[wave][lr][kk * 32 + lg * 8]);
            o0B = MFMA16(vs0[kk], pf, o0B);
            o1B = MFMA16(vs1[kk], pf, o1B);
        }
    }
    int g = gh >> 2, hh = gh & 3;
    {
        float inv = 1.f / lA;
        size_t obase = ((size_t)g * NPGC + qA + lr) * CHN + hh * HDIM;
        union { u16 u[4]; u64 v; } p0h, p0l, p1h, p1l;
#pragma unroll
        for (int i = 0; i < 4; ++i) {
            u16 a, b;
            fsplit(o0A[i] * inv, a, b); p0h.u[i] = a; p0l.u[i] = b;
            fsplit(o1A[i] * inv, a, b); p1h.u[i] = a; p1l.u[i] = b;
        }
        *reinterpret_cast<u64*>(aohi + obase + lg * 4) = p0h.v;
        *reinterpret_cast<u64*>(aolo + obase + lg * 4) = p0l.v;
        *reinterpret_cast<u64*>(aohi + obase + 16 + lg * 4) = p1h.v;
        *reinterpret_cast<u64*>(aolo + obase + 16 + lg * 4) = p1l.v;
    }
    {
        float inv = 1.f / lB;
        size_t obase = ((size_t)g * NPGC + qB + lr) * CHN + hh * HDIM;
        union { u16 u[4]; u64 v; } p0h, p0l, p1h, p1l;
#pragma unroll
        for (int i = 0; i < 4; ++i) {
            u16 a, b;
            fsplit(o0B[i] * inv, a, b); p0h.u[i] = a; p0l.u[i] = b;
            fsplit(o1B[i] * inv, a, b); p1h.u[i] = a; p1l.u[i] = b;
        }
        *reinterpret_cast<u64*>(aohi + obase + lg * 4) = p0h.v;
        *reinterpret_cast<u64*>(aolo + obase + lg * 4) = p0l.v;
        *reinterpret_cast<u64*>(aohi + obase + 16 + lg * 4) = p1h.v;
        *reinterpret_cast<u64*>(aolo + obase + 16 + lg * 4) = p1l.v;
    }
}

// ---------------- pooling + head MLP ----------------

__global__ __launch_bounds__(128) void k_pool(const float* __restrict__ h,
                                              float* __restrict__ pool) {
    int g = blockIdx.x, sl = blockIdx.y, c = threadIdx.x;
    const float* p = h + ((size_t)g * NPGC + sl * 128) * CHN + c;
    float s = 0.f;
    for (int i = 0; i < 128; ++i) s += p[(size_t)i * CHN];
    atomicAdd(&pool[g * CHN + c], s);
}

__global__ __launch_bounds__(256) void k_head(
    const float* __restrict__ pool, const float* __restrict__ w1,
    const float* __restrict__ b1, const float* __restrict__ w2,
    const float* __restrict__ b2, const float* __restrict__ w3,
    const float* __restrict__ b3, float* __restrict__ out) {
    __shared__ float g1[16][64];
    __shared__ float g2[16][32];
    int t = threadIdx.x;
    for (int idx = t; idx < 16 * 64; idx += 256) {
        int g = idx >> 6, n = idx & 63;
        float s = b1[n];
        for (int k = 0; k < 128; ++k) s += pool[g * 128 + k] * w1[n * 128 + k];
        g1[g][n] = fmaxf(s, 0.f);
    }
    __syncthreads();
    for (int idx = t; idx < 16 * 32; idx += 256) {
        int g = idx >> 5, n = idx & 31;
        float s = b2[n];
        for (int k = 0; k < 64; ++k) s += g1[g][k] * w2[n * 64 + k];
        g2[g][n] = fmaxf(s, 0.f);
    }
    __syncthreads();
    if (t < 16) {
        float s = b3[0];
        for (int k = 0; k < 32; ++k) s += g2[t][k] * w3[k];
        out[t] = s;
    }
}

// ---------------- host ----------------

extern "C" void kernel_launch(void* const* d_in, const int* in_sizes, int n_in,
                              void* d_out, int out_size, void* d_ws, size_t ws_size,
                              hipStream_t stream) {
    (void)in_sizes; (void)n_in; (void)out_size; (void)ws_size;
    const float* x = (const float*)d_in[0];
    const float* edge_attr = (const float*)d_in[1];
    const int* edge_index = (const int*)d_in[2];
    const float* node_w = (const float*)d_in[4];
    const float* node_b = (const float*)d_in[5];
    const float* edge_w = (const float*)d_in[6];
    const float* edge_b = (const float*)d_in[7];
    const float* gine_w1 = (const float*)d_in[8];
    const float* gine_b1 = (const float*)d_in[9];
    const float* gine_w2 = (const float*)d_in[10];
    const float* gine_b2 = (const float*)d_in[11];
    const float* attn_in_w = (const float*)d_in[12];
    const float* attn_in_b = (const float*)d_in[13];
    const float* attn_out_w = (const float*)d_in[14];
    const float* attn_out_b = (const float*)d_in[15];
    const float* mlp_w1 = (const float*)d_in[16];
    const float* mlp_b1 = (const float*)d_in[17];
    const float* mlp_w2 = (const float*)d_in[18];
    const float* mlp_b2 = (const float*)d_in[19];
    const float* bn_g = (const float*)d_in[20];
    const float* bn_bb = (const float*)d_in[21];
    const float* bn_m = (const float*)d_in[22];
    const float* bn_v = (const float*)d_in[23];
    const float* head_w1 = (const float*)d_in[24];
    const float* head_b1 = (const float*)d_in[25];
    const float* head_w2 = (const float*)d_in[26];
    const float* head_b2 = (const float*)d_in[27];
    const float* head_w3 = (const float*)d_in[28];
    const float* head_b3 = (const float*)d_in[29];

    char* ws = (char*)d_ws;
    size_t off = 0;
    auto alloc = [&](size_t bytes) {
        size_t r = off;
        off = (off + bytes + 255) & ~(size_t)255;
        return r;
    };
    const size_t NC = (size_t)NODES * CHN;
    float* h_f32 = (float*)(ws + alloc(NC * 4));
    u16* h_hi = (u16*)(ws + alloc(NC * 2));
    u16* h_lo = (u16*)(ws + alloc(NC * 2));
    u16* x_hi = (u16*)(ws + alloc((size_t)NODES * 64 * 2));
    u16* x_lo = (u16*)(ws + alloc((size_t)NODES * 64 * 2));
    u16* zao_hi = (u16*)(ws + alloc(NC * 2));
    u16* zao_lo = (u16*)(ws + alloc(NC * 2));
    float* h1_f32 = (float*)(ws + alloc(NC * 4));
    u16* q_hi = (u16*)(ws + alloc(NC * 2));
    u16* q_lo = (u16*)(ws + alloc(NC * 2));
    u16* kk_hi = (u16*)(ws + alloc(NC * 2));
    u16* kk_lo = (u16*)(ws + alloc(NC * 2));
    u16* vt_hi = (u16*)(ws + alloc(NC * 2));
    float* pool = (float*)(ws + alloc(NG * CHN * 4));
    u16* node_w_hi = (u16*)(ws + alloc(CHN * 64 * 2));
    u16* node_w_lo = (u16*)(ws + alloc(CHN * 64 * 2));
    u16* gw1_hi = (u16*)(ws + alloc((size_t)NLAYER * CHN * CHN * 2));
    u16* gw1_lo = (u16*)(ws + alloc((size_t)NLAYER * CHN * CHN * 2));
    u16* gw2_hi = (u16*)(ws + alloc((size_t)NLAYER * CHN * CHN * 2));
    u16* gw2_lo = (u16*)(ws + alloc((size_t)NLAYER * CHN * CHN * 2));
    u16* aiw_hi = (u16*)(ws + alloc((size_t)NLAYER * 3 * CHN * CHN * 2));
    u16* aiw_lo = (u16*)(ws + alloc((size_t)NLAYER * 3 * CHN * CHN * 2));
    u16* aow_hi = (u16*)(ws + alloc((size_t)NLAYER * CHN * CHN * 2));
    u16* aow_lo = (u16*)(ws + alloc((size_t)NLAYER * CHN * CHN * 2));
    u16* mw1_hi = (u16*)(ws + alloc((size_t)NLAYER * 2 * CHN * CHN * 2));
    u16* mw1_lo = (u16*)(ws + alloc((size_t)NLAYER * 2 * CHN * CHN * 2));
    u16* mw2_hi = (u16*)(ws + alloc((size_t)NLAYER * 2 * CHN * CHN * 2));
    u16* mw2_lo = (u16*)(ws + alloc((size_t)NLAYER * 2 * CHN * CHN * 2));
    float* bn_scale = (float*)(ws + alloc(NLAYER * 3 * CHN * 4));
    float* bn_shift = (float*)(ws + alloc(NLAYER * 3 * CHN * 4));
    u32* counts = (u32*)(ws + alloc(NODES * 4));
    u32* offsets = (u32*)(ws + alloc((NODES + 1) * 4));
    u32* cursor = (u32*)(ws + alloc(NODES * 4));
    int* csr_src = (int*)(ws + alloc((size_t)NEDGE * 4));
    float* csr_a = (float*)(ws + alloc((size_t)NEDGE * 4));

    const int* e_src = edge_index;
    const int* e_dst = edge_index + NEDGE;

    {
        SplitJobs j;
        const float* srcs[8] = {x, node_w, gine_w1, gine_w2, attn_in_w,
                                attn_out_w, mlp_w1, mlp_w2};
        u16* his[8] = {x_hi, node_w_hi, gw1_hi, gw2_hi, aiw_hi, aow_hi, mw1_hi, mw2_hi};
        u16* los[8] = {x_lo, node_w_lo, gw1_lo, gw2_lo, aiw_lo, aow_lo, mw1_lo, mw2_lo};
        int ns[8] = {NODES * 64, CHN * 64, NLAYER * CHN * CHN, NLAYER * CHN * CHN,
                     NLAYER * 3 * CHN * CHN, NLAYER * CHN * CHN,
                     NLAYER * 2 * CHN * CHN, NLAYER * 2 * CHN * CHN};
        int cum = 0;
        for (int i = 0; i < 8; ++i) {
            j.src[i] = srcs[i]; j.hi[i] = his[i]; j.lo[i] = los[i];
            cum += ns[i] / 256;
            j.blk_end[i] = cum;
        }
        k_split8<<<dim3(cum), dim3(256), 0, stream>>>(j);
    }

    k_bnprep<<<dim3((NLAYER * 3 * CHN + 255) / 256), dim3(256), 0, stream>>>(
        bn_g, bn_bb, bn_m, bn_v, bn_scale, bn_shift);

    k_zero_u32<<<dim3(NODES / 256), dim3(256), 0, stream>>>(counts, NODES);
    k_count<<<dim3(NEDGE / 256), dim3(256), 0, stream>>>(e_dst, counts);
    k_scan<<<dim3(1), dim3(256), 0, stream>>>(counts, offsets, cursor);
    k_fill<<<dim3(NEDGE / 256), dim3(256), 0, stream>>>(e_src, e_dst, edge_attr,
                                                        cursor, csr_src, csr_a);

    // node projection: h = x @ node_w^T + node_b
    k_gemm<<<dim3(NODES / 64, CHN / 32), dim3(256), 0, stream>>>(
        x_hi, x_lo, node_w_hi, node_w_lo, node_b, h_f32, h_hi, h_lo, 64, CHN);

    for (int l = 0; l < NLAYER; ++l) {
        size_t wo = (size_t)l * CHN * CHN;
        const float* sc0 = bn_scale + (l * 3 + 0) * CHN;
        const float* sh0 = bn_shift + (l * 3 + 0) * CHN;
        const float* sc1 = bn_scale + (l * 3 + 1) * CHN;
        const float* sh1 = bn_shift + (l * 3 + 1) * CHN;
        const float* sc2 = bn_scale + (l * 3 + 2) * CHN;
        const float* sh2 = bn_shift + (l * 3 + 2) * CHN;

        k_agg<<<dim3(NODES), dim3(64), 0, stream>>>(h_hi, h_f32, offsets, csr_src,
                                                    csr_a, edge_w, edge_b,
                                                    zao_hi, zao_lo);
        k_gine<<<dim3(NODES / 16), dim3(256), 0, stream>>>(
            zao_hi, zao_lo, gw1_hi + wo, gw1_lo + wo, gine_b1 + l * CHN,
            gw2_hi + wo, gw2_lo + wo, gine_b2 + l * CHN, h_f32, sc0, sh0, h1_f32);
        k_qkv<<<dim3(NODES / 64, 12), dim3(256), 0, stream>>>(
            h_hi, h_lo, aiw_hi + wo * 3, aiw_lo + wo * 3, attn_in_b + l * 3 * CHN,
            q_hi, q_lo, kk_hi, kk_lo, vt_hi);
        k_attn<<<dim3(16 * NG * NHEAD), dim3(128), 0, stream>>>(
            q_hi, q_lo, kk_hi, kk_lo, vt_hi, zao_hi, zao_lo);
        k_outffn<<<dim3(NODES / 16), dim3(256), 0, stream>>>(
            zao_hi, zao_lo, aow_hi + wo, aow_lo + wo, attn_out_b + l * CHN,
            h_f32, sc1, sh1, h1_f32,
            mw1_hi + wo * 2, mw1_lo + wo * 2, mlp_b1 + l * 2 * CHN,
            mw2_hi + wo * 2, mw2_lo + wo * 2, mlp_b2 + l * CHN, sc2, sh2,
            h_f32, h_hi, h_lo);
    }

    k_zero_u32<<<dim3(NG * CHN / 256), dim3(256), 0, stream>>>((u32*)pool, NG * CHN);
    k_pool<<<dim3(NG, 8), dim3(128), 0, stream>>>(h_f32, pool);
    k_head<<<dim3(1), dim3(256), 0, stream>>>(pool, head_w1, head_b1, head_w2,
                                              head_b2, head_w3, head_b3,
                                              (float*)d_out);
}

// Round 10
// 865.056 us; speedup vs baseline: 1.3286x; 1.0740x over previous
//
#include <hip/hip_runtime.h>
#include <hip/hip_bf16.h>

typedef __attribute__((ext_vector_type(8))) short short8;
typedef __attribute__((ext_vector_type(4))) float f32x4;
typedef __attribute__((ext_vector_type(2))) unsigned int u32x2;
typedef unsigned short u16;
typedef unsigned int u32;
typedef unsigned long long u64;

#define NODES 16384
#define CHN 128
#define NEDGE 524288
#define NG 16
#define NPGC 1024
#define NHEAD 4
#define HDIM 32
#define NLAYER 4
#define CL 0.2550348281f   // log2(e)/sqrt(HDIM), folded into Q at QKV store

#if __has_builtin(__builtin_amdgcn_exp2f)
#define EXP2(x) __builtin_amdgcn_exp2f(x)
#else
#define EXP2(x) exp2f(x)
#endif

__device__ __forceinline__ float bf2f(u16 u) {
    union { u32 u; float f; } c; c.u = ((u32)u) << 16; return c.f;
}
__device__ __forceinline__ u16 f2bf(float f) {
    union { float f; u32 u; } c; c.f = f;
    u32 r = c.u + 0x7fffu + ((c.u >> 16) & 1u);
    return (u16)(r >> 16);
}
__device__ __forceinline__ void fsplit(float f, u16& hi, u16& lo) {
    u16 h = f2bf(f);
    hi = h;
    lo = f2bf(f - bf2f(h));
}
__device__ __forceinline__ u32 cvtpk_bf16(float a, float b) {
    u32 r;
    asm("v_cvt_pk_bf16_f32 %0, %1, %2" : "=v"(r) : "v"(a), "v"(b));
    return r;
}

#define MFMA16(a, b, c) __builtin_amdgcn_mfma_f32_16x16x32_bf16((a), (b), (c), 0, 0, 0)

__device__ __forceinline__ short8 ld_frag(const u16* p) {
    return *reinterpret_cast<const short8*>(p);
}

// ---------------- setup kernels ----------------

struct SplitJobs {
    const float* src[8];
    u16* hi[8];
    u16* lo[8];
    int blk_end[8];
};

__global__ void k_split8(SplitJobs jobs) {
    int b = blockIdx.x;
    int seg = 0;
    while (b >= jobs.blk_end[seg]) ++seg;
    int base = seg ? jobs.blk_end[seg - 1] : 0;
    int i = (b - base) * 256 + threadIdx.x;
    u16 h, l;
    fsplit(jobs.src[seg][i], h, l);
    jobs.hi[seg][i] = h;
    jobs.lo[seg][i] = l;
}

__global__ void k_bnprep(const float* __restrict__ g, const float* __restrict__ b,
                         const float* __restrict__ m, const float* __restrict__ v,
                         float* __restrict__ scale, float* __restrict__ shift) {
    int i = blockIdx.x * 256 + threadIdx.x;
    if (i < NLAYER * 3 * CHN) {
        float s = g[i] * rsqrtf(v[i] + 1e-5f);
        scale[i] = s;
        shift[i] = b[i] - m[i] * s;
    }
}

__global__ void k_zero_u32(u32* __restrict__ p, int n) {
    int i = blockIdx.x * 256 + threadIdx.x;
    if (i < n) p[i] = 0u;
}

__global__ void k_count(const int* __restrict__ dst, u32* __restrict__ counts) {
    int e = blockIdx.x * 256 + threadIdx.x;
    if (e < NEDGE) atomicAdd(&counts[dst[e]], 1u);
}

__global__ void k_scan(const u32* __restrict__ counts, u32* __restrict__ offsets,
                       u32* __restrict__ cursor) {
    __shared__ u32 part[256];
    int t = threadIdx.x;
    int base = t * 64;
    u32 s = 0;
    for (int i = 0; i < 64; ++i) s += counts[base + i];
    part[t] = s;
    __syncthreads();
    for (int off = 1; off < 256; off <<= 1) {
        u32 val = (t >= off) ? part[t - off] : 0u;
        __syncthreads();
        part[t] += val;
        __syncthreads();
    }
    u32 run = (t == 0) ? 0u : part[t - 1];
    for (int i = 0; i < 64; ++i) {
        offsets[base + i] = run;
        cursor[base + i] = run;
        run += counts[base + i];
    }
    if (t == 255) offsets[NODES] = run;
}

__global__ void k_fill(const int* __restrict__ src, const int* __restrict__ dst,
                       const float* __restrict__ eattr, u32* __restrict__ cursor,
                       int* __restrict__ csr_src, float* __restrict__ csr_a) {
    int e = blockIdx.x * 256 + threadIdx.x;
    if (e >= NEDGE) return;
    int d = dst[e];
    u32 p = atomicAdd(&cursor[d], 1u);
    csr_src[p] = src[e];
    csr_a[p] = eattr[e];
}

// ------ GINE aggregation, software-pipelined gather ------

__global__ __launch_bounds__(64) void k_agg(
    const u16* __restrict__ h_hi, const float* __restrict__ h_f32,
    const u32* __restrict__ offsets, const int* __restrict__ csr_src,
    const float* __restrict__ csr_a, const float* __restrict__ ew,
    const float* __restrict__ eb, u16* __restrict__ z_hi, u16* __restrict__ z_lo) {
    int node = blockIdx.x;
    int t = threadIdx.x;
    int c0 = t * 2;
    float w0 = ew[c0], w1 = ew[c0 + 1];
    float b0 = eb[c0], b1 = eb[c0 + 1];
    u32 beg = offsets[node], end = offsets[node + 1];
    float acc0 = 0.f, acc1 = 0.f;
    u32 n = end - beg;
    if (n) {
        int sa = csr_src[beg];
        float aa = csr_a[beg];
        u32 ua = *reinterpret_cast<const u32*>(h_hi + (size_t)sa * CHN + c0);
        u32 j1 = (n > 1) ? beg + 1 : beg;
        int sb = csr_src[j1];
        float ab = csr_a[j1];
        for (u32 i = 0; i < n; ++i) {
            u32 jn = beg + i + 2;
            jn = jn < end ? jn : end - 1;
            int sc2 = csr_src[jn];
            float ac = csr_a[jn];
            u32 ub = *reinterpret_cast<const u32*>(h_hi + (size_t)sb * CHN + c0);
            float f0 = bf2f((u16)(ua & 0xffffu));
            float f1 = bf2f((u16)(ua >> 16));
            acc0 += fmaxf(f0 + aa * w0 + b0, 0.f);
            acc1 += fmaxf(f1 + aa * w1 + b1, 0.f);
            ua = ub; aa = ab;
            sb = sc2; ab = ac;
        }
    }
    size_t idx = (size_t)node * CHN + c0;
    float z0 = h_f32[idx] + acc0;
    float z1v = h_f32[idx + 1] + acc1;
    u16 h, l;
    fsplit(z0, h, l); z_hi[idx] = h; z_lo[idx] = l;
    fsplit(z1v, h, l); z_hi[idx + 1] = h; z_lo[idx + 1] = l;
}

// ------ split GEMM (16x32 wave tile) — used for node projection ------

__global__ __launch_bounds__(256) void k_gemm(
    const u16* __restrict__ Ahi, const u16* __restrict__ Alo,
    const u16* __restrict__ Whi, const u16* __restrict__ Wlo,
    const float* __restrict__ bias, float* __restrict__ out_f32,
    u16* __restrict__ out_hi, u16* __restrict__ out_lo, int K, int Nc) {
    int tid = threadIdx.x;
    int wave = tid >> 6, lane = tid & 63;
    int lr = lane & 15, lg = lane >> 4;
    int r0 = blockIdx.x * 64 + wave * 16;
    int nb = blockIdx.y * 32;
    f32x4 acc[2] = {};
    size_t arow = (size_t)(r0 + lr) * K + lg * 8;
    for (int ks = 0; ks < K; ks += 32) {
        short8 ah = ld_frag(Ahi + arow + ks);
        short8 al = ld_frag(Alo + arow + ks);
#pragma unroll
        for (int n = 0; n < 2; ++n) {
            size_t wrow = (size_t)(nb + n * 16 + lr) * K + ks + lg * 8;
            short8 wh = ld_frag(Whi + wrow);
            short8 wl = ld_frag(Wlo + wrow);
            acc[n] = MFMA16(ah, wh, acc[n]);
            acc[n] = MFMA16(al, wh, acc[n]);
            acc[n] = MFMA16(ah, wl, acc[n]);
        }
    }
#pragma unroll
    for (int n = 0; n < 2; ++n) {
        int col = nb + n * 16 + lr;
        float bs = bias[col];
#pragma unroll
        for (int r = 0; r < 4; ++r) {
            int row = r0 + lg * 4 + r;
            size_t oidx = (size_t)row * Nc + col;
            float v = acc[n][r] + bs;
            out_f32[oidx] = v;
            u16 hh, ll;
            fsplit(v, hh, ll);
            out_hi[oidx] = hh; out_lo[oidx] = ll;
        }
    }
}

// ---- fused GINE MLP: h1 = bn(relu(z@W1+b1)@W2 + b2 + h) ----
// 16 rows/block, 4 waves col-split (32 cols each) -> grid NODES/16 = 1024 blocks.

__global__ __launch_bounds__(256) void k_gine(
    const u16* __restrict__ zhi, const u16* __restrict__ zlo,
    const u16* __restrict__ w1hi, const u16* __restrict__ w1lo,
    const float* __restrict__ b1,
    const u16* __restrict__ w2hi, const u16* __restrict__ w2lo,
    const float* __restrict__ b2, const float* __restrict__ resid,
    const float* __restrict__ bnsc, const float* __restrict__ bnsh,
    float* __restrict__ h1out) {
    __shared__ __align__(16) u16 t_hi[16][136];
    __shared__ __align__(16) u16 t_lo[16][136];
    int tid = threadIdx.x;
    int wave = tid >> 6, lane = tid & 63;
    int lr = lane & 15, lg = lane >> 4;
    int r0 = blockIdx.x * 16;
    int cb = wave * 32;
    {
        f32x4 acc[2] = {};
        size_t arow = (size_t)(r0 + lr) * CHN + lg * 8;
        for (int ks = 0; ks < CHN; ks += 32) {
            short8 ah = ld_frag(zhi + arow + ks);
            short8 al = ld_frag(zlo + arow + ks);
#pragma unroll
            for (int n = 0; n < 2; ++n) {
                size_t wrow = (size_t)(cb + n * 16 + lr) * CHN + ks + lg * 8;
                short8 wh = ld_frag(w1hi + wrow);
                short8 wl = ld_frag(w1lo + wrow);
                acc[n] = MFMA16(ah, wh, acc[n]);
                acc[n] = MFMA16(al, wh, acc[n]);
                acc[n] = MFMA16(ah, wl, acc[n]);
            }
        }
#pragma unroll
        for (int n = 0; n < 2; ++n) {
            int col = cb + n * 16 + lr;
            float bs = b1[col];
#pragma unroll
            for (int r = 0; r < 4; ++r) {
                float v = fmaxf(acc[n][r] + bs, 0.f);
                u16 hh, ll;
                fsplit(v, hh, ll);
                t_hi[lg * 4 + r][col] = hh;
                t_lo[lg * 4 + r][col] = ll;
            }
        }
    }
    __syncthreads();
    {
        f32x4 acc[2] = {};
        for (int ks = 0; ks < CHN; ks += 32) {
            short8 ah = ld_frag(&t_hi[lr][ks + lg * 8]);
            short8 al = ld_frag(&t_lo[lr][ks + lg * 8]);
#pragma unroll
            for (int n = 0; n < 2; ++n) {
                size_t wrow = (size_t)(cb + n * 16 + lr) * CHN + ks + lg * 8;
                short8 wh = ld_frag(w2hi + wrow);
                short8 wl = ld_frag(w2lo + wrow);
                acc[n] = MFMA16(ah, wh, acc[n]);
                acc[n] = MFMA16(al, wh, acc[n]);
                acc[n] = MFMA16(ah, wl, acc[n]);
            }
        }
#pragma unroll
        for (int n = 0; n < 2; ++n) {
            int col = cb + n * 16 + lr;
            float bs = b2[col], sc = bnsc[col], sh = bnsh[col];
#pragma unroll
            for (int r = 0; r < 4; ++r) {
                int row = r0 + lg * 4 + r;
                size_t oidx = (size_t)row * CHN + col;
                float v = acc[n][r] + bs + resid[oidx];
                h1out[oidx] = v * sc + sh;
            }
        }
    }
}

// ---- fused out-proj + FFN, 16 rows/block, 4 waves col-split -> grid 1024 ----

__global__ __launch_bounds__(256) void k_outffn(
    const u16* __restrict__ aoh, const u16* __restrict__ aol,
    const u16* __restrict__ awh, const u16* __restrict__ awl,
    const float* __restrict__ ab, const float* __restrict__ hres,
    const float* __restrict__ sc1, const float* __restrict__ sh1,
    const float* __restrict__ h1res,
    const u16* __restrict__ w1h, const u16* __restrict__ w1l,
    const float* __restrict__ b1,
    const u16* __restrict__ w2h, const u16* __restrict__ w2l,
    const float* __restrict__ b2,
    const float* __restrict__ sc2, const float* __restrict__ sh2,
    float* __restrict__ hf, u16* __restrict__ hhi, u16* __restrict__ hlo) {
    __shared__ __align__(16) u16 o_hi[16][136];
    __shared__ __align__(16) u16 o_lo[16][136];
    __shared__ __align__(16) u16 t_hi[16][264];
    __shared__ __align__(16) u16 t_lo[16][264];
    int tid = threadIdx.x;
    int wave = tid >> 6, lane = tid & 63;
    int lr = lane & 15, lg = lane >> 4;
    int r0 = blockIdx.x * 16;
    int cb = wave * 32;
    // stage A: out-proj, 16 rows x 32 cols per wave
    {
        f32x4 acc[2] = {};
        size_t arow = (size_t)(r0 + lr) * CHN + lg * 8;
        for (int ks = 0; ks < CHN; ks += 32) {
            short8 ah = ld_frag(aoh + arow + ks);
            short8 al = ld_frag(aol + arow + ks);
#pragma unroll
            for (int n = 0; n < 2; ++n) {
                size_t wrow = (size_t)(cb + n * 16 + lr) * CHN + ks + lg * 8;
                short8 wh = ld_frag(awh + wrow);
                short8 wl = ld_frag(awl + wrow);
                acc[n] = MFMA16(ah, wh, acc[n]);
                acc[n] = MFMA16(al, wh, acc[n]);
                acc[n] = MFMA16(ah, wl, acc[n]);
            }
        }
#pragma unroll
        for (int n = 0; n < 2; ++n) {
            int col = cb + n * 16 + lr;
            float bs = ab[col], sc = sc1[col], sh = sh1[col];
#pragma unroll
            for (int r = 0; r < 4; ++r) {
                int row = r0 + lg * 4 + r;
                int rl = lg * 4 + r;
                size_t oidx = (size_t)row * CHN + col;
                float v = (acc[n][r] + bs + hres[oidx]) * sc + sh + h1res[oidx];
                u16 hh, ll;
                fsplit(v, hh, ll);
                o_hi[rl][col] = hh; o_lo[rl][col] = ll;
            }
        }
    }
    __syncthreads();
    // stage B: FFN up, 16 rows x 64 cols per wave (of 256)
    {
        f32x4 acc[4] = {};
        int cbB = wave * 64;
        for (int ks = 0; ks < CHN; ks += 32) {
            short8 ah = ld_frag(&o_hi[lr][ks + lg * 8]);
            short8 al = ld_frag(&o_lo[lr][ks + lg * 8]);
#pragma unroll
            for (int n = 0; n < 4; ++n) {
                size_t wrow = (size_t)(cbB + n * 16 + lr) * CHN + ks + lg * 8;
                short8 wh = ld_frag(w1h + wrow);
                short8 wl = ld_frag(w1l + wrow);
                acc[n] = MFMA16(ah, wh, acc[n]);
                acc[n] = MFMA16(al, wh, acc[n]);
                acc[n] = MFMA16(ah, wl, acc[n]);
            }
        }
#pragma unroll
        for (int n = 0; n < 4; ++n) {
            int col = cbB + n * 16 + lr;
            float bs = b1[col];
#pragma unroll
            for (int r = 0; r < 4; ++r) {
                float v = fmaxf(acc[n][r] + bs, 0.f);
                u16 hh, ll;
                fsplit(v, hh, ll);
                t_hi[lg * 4 + r][col] = hh;
                t_lo[lg * 4 + r][col] = ll;
            }
        }
    }
    __syncthreads();
    // stage C: FFN down, K=256, 16 rows x 32 cols per wave
    {
        f32x4 acc[2] = {};
        for (int ks = 0; ks < 2 * CHN; ks += 32) {
            short8 ah = ld_frag(&t_hi[lr][ks + lg * 8]);
            short8 al = ld_frag(&t_lo[lr][ks + lg * 8]);
#pragma unroll
            for (int n = 0; n < 2; ++n) {
                size_t wrow = (size_t)(cb + n * 16 + lr) * 2 * CHN + ks + lg * 8;
                short8 wh = ld_frag(w2h + wrow);
                short8 wl = ld_frag(w2l + wrow);
                acc[n] = MFMA16(ah, wh, acc[n]);
                acc[n] = MFMA16(al, wh, acc[n]);
                acc[n] = MFMA16(ah, wl, acc[n]);
            }
        }
#pragma unroll
        for (int n = 0; n < 2; ++n) {
            int col = cb + n * 16 + lr;
            float bs = b2[col], sc = sc2[col], sh = sh2[col];
#pragma unroll
            for (int r = 0; r < 4; ++r) {
                int row = r0 + lg * 4 + r;
                int rl = lg * 4 + r;
                size_t oidx = (size_t)row * CHN + col;
                float ores = bf2f(o_hi[rl][col]) + bf2f(o_lo[rl][col]);
                float v = (acc[n][r] + bs + ores) * sc + sh;
                hf[oidx] = v;
                u16 hh, ll;
                fsplit(v, hh, ll);
                hhi[oidx] = hh; hlo[oidx] = ll;
            }
        }
    }
}

// -------- QKV GEMM; Q is pre-scaled by CL = log2(e)/sqrt(HDIM) --------

__global__ __launch_bounds__(256) void k_qkv(
    const u16* __restrict__ Ahi, const u16* __restrict__ Alo,
    const u16* __restrict__ Whi, const u16* __restrict__ Wlo,
    const float* __restrict__ bias,
    u16* __restrict__ q_hi, u16* __restrict__ q_lo,
    u16* __restrict__ k_hi, u16* __restrict__ k_lo,
    u16* __restrict__ vt_hi) {
    const int K = 128;
    int tid = threadIdx.x;
    int wave = tid >> 6, lane = tid & 63;
    int lr = lane & 15, lg = lane >> 4;
    int r0 = blockIdx.x * 64 + wave * 16;
    int nb = blockIdx.y * 32;
    f32x4 acc[2] = {};
    size_t arow = (size_t)(r0 + lr) * K + lg * 8;
    for (int ks = 0; ks < K; ks += 32) {
        short8 ah = ld_frag(Ahi + arow + ks);
        short8 al = ld_frag(Alo + arow + ks);
#pragma unroll
        for (int n = 0; n < 2; ++n) {
            size_t wrow = (size_t)(nb + n * 16 + lr) * K + ks + lg * 8;
            short8 wh = ld_frag(Whi + wrow);
            short8 wl = ld_frag(Wlo + wrow);
            acc[n] = MFMA16(ah, wh, acc[n]);
            acc[n] = MFMA16(al, wh, acc[n]);
            acc[n] = MFMA16(ah, wl, acc[n]);
        }
    }
#pragma unroll
    for (int n = 0; n < 2; ++n) {
        int col = nb + n * 16 + lr;
        int region = col >> 7;
        int c = col & 127;
        int hh = c >> 5, d = c & 31;
        float bs = bias[col];
#pragma unroll
        for (int r = 0; r < 4; ++r) {
            int row = r0 + lg * 4 + r;
            float v = acc[n][r] + bs;
            int g = row >> 10, p = row & 1023;
            size_t gh = (size_t)(g * NHEAD + hh);
            if (region == 0) {
                u16 vh, vl;
                fsplit(v * CL, vh, vl);   // fold softmax scale into Q
                size_t o = (gh * NPGC + p) * HDIM + d;
                q_hi[o] = vh; q_lo[o] = vl;
            } else if (region == 1) {
                u16 vh, vl;
                fsplit(v, vh, vl);
                size_t o = (gh * NPGC + p) * HDIM + d;
                k_hi[o] = vh; k_lo[o] = vl;
            } else {
                vt_hi[(gh * HDIM + d) * NPGC + p] = f2bf(v);
            }
        }
    }
}

// --- flash attention: swapped QK^T, dual-stream, XCD-swizzled, defer-max softmax ---
// Scores pre-scaled (Q carries CL). Rescale only when a chunk's max exceeds the
// running max by >8 (checked with one __all); fast path has ZERO cross-lane ops.
// P bounded by 2^8=256 (bf16/fp32 safe); l accumulates in-lane, reduced once at end.

__global__ __launch_bounds__(128) void k_attn(
    const u16* __restrict__ qhi, const u16* __restrict__ qlo,
    const u16* __restrict__ khi, const u16* __restrict__ klo,
    const u16* __restrict__ vthi,
    u16* __restrict__ aohi, u16* __restrict__ aolo) {
    __shared__ __align__(16) u16 plds[2][16][136];
    int tid = threadIdx.x;
    int wave = tid >> 6, lane = tid & 63;
    int lr = lane & 15, lg = lane >> 4;
    int id = blockIdx.x;
    int gh = id & 63;           // g*4 + head; id%8==gh%8 -> per-gh XCD locality
    int bx = id >> 6;
    int qA = bx * 64 + wave * 32;
    int qB = qA + 16;
    size_t base = (size_t)gh * NPGC * HDIM;
    size_t vbase = (size_t)gh * HDIM * NPGC;
    short8 qhA = ld_frag(qhi + base + (size_t)(qA + lr) * HDIM + lg * 8);
    short8 qlA = ld_frag(qlo + base + (size_t)(qA + lr) * HDIM + lg * 8);
    short8 qhB = ld_frag(qhi + base + (size_t)(qB + lr) * HDIM + lg * 8);
    short8 qlB = ld_frag(qlo + base + (size_t)(qB + lr) * HDIM + lg * 8);
    const u16* Kh = khi + base;
    const u16* Kl = klo + base;
    const u16* Vh = vthi + vbase;
    f32x4 o0A = {}, o1A = {}, o0B = {}, o1B = {};
    f32x4 lsA = {}, lsB = {};
    float mA = -1e30f, mB = -1e30f;
    const f32x4 zero = {};
    for (int kv = 0; kv < NPGC; kv += 128) {
        f32x4 sA[8], sB[8];
        __builtin_amdgcn_s_setprio(1);
#pragma unroll
        for (int f = 0; f < 8; ++f) {
            size_t kr = (size_t)(kv + f * 16 + lr) * HDIM + lg * 8;
            short8 kh = ld_frag(Kh + kr);
            short8 kl2 = ld_frag(Kl + kr);
            sA[f] = MFMA16(kh, qlA, MFMA16(kl2, qhA, MFMA16(kh, qhA, zero)));
            sB[f] = MFMA16(kh, qlB, MFMA16(kl2, qhB, MFMA16(kh, qhB, zero)));
        }
        __builtin_amdgcn_s_setprio(0);
        // ---- softmax A: defer-max fast path (no cross-lane) ----
        {
            f32x4 mm = sA[0];
#pragma unroll
            for (int f = 1; f < 8; ++f)
#pragma unroll
                for (int i = 0; i < 4; ++i) mm[i] = fmaxf(mm[i], sA[f][i]);
            float mx = fmaxf(fmaxf(mm[0], mm[1]), fmaxf(mm[2], mm[3]));
            if (!__all(mx <= mA + 8.f)) {
                mx = fmaxf(mx, __shfl_xor(mx, 16));
                mx = fmaxf(mx, __shfl_xor(mx, 32));
                float mn = fmaxf(mA, mx);
                float corr = EXP2(mA - mn);
                mA = mn;
#pragma unroll
                for (int i = 0; i < 4; ++i) {
                    lsA[i] *= corr;
                    o0A[i] *= corr; o1A[i] *= corr;
                }
            }
#pragma unroll
            for (int f = 0; f < 8; ++f)
#pragma unroll
                for (int i = 0; i < 4; ++i) sA[f][i] = EXP2(sA[f][i] - mA);
            f32x4 s4 = sA[0];
#pragma unroll
            for (int f = 1; f < 8; ++f)
#pragma unroll
                for (int i = 0; i < 4; ++i) s4[i] += sA[f][i];
            lsA += s4;
#pragma unroll
            for (int f = 0; f < 8; ++f) {
                u32x2 wv;
                wv[0] = cvtpk_bf16(sA[f][0], sA[f][1]);
                wv[1] = cvtpk_bf16(sA[f][2], sA[f][3]);
                *reinterpret_cast<u32x2*>(&plds[wave][lr][f * 16 + lg * 4]) = wv;
            }
        }
        // ---- PV A (V frags kept for B) ----
        short8 vs0[4], vs1[4];
        __builtin_amdgcn_s_setprio(1);
#pragma unroll
        for (int kk = 0; kk < 4; ++kk) {
            short8 pf = ld_frag(&plds[wave][lr][kk * 32 + lg * 8]);
            vs0[kk] = ld_frag(Vh + (size_t)lr * NPGC + kv + kk * 32 + lg * 8);
            vs1[kk] = ld_frag(Vh + (size_t)(16 + lr) * NPGC + kv + kk * 32 + lg * 8);
            o0A = MFMA16(vs0[kk], pf, o0A);
            o1A = MFMA16(vs1[kk], pf, o1A);
        }
        __builtin_amdgcn_s_setprio(0);
        // ---- softmax B (overlaps PV_A drain) ----
        {
            f32x4 mm = sB[0];
#pragma unroll
            for (int f = 1; f < 8; ++f)
#pragma unroll
                for (int i = 0; i < 4; ++i) mm[i] = fmaxf(mm[i], sB[f][i]);
            float mx = fmaxf(fmaxf(mm[0], mm[1]), fmaxf(mm[2], mm[3]));
            if (!__all(mx <= mB + 8.f)) {
                mx = fmaxf(mx, __shfl_xor(mx, 16));
                mx = fmaxf(mx, __shfl_xor(mx, 32));
                float mn = fmaxf(mB, mx);
                float corr = EXP2(mB - mn);
                mB = mn;
#pragma unroll
                for (int i = 0; i < 4; ++i) {
                    lsB[i] *= corr;
                    o0B[i] *= corr; o1B[i] *= corr;
                }
            }
#pragma unroll
            for (int f = 0; f < 8; ++f)
#pragma unroll
                for (int i = 0; i < 4; ++i) sB[f][i] = EXP2(sB[f][i] - mB);
            f32x4 s4 = sB[0];
#pragma unroll
            for (int f = 1; f < 8; ++f)
#pragma unroll
                for (int i = 0; i < 4; ++i) s4[i] += sB[f][i];
            lsB += s4;
            // same-wave DS ordering: PV_A reads complete before these writes land
#pragma unroll
            for (int f = 0; f < 8; ++f) {
                u32x2 wv;
                wv[0] = cvtpk_bf16(sB[f][0], sB[f][1]);
                wv[1] = cvtpk_bf16(sB[f][2], sB[f][3]);
                *reinterpret_cast<u32x2*>(&plds[wave][lr][f * 16 + lg * 4]) = wv;
            }
        }
        // ---- PV B ----
        __builtin_amdgcn_s_setprio(1);
#pragma unroll
        for (int kk = 0; kk < 4; ++kk) {
            short8 pf = ld_frag(&plds[wave][lr][kk * 32 + lg * 8]);
            o0B = MFMA16(vs0[kk], pf, o0B);
            o1B = MFMA16(vs1[kk], pf, o1B);
        }
        __builtin_amdgcn_s_setprio(0);
    }
    // single cross-lane l reduction at the end
    float lA = (lsA[0] + lsA[1]) + (lsA[2] + lsA[3]);
    lA += __shfl_xor(lA, 16);
    lA += __shfl_xor(lA, 32);
    float lB = (lsB[0] + lsB[1]) + (lsB[2] + lsB[3]);
    lB += __shfl_xor(lB, 16);
    lB += __shfl_xor(lB, 32);
    int g = gh >> 2, hh = gh & 3;
    {
        float inv = 1.f / lA;
        size_t obase = ((size_t)g * NPGC + qA + lr) * CHN + hh * HDIM;
        union { u16 u[4]; u64 v; } p0h, p0l, p1h, p1l;
#pragma unroll
        for (int i = 0; i < 4; ++i) {
            u16 a, b;
            fsplit(o0A[i] * inv, a, b); p0h.u[i] = a; p0l.u[i] = b;
            fsplit(o1A[i] * inv, a, b); p1h.u[i] = a; p1l.u[i] = b;
        }
        *reinterpret_cast<u64*>(aohi + obase + lg * 4) = p0h.v;
        *reinterpret_cast<u64*>(aolo + obase + lg * 4) = p0l.v;
        *reinterpret_cast<u64*>(aohi + obase + 16 + lg * 4) = p1h.v;
        *reinterpret_cast<u64*>(aolo + obase + 16 + lg * 4) = p1l.v;
    }
    {
        float inv = 1.f / lB;
        size_t obase = ((size_t)g * NPGC + qB + lr) * CHN + hh * HDIM;
        union { u16 u[4]; u64 v; } p0h, p0l, p1h, p1l;
#pragma unroll
        for (int i = 0; i < 4; ++i) {
            u16 a, b;
            fsplit(o0B[i] * inv, a, b); p0h.u[i] = a; p0l.u[i] = b;
            fsplit(o1B[i] * inv, a, b); p1h.u[i] = a; p1l.u[i] = b;
        }
        *reinterpret_cast<u64*>(aohi + obase + lg * 4) = p0h.v;
        *reinterpret_cast<u64*>(aolo + obase + lg * 4) = p0l.v;
        *reinterpret_cast<u64*>(aohi + obase + 16 + lg * 4) = p1h.v;
        *reinterpret_cast<u64*>(aolo + obase + 16 + lg * 4) = p1l.v;
    }
}

// ---------------- pooling + head MLP ----------------

__global__ __launch_bounds__(128) void k_pool(const float* __restrict__ h,
                                              float* __restrict__ pool) {
    int g = blockIdx.x, sl = blockIdx.y, c = threadIdx.x;
    const float* p = h + ((size_t)g * NPGC + sl * 128) * CHN + c;
    float s = 0.f;
    for (int i = 0; i < 128; ++i) s += p[(size_t)i * CHN];
    atomicAdd(&pool[g * CHN + c], s);
}

__global__ __launch_bounds__(256) void k_head(
    const float* __restrict__ pool, const float* __restrict__ w1,
    const float* __restrict__ b1, const float* __restrict__ w2,
    const float* __restrict__ b2, const float* __restrict__ w3,
    const float* __restrict__ b3, float* __restrict__ out) {
    __shared__ float g1[16][64];
    __shared__ float g2[16][32];
    int t = threadIdx.x;
    for (int idx = t; idx < 16 * 64; idx += 256) {
        int g = idx >> 6, n = idx & 63;
        float s = b1[n];
        for (int k = 0; k < 128; ++k) s += pool[g * 128 + k] * w1[n * 128 + k];
        g1[g][n] = fmaxf(s, 0.f);
    }
    __syncthreads();
    for (int idx = t; idx < 16 * 32; idx += 256) {
        int g = idx >> 5, n = idx & 31;
        float s = b2[n];
        for (int k = 0; k < 64; ++k) s += g1[g][k] * w2[n * 64 + k];
        g2[g][n] = fmaxf(s, 0.f);
    }
    __syncthreads();
    if (t < 16) {
        float s = b3[0];
        for (int k = 0; k < 32; ++k) s += g2[t][k] * w3[k];
        out[t] = s;
    }
}

// ---------------- host ----------------

extern "C" void kernel_launch(void* const* d_in, const int* in_sizes, int n_in,
                              void* d_out, int out_size, void* d_ws, size_t ws_size,
                              hipStream_t stream) {
    (void)in_sizes; (void)n_in; (void)out_size; (void)ws_size;
    const float* x = (const float*)d_in[0];
    const float* edge_attr = (const float*)d_in[1];
    const int* edge_index = (const int*)d_in[2];
    const float* node_w = (const float*)d_in[4];
    const float* node_b = (const float*)d_in[5];
    const float* edge_w = (const float*)d_in[6];
    const float* edge_b = (const float*)d_in[7];
    const float* gine_w1 = (const float*)d_in[8];
    const float* gine_b1 = (const float*)d_in[9];
    const float* gine_w2 = (const float*)d_in[10];
    const float* gine_b2 = (const float*)d_in[11];
    const float* attn_in_w = (const float*)d_in[12];
    const float* attn_in_b = (const float*)d_in[13];
    const float* attn_out_w = (const float*)d_in[14];
    const float* attn_out_b = (const float*)d_in[15];
    const float* mlp_w1 = (const float*)d_in[16];
    const float* mlp_b1 = (const float*)d_in[17];
    const float* mlp_w2 = (const float*)d_in[18];
    const float* mlp_b2 = (const float*)d_in[19];
    const float* bn_g = (const float*)d_in[20];
    const float* bn_bb = (const float*)d_in[21];
    const float* bn_m = (const float*)d_in[22];
    const float* bn_v = (const float*)d_in[23];
    const float* head_w1 = (const float*)d_in[24];
    const float* head_b1 = (const float*)d_in[25];
    const float* head_w2 = (const float*)d_in[26];
    const float* head_b2 = (const float*)d_in[27];
    const float* head_w3 = (const float*)d_in[28];
    const float* head_b3 = (const float*)d_in[29];

    char* ws = (char*)d_ws;
    size_t off = 0;
    auto alloc = [&](size_t bytes) {
        size_t r = off;
        off = (off + bytes + 255) & ~(size_t)255;
        return r;
    };
    const size_t NC = (size_t)NODES * CHN;
    float* h_f32 = (float*)(ws + alloc(NC * 4));
    u16* h_hi = (u16*)(ws + alloc(NC * 2));
    u16* h_lo = (u16*)(ws + alloc(NC * 2));
    u16* x_hi = (u16*)(ws + alloc((size_t)NODES * 64 * 2));
    u16* x_lo = (u16*)(ws + alloc((size_t)NODES * 64 * 2));
    u16* zao_hi = (u16*)(ws + alloc(NC * 2));
    u16* zao_lo = (u16*)(ws + alloc(NC * 2));
    float* h1_f32 = (float*)(ws + alloc(NC * 4));
    u16* q_hi = (u16*)(ws + alloc(NC * 2));
    u16* q_lo = (u16*)(ws + alloc(NC * 2));
    u16* kk_hi = (u16*)(ws + alloc(NC * 2));
    u16* kk_lo = (u16*)(ws + alloc(NC * 2));
    u16* vt_hi = (u16*)(ws + alloc(NC * 2));
    float* pool = (float*)(ws + alloc(NG * CHN * 4));
    u16* node_w_hi = (u16*)(ws + alloc(CHN * 64 * 2));
    u16* node_w_lo = (u16*)(ws + alloc(CHN * 64 * 2));
    u16* gw1_hi = (u16*)(ws + alloc((size_t)NLAYER * CHN * CHN * 2));
    u16* gw1_lo = (u16*)(ws + alloc((size_t)NLAYER * CHN * CHN * 2));
    u16* gw2_hi = (u16*)(ws + alloc((size_t)NLAYER * CHN * CHN * 2));
    u16* gw2_lo = (u16*)(ws + alloc((size_t)NLAYER * CHN * CHN * 2));
    u16* aiw_hi = (u16*)(ws + alloc((size_t)NLAYER * 3 * CHN * CHN * 2));
    u16* aiw_lo = (u16*)(ws + alloc((size_t)NLAYER * 3 * CHN * CHN * 2));
    u16* aow_hi = (u16*)(ws + alloc((size_t)NLAYER * CHN * CHN * 2));
    u16* aow_lo = (u16*)(ws + alloc((size_t)NLAYER * CHN * CHN * 2));
    u16* mw1_hi = (u16*)(ws + alloc((size_t)NLAYER * 2 * CHN * CHN * 2));
    u16* mw1_lo = (u16*)(ws + alloc((size_t)NLAYER * 2 * CHN * CHN * 2));
    u16* mw2_hi = (u16*)(ws + alloc((size_t)NLAYER * 2 * CHN * CHN * 2));
    u16* mw2_lo = (u16*)(ws + alloc((size_t)NLAYER * 2 * CHN * CHN * 2));
    float* bn_scale = (float*)(ws + alloc(NLAYER * 3 * CHN * 4));
    float* bn_shift = (float*)(ws + alloc(NLAYER * 3 * CHN * 4));
    u32* counts = (u32*)(ws + alloc(NODES * 4));
    u32* offsets = (u32*)(ws + alloc((NODES + 1) * 4));
    u32* cursor = (u32*)(ws + alloc(NODES * 4));
    int* csr_src = (int*)(ws + alloc((size_t)NEDGE * 4));
    float* csr_a = (float*)(ws + alloc((size_t)NEDGE * 4));

    const int* e_src = edge_index;
    const int* e_dst = edge_index + NEDGE;

    {
        SplitJobs j;
        const float* srcs[8] = {x, node_w, gine_w1, gine_w2, attn_in_w,
                                attn_out_w, mlp_w1, mlp_w2};
        u16* his[8] = {x_hi, node_w_hi, gw1_hi, gw2_hi, aiw_hi, aow_hi, mw1_hi, mw2_hi};
        u16* los[8] = {x_lo, node_w_lo, gw1_lo, gw2_lo, aiw_lo, aow_lo, mw1_lo, mw2_lo};
        int ns[8] = {NODES * 64, CHN * 64, NLAYER * CHN * CHN, NLAYER * CHN * CHN,
                     NLAYER * 3 * CHN * CHN, NLAYER * CHN * CHN,
                     NLAYER * 2 * CHN * CHN, NLAYER * 2 * CHN * CHN};
        int cum = 0;
        for (int i = 0; i < 8; ++i) {
            j.src[i] = srcs[i]; j.hi[i] = his[i]; j.lo[i] = los[i];
            cum += ns[i] / 256;
            j.blk_end[i] = cum;
        }
        k_split8<<<dim3(cum), dim3(256), 0, stream>>>(j);
    }

    k_bnprep<<<dim3((NLAYER * 3 * CHN + 255) / 256), dim3(256), 0, stream>>>(
        bn_g, bn_bb, bn_m, bn_v, bn_scale, bn_shift);

    k_zero_u32<<<dim3(NODES / 256), dim3(256), 0, stream>>>(counts, NODES);
    k_count<<<dim3(NEDGE / 256), dim3(256), 0, stream>>>(e_dst, counts);
    k_scan<<<dim3(1), dim3(256), 0, stream>>>(counts, offsets, cursor);
    k_fill<<<dim3(NEDGE / 256), dim3(256), 0, stream>>>(e_src, e_dst, edge_attr,
                                                        cursor, csr_src, csr_a);

    // node projection: h = x @ node_w^T + node_b
    k_gemm<<<dim3(NODES / 64, CHN / 32), dim3(256), 0, stream>>>(
        x_hi, x_lo, node_w_hi, node_w_lo, node_b, h_f32, h_hi, h_lo, 64, CHN);

    for (int l = 0; l < NLAYER; ++l) {
        size_t wo = (size_t)l * CHN * CHN;
        const float* sc0 = bn_scale + (l * 3 + 0) * CHN;
        const float* sh0 = bn_shift + (l * 3 + 0) * CHN;
        const float* sc1 = bn_scale + (l * 3 + 1) * CHN;
        const float* sh1 = bn_shift + (l * 3 + 1) * CHN;
        const float* sc2 = bn_scale + (l * 3 + 2) * CHN;
        const float* sh2 = bn_shift + (l * 3 + 2) * CHN;

        k_agg<<<dim3(NODES), dim3(64), 0, stream>>>(h_hi, h_f32, offsets, csr_src,
                                                    csr_a, edge_w, edge_b,
                                                    zao_hi, zao_lo);
        k_gine<<<dim3(NODES / 16), dim3(256), 0, stream>>>(
            zao_hi, zao_lo, gw1_hi + wo, gw1_lo + wo, gine_b1 + l * CHN,
            gw2_hi + wo, gw2_lo + wo, gine_b2 + l * CHN, h_f32, sc0, sh0, h1_f32);
        k_qkv<<<dim3(NODES / 64, 12), dim3(256), 0, stream>>>(
            h_hi, h_lo, aiw_hi + wo * 3, aiw_lo + wo * 3, attn_in_b + l * 3 * CHN,
            q_hi, q_lo, kk_hi, kk_lo, vt_hi);
        k_attn<<<dim3(16 * NG * NHEAD), dim3(128), 0, stream>>>(
            q_hi, q_lo, kk_hi, kk_lo, vt_hi, zao_hi, zao_lo);
        k_outffn<<<dim3(NODES / 16), dim3(256), 0, stream>>>(
            zao_hi, zao_lo, aow_hi + wo, aow_lo + wo, attn_out_b + l * CHN,
            h_f32, sc1, sh1, h1_f32,
            mw1_hi + wo * 2, mw1_lo + wo * 2, mlp_b1 + l * 2 * CHN,
            mw2_hi + wo * 2, mw2_lo + wo * 2, mlp_b2 + l * CHN, sc2, sh2,
            h_f32, h_hi, h_lo);
    }

    k_zero_u32<<<dim3(NG * CHN / 256), dim3(256), 0, stream>>>((u32*)pool, NG * CHN);
    k_pool<<<dim3(NG, 8), dim3(128), 0, stream>>>(h_f32, pool);
    k_head<<<dim3(1), dim3(256), 0, stream>>>(pool, head_w1, head_b1, head_w2,
                                              head_b2, head_w3, head_b3,
                                              (float*)d_out);
}

// Round 11
// 770.514 us; speedup vs baseline: 1.4916x; 1.1227x over previous
//
#include <hip/hip_runtime.h>
#include <hip/hip_bf16.h>

typedef __attribute__((ext_vector_type(8))) short short8;
typedef __attribute__((ext_vector_type(4))) float f32x4;
typedef __attribute__((ext_vector_type(2))) unsigned int u32x2;
typedef unsigned short u16;
typedef unsigned int u32;
typedef unsigned long long u64;

#define NODES 16384
#define CHN 128
#define NEDGE 524288
#define NG 16
#define NPGC 1024
#define NHEAD 4
#define HDIM 32
#define NLAYER 4
#define CL 0.2550348281f   // log2(e)/sqrt(HDIM), folded into Q at QKV store

#if __has_builtin(__builtin_amdgcn_exp2f)
#define EXP2(x) __builtin_amdgcn_exp2f(x)
#else
#define EXP2(x) exp2f(x)
#endif

__device__ __forceinline__ float bf2f(u16 u) {
    union { u32 u; float f; } c; c.u = ((u32)u) << 16; return c.f;
}
__device__ __forceinline__ u16 f2bf(float f) {
    union { float f; u32 u; } c; c.f = f;
    u32 r = c.u + 0x7fffu + ((c.u >> 16) & 1u);
    return (u16)(r >> 16);
}
__device__ __forceinline__ void fsplit(float f, u16& hi, u16& lo) {
    u16 h = f2bf(f);
    hi = h;
    lo = f2bf(f - bf2f(h));
}
__device__ __forceinline__ u32 cvtpk_bf16(float a, float b) {
    u32 r;
    asm("v_cvt_pk_bf16_f32 %0, %1, %2" : "=v"(r) : "v"(a), "v"(b));
    return r;
}

#define MFMA16(a, b, c) __builtin_amdgcn_mfma_f32_16x16x32_bf16((a), (b), (c), 0, 0, 0)

__device__ __forceinline__ short8 ld_frag(const u16* p) {
    return *reinterpret_cast<const short8*>(p);
}

// ---------------- setup kernels ----------------

struct SplitJobs {
    const float* src[8];
    u16* hi[8];
    u16* lo[8];
    int blk_end[8];
};

__global__ void k_split8(SplitJobs jobs) {
    int b = blockIdx.x;
    int seg = 0;
    while (b >= jobs.blk_end[seg]) ++seg;
    int base = seg ? jobs.blk_end[seg - 1] : 0;
    int i = (b - base) * 256 + threadIdx.x;
    u16 h, l;
    fsplit(jobs.src[seg][i], h, l);
    jobs.hi[seg][i] = h;
    jobs.lo[seg][i] = l;
}

__global__ void k_bnprep(const float* __restrict__ g, const float* __restrict__ b,
                         const float* __restrict__ m, const float* __restrict__ v,
                         float* __restrict__ scale, float* __restrict__ shift) {
    int i = blockIdx.x * 256 + threadIdx.x;
    if (i < NLAYER * 3 * CHN) {
        float s = g[i] * rsqrtf(v[i] + 1e-5f);
        scale[i] = s;
        shift[i] = b[i] - m[i] * s;
    }
}

__global__ void k_zero_u32(u32* __restrict__ p, int n) {
    int i = blockIdx.x * 256 + threadIdx.x;
    if (i < n) p[i] = 0u;
}

__global__ void k_count(const int* __restrict__ dst, u32* __restrict__ counts) {
    int e = blockIdx.x * 256 + threadIdx.x;
    if (e < NEDGE) atomicAdd(&counts[dst[e]], 1u);
}

__global__ void k_scan(const u32* __restrict__ counts, u32* __restrict__ offsets,
                       u32* __restrict__ cursor) {
    __shared__ u32 part[256];
    int t = threadIdx.x;
    int base = t * 64;
    u32 s = 0;
    for (int i = 0; i < 64; ++i) s += counts[base + i];
    part[t] = s;
    __syncthreads();
    for (int off = 1; off < 256; off <<= 1) {
        u32 val = (t >= off) ? part[t - off] : 0u;
        __syncthreads();
        part[t] += val;
        __syncthreads();
    }
    u32 run = (t == 0) ? 0u : part[t - 1];
    for (int i = 0; i < 64; ++i) {
        offsets[base + i] = run;
        cursor[base + i] = run;
        run += counts[base + i];
    }
    if (t == 255) offsets[NODES] = run;
}

__global__ void k_fill(const int* __restrict__ src, const int* __restrict__ dst,
                       const float* __restrict__ eattr, u32* __restrict__ cursor,
                       int* __restrict__ csr_src, float* __restrict__ csr_a) {
    int e = blockIdx.x * 256 + threadIdx.x;
    if (e >= NEDGE) return;
    int d = dst[e];
    u32 p = atomicAdd(&cursor[d], 1u);
    csr_src[p] = src[e];
    csr_a[p] = eattr[e];
}

// ------ GINE aggregation, software-pipelined gather ------

__global__ __launch_bounds__(64) void k_agg(
    const u16* __restrict__ h_hi, const float* __restrict__ h_f32,
    const u32* __restrict__ offsets, const int* __restrict__ csr_src,
    const float* __restrict__ csr_a, const float* __restrict__ ew,
    const float* __restrict__ eb, u16* __restrict__ z_hi, u16* __restrict__ z_lo) {
    int node = blockIdx.x;
    int t = threadIdx.x;
    int c0 = t * 2;
    float w0 = ew[c0], w1 = ew[c0 + 1];
    float b0 = eb[c0], b1 = eb[c0 + 1];
    u32 beg = offsets[node], end = offsets[node + 1];
    float acc0 = 0.f, acc1 = 0.f;
    u32 n = end - beg;
    if (n) {
        int sa = csr_src[beg];
        float aa = csr_a[beg];
        u32 ua = *reinterpret_cast<const u32*>(h_hi + (size_t)sa * CHN + c0);
        u32 j1 = (n > 1) ? beg + 1 : beg;
        int sb = csr_src[j1];
        float ab = csr_a[j1];
        for (u32 i = 0; i < n; ++i) {
            u32 jn = beg + i + 2;
            jn = jn < end ? jn : end - 1;
            int sc2 = csr_src[jn];
            float ac = csr_a[jn];
            u32 ub = *reinterpret_cast<const u32*>(h_hi + (size_t)sb * CHN + c0);
            float f0 = bf2f((u16)(ua & 0xffffu));
            float f1 = bf2f((u16)(ua >> 16));
            acc0 += fmaxf(f0 + aa * w0 + b0, 0.f);
            acc1 += fmaxf(f1 + aa * w1 + b1, 0.f);
            ua = ub; aa = ab;
            sb = sc2; ab = ac;
        }
    }
    size_t idx = (size_t)node * CHN + c0;
    float z0 = h_f32[idx] + acc0;
    float z1v = h_f32[idx + 1] + acc1;
    u16 h, l;
    fsplit(z0, h, l); z_hi[idx] = h; z_lo[idx] = l;
    fsplit(z1v, h, l); z_hi[idx + 1] = h; z_lo[idx + 1] = l;
}

// ------ split GEMM (16x32 wave tile) — used for node projection ------

__global__ __launch_bounds__(256) void k_gemm(
    const u16* __restrict__ Ahi, const u16* __restrict__ Alo,
    const u16* __restrict__ Whi, const u16* __restrict__ Wlo,
    const float* __restrict__ bias, float* __restrict__ out_f32,
    u16* __restrict__ out_hi, u16* __restrict__ out_lo, int K, int Nc) {
    int tid = threadIdx.x;
    int wave = tid >> 6, lane = tid & 63;
    int lr = lane & 15, lg = lane >> 4;
    int r0 = blockIdx.x * 64 + wave * 16;
    int nb = blockIdx.y * 32;
    f32x4 acc[2] = {};
    size_t arow = (size_t)(r0 + lr) * K + lg * 8;
    for (int ks = 0; ks < K; ks += 32) {
        short8 ah = ld_frag(Ahi + arow + ks);
        short8 al = ld_frag(Alo + arow + ks);
#pragma unroll
        for (int n = 0; n < 2; ++n) {
            size_t wrow = (size_t)(nb + n * 16 + lr) * K + ks + lg * 8;
            short8 wh = ld_frag(Whi + wrow);
            short8 wl = ld_frag(Wlo + wrow);
            acc[n] = MFMA16(ah, wh, acc[n]);
            acc[n] = MFMA16(al, wh, acc[n]);
            acc[n] = MFMA16(ah, wl, acc[n]);
        }
    }
#pragma unroll
    for (int n = 0; n < 2; ++n) {
        int col = nb + n * 16 + lr;
        float bs = bias[col];
#pragma unroll
        for (int r = 0; r < 4; ++r) {
            int row = r0 + lg * 4 + r;
            size_t oidx = (size_t)row * Nc + col;
            float v = acc[n][r] + bs;
            out_f32[oidx] = v;
            u16 hh, ll;
            fsplit(v, hh, ll);
            out_hi[oidx] = hh; out_lo[oidx] = ll;
        }
    }
}

// ---- fused GINE MLP: h1 = bn(relu(z@W1+b1)@W2 + b2 + h) ----
// 32 rows/block, 4 waves col-split; each wave computes 2 row-groups sharing
// weight fragments (6 MFMA per wh/wl load) -> grid NODES/32 = 512.

__global__ __launch_bounds__(256) void k_gine(
    const u16* __restrict__ zhi, const u16* __restrict__ zlo,
    const u16* __restrict__ w1hi, const u16* __restrict__ w1lo,
    const float* __restrict__ b1,
    const u16* __restrict__ w2hi, const u16* __restrict__ w2lo,
    const float* __restrict__ b2, const float* __restrict__ resid,
    const float* __restrict__ bnsc, const float* __restrict__ bnsh,
    float* __restrict__ h1out) {
    __shared__ __align__(16) u16 t_hi[32][136];
    __shared__ __align__(16) u16 t_lo[32][136];
    int tid = threadIdx.x;
    int wave = tid >> 6, lane = tid & 63;
    int lr = lane & 15, lg = lane >> 4;
    int r0 = blockIdx.x * 32;
    int cb = wave * 32;
    {
        f32x4 acc[2][2] = {};
        size_t arow0 = (size_t)(r0 + lr) * CHN + lg * 8;
        size_t arow1 = (size_t)(r0 + 16 + lr) * CHN + lg * 8;
        for (int ks = 0; ks < CHN; ks += 32) {
            short8 ah0 = ld_frag(zhi + arow0 + ks);
            short8 al0 = ld_frag(zlo + arow0 + ks);
            short8 ah1 = ld_frag(zhi + arow1 + ks);
            short8 al1 = ld_frag(zlo + arow1 + ks);
#pragma unroll
            for (int n = 0; n < 2; ++n) {
                size_t wrow = (size_t)(cb + n * 16 + lr) * CHN + ks + lg * 8;
                short8 wh = ld_frag(w1hi + wrow);
                short8 wl = ld_frag(w1lo + wrow);
                acc[0][n] = MFMA16(ah0, wh, acc[0][n]);
                acc[0][n] = MFMA16(al0, wh, acc[0][n]);
                acc[0][n] = MFMA16(ah0, wl, acc[0][n]);
                acc[1][n] = MFMA16(ah1, wh, acc[1][n]);
                acc[1][n] = MFMA16(al1, wh, acc[1][n]);
                acc[1][n] = MFMA16(ah1, wl, acc[1][n]);
            }
        }
#pragma unroll
        for (int rg = 0; rg < 2; ++rg)
#pragma unroll
            for (int n = 0; n < 2; ++n) {
                int col = cb + n * 16 + lr;
                float bs = b1[col];
#pragma unroll
                for (int r = 0; r < 4; ++r) {
                    float v = fmaxf(acc[rg][n][r] + bs, 0.f);
                    u16 hh, ll;
                    fsplit(v, hh, ll);
                    int rl = rg * 16 + lg * 4 + r;
                    t_hi[rl][col] = hh;
                    t_lo[rl][col] = ll;
                }
            }
    }
    __syncthreads();
    {
        f32x4 acc[2][2] = {};
        for (int ks = 0; ks < CHN; ks += 32) {
            short8 ah0 = ld_frag(&t_hi[lr][ks + lg * 8]);
            short8 al0 = ld_frag(&t_lo[lr][ks + lg * 8]);
            short8 ah1 = ld_frag(&t_hi[16 + lr][ks + lg * 8]);
            short8 al1 = ld_frag(&t_lo[16 + lr][ks + lg * 8]);
#pragma unroll
            for (int n = 0; n < 2; ++n) {
                size_t wrow = (size_t)(cb + n * 16 + lr) * CHN + ks + lg * 8;
                short8 wh = ld_frag(w2hi + wrow);
                short8 wl = ld_frag(w2lo + wrow);
                acc[0][n] = MFMA16(ah0, wh, acc[0][n]);
                acc[0][n] = MFMA16(al0, wh, acc[0][n]);
                acc[0][n] = MFMA16(ah0, wl, acc[0][n]);
                acc[1][n] = MFMA16(ah1, wh, acc[1][n]);
                acc[1][n] = MFMA16(al1, wh, acc[1][n]);
                acc[1][n] = MFMA16(ah1, wl, acc[1][n]);
            }
        }
#pragma unroll
        for (int rg = 0; rg < 2; ++rg)
#pragma unroll
            for (int n = 0; n < 2; ++n) {
                int col = cb + n * 16 + lr;
                float bs = b2[col], sc = bnsc[col], sh = bnsh[col];
#pragma unroll
                for (int r = 0; r < 4; ++r) {
                    int row = r0 + rg * 16 + lg * 4 + r;
                    size_t oidx = (size_t)row * CHN + col;
                    float v = acc[rg][n][r] + bs + resid[oidx];
                    h1out[oidx] = v * sc + sh;
                }
            }
    }
}

// ---- fused out-proj + FFN, 32 rows/block, weight frags shared across 2 row-groups ----

__global__ __launch_bounds__(256) void k_outffn(
    const u16* __restrict__ aoh, const u16* __restrict__ aol,
    const u16* __restrict__ awh, const u16* __restrict__ awl,
    const float* __restrict__ ab, const float* __restrict__ hres,
    const float* __restrict__ sc1, const float* __restrict__ sh1,
    const float* __restrict__ h1res,
    const u16* __restrict__ w1h, const u16* __restrict__ w1l,
    const float* __restrict__ b1,
    const u16* __restrict__ w2h, const u16* __restrict__ w2l,
    const float* __restrict__ b2,
    const float* __restrict__ sc2, const float* __restrict__ sh2,
    float* __restrict__ hf, u16* __restrict__ hhi, u16* __restrict__ hlo) {
    __shared__ __align__(16) u16 o_hi[32][136];
    __shared__ __align__(16) u16 o_lo[32][136];
    __shared__ __align__(16) u16 t_hi[32][264];
    __shared__ __align__(16) u16 t_lo[32][264];
    int tid = threadIdx.x;
    int wave = tid >> 6, lane = tid & 63;
    int lr = lane & 15, lg = lane >> 4;
    int r0 = blockIdx.x * 32;
    int cb = wave * 32;
    // stage A: out-proj, 32 rows x 32 cols per wave (weights shared across row-groups)
    {
        f32x4 acc[2][2] = {};
        size_t arow0 = (size_t)(r0 + lr) * CHN + lg * 8;
        size_t arow1 = (size_t)(r0 + 16 + lr) * CHN + lg * 8;
        for (int ks = 0; ks < CHN; ks += 32) {
            short8 ah0 = ld_frag(aoh + arow0 + ks);
            short8 al0 = ld_frag(aol + arow0 + ks);
            short8 ah1 = ld_frag(aoh + arow1 + ks);
            short8 al1 = ld_frag(aol + arow1 + ks);
#pragma unroll
            for (int n = 0; n < 2; ++n) {
                size_t wrow = (size_t)(cb + n * 16 + lr) * CHN + ks + lg * 8;
                short8 wh = ld_frag(awh + wrow);
                short8 wl = ld_frag(awl + wrow);
                acc[0][n] = MFMA16(ah0, wh, acc[0][n]);
                acc[0][n] = MFMA16(al0, wh, acc[0][n]);
                acc[0][n] = MFMA16(ah0, wl, acc[0][n]);
                acc[1][n] = MFMA16(ah1, wh, acc[1][n]);
                acc[1][n] = MFMA16(al1, wh, acc[1][n]);
                acc[1][n] = MFMA16(ah1, wl, acc[1][n]);
            }
        }
#pragma unroll
        for (int rg = 0; rg < 2; ++rg)
#pragma unroll
            for (int n = 0; n < 2; ++n) {
                int col = cb + n * 16 + lr;
                float bs = ab[col], sc = sc1[col], sh = sh1[col];
#pragma unroll
                for (int r = 0; r < 4; ++r) {
                    int row = r0 + rg * 16 + lg * 4 + r;
                    int rl = rg * 16 + lg * 4 + r;
                    size_t oidx = (size_t)row * CHN + col;
                    float v = (acc[rg][n][r] + bs + hres[oidx]) * sc + sh + h1res[oidx];
                    u16 hh, ll;
                    fsplit(v, hh, ll);
                    o_hi[rl][col] = hh; o_lo[rl][col] = ll;
                }
            }
    }
    __syncthreads();
    // stage B: FFN up, 32 rows x 64 cols per wave (of 256)
    {
        f32x4 acc[2][4] = {};
        int cbB = wave * 64;
        for (int ks = 0; ks < CHN; ks += 32) {
            short8 ah0 = ld_frag(&o_hi[lr][ks + lg * 8]);
            short8 al0 = ld_frag(&o_lo[lr][ks + lg * 8]);
            short8 ah1 = ld_frag(&o_hi[16 + lr][ks + lg * 8]);
            short8 al1 = ld_frag(&o_lo[16 + lr][ks + lg * 8]);
#pragma unroll
            for (int n = 0; n < 4; ++n) {
                size_t wrow = (size_t)(cbB + n * 16 + lr) * CHN + ks + lg * 8;
                short8 wh = ld_frag(w1h + wrow);
                short8 wl = ld_frag(w1l + wrow);
                acc[0][n] = MFMA16(ah0, wh, acc[0][n]);
                acc[0][n] = MFMA16(al0, wh, acc[0][n]);
                acc[0][n] = MFMA16(ah0, wl, acc[0][n]);
                acc[1][n] = MFMA16(ah1, wh, acc[1][n]);
                acc[1][n] = MFMA16(al1, wh, acc[1][n]);
                acc[1][n] = MFMA16(ah1, wl, acc[1][n]);
            }
        }
#pragma unroll
        for (int rg = 0; rg < 2; ++rg)
#pragma unroll
            for (int n = 0; n < 4; ++n) {
                int col = cbB + n * 16 + lr;
                float bs = b1[col];
#pragma unroll
                for (int r = 0; r < 4; ++r) {
                    float v = fmaxf(acc[rg][n][r] + bs, 0.f);
                    u16 hh, ll;
                    fsplit(v, hh, ll);
                    int rl = rg * 16 + lg * 4 + r;
                    t_hi[rl][col] = hh;
                    t_lo[rl][col] = ll;
                }
            }
    }
    __syncthreads();
    // stage C: FFN down, K=256, 32 rows x 32 cols per wave
    {
        f32x4 acc[2][2] = {};
        for (int ks = 0; ks < 2 * CHN; ks += 32) {
            short8 ah0 = ld_frag(&t_hi[lr][ks + lg * 8]);
            short8 al0 = ld_frag(&t_lo[lr][ks + lg * 8]);
            short8 ah1 = ld_frag(&t_hi[16 + lr][ks + lg * 8]);
            short8 al1 = ld_frag(&t_lo[16 + lr][ks + lg * 8]);
#pragma unroll
            for (int n = 0; n < 2; ++n) {
                size_t wrow = (size_t)(cb + n * 16 + lr) * 2 * CHN + ks + lg * 8;
                short8 wh = ld_frag(w2h + wrow);
                short8 wl = ld_frag(w2l + wrow);
                acc[0][n] = MFMA16(ah0, wh, acc[0][n]);
                acc[0][n] = MFMA16(al0, wh, acc[0][n]);
                acc[0][n] = MFMA16(ah0, wl, acc[0][n]);
                acc[1][n] = MFMA16(ah1, wh, acc[1][n]);
                acc[1][n] = MFMA16(al1, wh, acc[1][n]);
                acc[1][n] = MFMA16(ah1, wl, acc[1][n]);
            }
        }
#pragma unroll
        for (int rg = 0; rg < 2; ++rg)
#pragma unroll
            for (int n = 0; n < 2; ++n) {
                int col = cb + n * 16 + lr;
                float bs = b2[col], sc = sc2[col], sh = sh2[col];
#pragma unroll
                for (int r = 0; r < 4; ++r) {
                    int row = r0 + rg * 16 + lg * 4 + r;
                    int rl = rg * 16 + lg * 4 + r;
                    size_t oidx = (size_t)row * CHN + col;
                    float ores = bf2f(o_hi[rl][col]) + bf2f(o_lo[rl][col]);
                    float v = (acc[rg][n][r] + bs + ores) * sc + sh;
                    hf[oidx] = v;
                    u16 hh, ll;
                    fsplit(v, hh, ll);
                    hhi[oidx] = hh; hlo[oidx] = ll;
                }
            }
    }
}

// -------- QKV GEMM; Q is pre-scaled by CL = log2(e)/sqrt(HDIM) --------

__global__ __launch_bounds__(256) void k_qkv(
    const u16* __restrict__ Ahi, const u16* __restrict__ Alo,
    const u16* __restrict__ Whi, const u16* __restrict__ Wlo,
    const float* __restrict__ bias,
    u16* __restrict__ q_hi, u16* __restrict__ q_lo,
    u16* __restrict__ k_hi, u16* __restrict__ k_lo,
    u16* __restrict__ vt_hi) {
    const int K = 128;
    int tid = threadIdx.x;
    int wave = tid >> 6, lane = tid & 63;
    int lr = lane & 15, lg = lane >> 4;
    int r0 = blockIdx.x * 64 + wave * 16;
    int nb = blockIdx.y * 32;
    f32x4 acc[2] = {};
    size_t arow = (size_t)(r0 + lr) * K + lg * 8;
    for (int ks = 0; ks < K; ks += 32) {
        short8 ah = ld_frag(Ahi + arow + ks);
        short8 al = ld_frag(Alo + arow + ks);
#pragma unroll
        for (int n = 0; n < 2; ++n) {
            size_t wrow = (size_t)(nb + n * 16 + lr) * K + ks + lg * 8;
            short8 wh = ld_frag(Whi + wrow);
            short8 wl = ld_frag(Wlo + wrow);
            acc[n] = MFMA16(ah, wh, acc[n]);
            acc[n] = MFMA16(al, wh, acc[n]);
            acc[n] = MFMA16(ah, wl, acc[n]);
        }
    }
#pragma unroll
    for (int n = 0; n < 2; ++n) {
        int col = nb + n * 16 + lr;
        int region = col >> 7;
        int c = col & 127;
        int hh = c >> 5, d = c & 31;
        float bs = bias[col];
#pragma unroll
        for (int r = 0; r < 4; ++r) {
            int row = r0 + lg * 4 + r;
            float v = acc[n][r] + bs;
            int g = row >> 10, p = row & 1023;
            size_t gh = (size_t)(g * NHEAD + hh);
            if (region == 0) {
                u16 vh, vl;
                fsplit(v * CL, vh, vl);   // fold softmax scale into Q
                size_t o = (gh * NPGC + p) * HDIM + d;
                q_hi[o] = vh; q_lo[o] = vl;
            } else if (region == 1) {
                u16 vh, vl;
                fsplit(v, vh, vl);
                size_t o = (gh * NPGC + p) * HDIM + d;
                k_hi[o] = vh; k_lo[o] = vl;
            } else {
                vt_hi[(gh * HDIM + d) * NPGC + p] = f2bf(v);
            }
        }
    }
}

// --- flash attention: swapped QK^T, dual-stream, XCD-swizzled, defer-max softmax ---

__global__ __launch_bounds__(128) void k_attn(
    const u16* __restrict__ qhi, const u16* __restrict__ qlo,
    const u16* __restrict__ khi, const u16* __restrict__ klo,
    const u16* __restrict__ vthi,
    u16* __restrict__ aohi, u16* __restrict__ aolo) {
    __shared__ __align__(16) u16 plds[2][16][136];
    int tid = threadIdx.x;
    int wave = tid >> 6, lane = tid & 63;
    int lr = lane & 15, lg = lane >> 4;
    int id = blockIdx.x;
    int gh = id & 63;           // g*4 + head; id%8==gh%8 -> per-gh XCD locality
    int bx = id >> 6;
    int qA = bx * 64 + wave * 32;
    int qB = qA + 16;
    size_t base = (size_t)gh * NPGC * HDIM;
    size_t vbase = (size_t)gh * HDIM * NPGC;
    short8 qhA = ld_frag(qhi + base + (size_t)(qA + lr) * HDIM + lg * 8);
    short8 qlA = ld_frag(qlo + base + (size_t)(qA + lr) * HDIM + lg * 8);
    short8 qhB = ld_frag(qhi + base + (size_t)(qB + lr) * HDIM + lg * 8);
    short8 qlB = ld_frag(qlo + base + (size_t)(qB + lr) * HDIM + lg * 8);
    const u16* Kh = khi + base;
    const u16* Kl = klo + base;
    const u16* Vh = vthi + vbase;
    f32x4 o0A = {}, o1A = {}, o0B = {}, o1B = {};
    f32x4 lsA = {}, lsB = {};
    float mA = -1e30f, mB = -1e30f;
    const f32x4 zero = {};
    for (int kv = 0; kv < NPGC; kv += 128) {
        f32x4 sA[8], sB[8];
        __builtin_amdgcn_s_setprio(1);
#pragma unroll
        for (int f = 0; f < 8; ++f) {
            size_t kr = (size_t)(kv + f * 16 + lr) * HDIM + lg * 8;
            short8 kh = ld_frag(Kh + kr);
            short8 kl2 = ld_frag(Kl + kr);
            sA[f] = MFMA16(kh, qlA, MFMA16(kl2, qhA, MFMA16(kh, qhA, zero)));
            sB[f] = MFMA16(kh, qlB, MFMA16(kl2, qhB, MFMA16(kh, qhB, zero)));
        }
        __builtin_amdgcn_s_setprio(0);
        // ---- softmax A: defer-max fast path (no cross-lane) ----
        {
            f32x4 mm = sA[0];
#pragma unroll
            for (int f = 1; f < 8; ++f)
#pragma unroll
                for (int i = 0; i < 4; ++i) mm[i] = fmaxf(mm[i], sA[f][i]);
            float mx = fmaxf(fmaxf(mm[0], mm[1]), fmaxf(mm[2], mm[3]));
            if (!__all(mx <= mA + 8.f)) {
                mx = fmaxf(mx, __shfl_xor(mx, 16));
                mx = fmaxf(mx, __shfl_xor(mx, 32));
                float mn = fmaxf(mA, mx);
                float corr = EXP2(mA - mn);
                mA = mn;
#pragma unroll
                for (int i = 0; i < 4; ++i) {
                    lsA[i] *= corr;
                    o0A[i] *= corr; o1A[i] *= corr;
                }
            }
#pragma unroll
            for (int f = 0; f < 8; ++f)
#pragma unroll
                for (int i = 0; i < 4; ++i) sA[f][i] = EXP2(sA[f][i] - mA);
            f32x4 s4 = sA[0];
#pragma unroll
            for (int f = 1; f < 8; ++f)
#pragma unroll
                for (int i = 0; i < 4; ++i) s4[i] += sA[f][i];
            lsA += s4;
#pragma unroll
            for (int f = 0; f < 8; ++f) {
                u32x2 wv;
                wv[0] = cvtpk_bf16(sA[f][0], sA[f][1]);
                wv[1] = cvtpk_bf16(sA[f][2], sA[f][3]);
                *reinterpret_cast<u32x2*>(&plds[wave][lr][f * 16 + lg * 4]) = wv;
            }
        }
        // ---- PV A (V frags kept for B) ----
        short8 vs0[4], vs1[4];
        __builtin_amdgcn_s_setprio(1);
#pragma unroll
        for (int kk = 0; kk < 4; ++kk) {
            short8 pf = ld_frag(&plds[wave][lr][kk * 32 + lg * 8]);
            vs0[kk] = ld_frag(Vh + (size_t)lr * NPGC + kv + kk * 32 + lg * 8);
            vs1[kk] = ld_frag(Vh + (size_t)(16 + lr) * NPGC + kv + kk * 32 + lg * 8);
            o0A = MFMA16(vs0[kk], pf, o0A);
            o1A = MFMA16(vs1[kk], pf, o1A);
        }
        __builtin_amdgcn_s_setprio(0);
        // ---- softmax B (overlaps PV_A drain) ----
        {
            f32x4 mm = sB[0];
#pragma unroll
            for (int f = 1; f < 8; ++f)
#pragma unroll
                for (int i = 0; i < 4; ++i) mm[i] = fmaxf(mm[i], sB[f][i]);
            float mx = fmaxf(fmaxf(mm[0], mm[1]), fmaxf(mm[2], mm[3]));
            if (!__all(mx <= mB + 8.f)) {
                mx = fmaxf(mx, __shfl_xor(mx, 16));
                mx = fmaxf(mx, __shfl_xor(mx, 32));
                float mn = fmaxf(mB, mx);
                float corr = EXP2(mB - mn);
                mB = mn;
#pragma unroll
                for (int i = 0; i < 4; ++i) {
                    lsB[i] *= corr;
                    o0B[i] *= corr; o1B[i] *= corr;
                }
            }
#pragma unroll
            for (int f = 0; f < 8; ++f)
#pragma unroll
                for (int i = 0; i < 4; ++i) sB[f][i] = EXP2(sB[f][i] - mB);
            f32x4 s4 = sB[0];
#pragma unroll
            for (int f = 1; f < 8; ++f)
#pragma unroll
                for (int i = 0; i < 4; ++i) s4[i] += sB[f][i];
            lsB += s4;
            // same-wave DS ordering: PV_A reads complete before these writes land
#pragma unroll
            for (int f = 0; f < 8; ++f) {
                u32x2 wv;
                wv[0] = cvtpk_bf16(sB[f][0], sB[f][1]);
                wv[1] = cvtpk_bf16(sB[f][2], sB[f][3]);
                *reinterpret_cast<u32x2*>(&plds[wave][lr][f * 16 + lg * 4]) = wv;
            }
        }
        // ---- PV B ----
        __builtin_amdgcn_s_setprio(1);
#pragma unroll
        for (int kk = 0; kk < 4; ++kk) {
            short8 pf = ld_frag(&plds[wave][lr][kk * 32 + lg * 8]);
            o0B = MFMA16(vs0[kk], pf, o0B);
            o1B = MFMA16(vs1[kk], pf, o1B);
        }
        __builtin_amdgcn_s_setprio(0);
    }
    // single cross-lane l reduction at the end
    float lA = (lsA[0] + lsA[1]) + (lsA[2] + lsA[3]);
    lA += __shfl_xor(lA, 16);
    lA += __shfl_xor(lA, 32);
    float lB = (lsB[0] + lsB[1]) + (lsB[2] + lsB[3]);
    lB += __shfl_xor(lB, 16);
    lB += __shfl_xor(lB, 32);
    int g = gh >> 2, hh = gh & 3;
    {
        float inv = 1.f / lA;
        size_t obase = ((size_t)g * NPGC + qA + lr) * CHN + hh * HDIM;
        union { u16 u[4]; u64 v; } p0h, p0l, p1h, p1l;
#pragma unroll
        for (int i = 0; i < 4; ++i) {
            u16 a, b;
            fsplit(o0A[i] * inv, a, b); p0h.u[i] = a; p0l.u[i] = b;
            fsplit(o1A[i] * inv, a, b); p1h.u[i] = a; p1l.u[i] = b;
        }
        *reinterpret_cast<u64*>(aohi + obase + lg * 4) = p0h.v;
        *reinterpret_cast<u64*>(aolo + obase + lg * 4) = p0l.v;
        *reinterpret_cast<u64*>(aohi + obase + 16 + lg * 4) = p1h.v;
        *reinterpret_cast<u64*>(aolo + obase + 16 + lg * 4) = p1l.v;
    }
    {
        float inv = 1.f / lB;
        size_t obase = ((size_t)g * NPGC + qB + lr) * CHN + hh * HDIM;
        union { u16 u[4]; u64 v; } p0h, p0l, p1h, p1l;
#pragma unroll
        for (int i = 0; i < 4; ++i) {
            u16 a, b;
            fsplit(o0B[i] * inv, a, b); p0h.u[i] = a; p0l.u[i] = b;
            fsplit(o1B[i] * inv, a, b); p1h.u[i] = a; p1l.u[i] = b;
        }
        *reinterpret_cast<u64*>(aohi + obase + lg * 4) = p0h.v;
        *reinterpret_cast<u64*>(aolo + obase + lg * 4) = p0l.v;
        *reinterpret_cast<u64*>(aohi + obase + 16 + lg * 4) = p1h.v;
        *reinterpret_cast<u64*>(aolo + obase + 16 + lg * 4) = p1l.v;
    }
}

// ---------------- pooling + head MLP ----------------

__global__ __launch_bounds__(128) void k_pool(const float* __restrict__ h,
                                              float* __restrict__ pool) {
    int g = blockIdx.x, sl = blockIdx.y, c = threadIdx.x;
    const float* p = h + ((size_t)g * NPGC + sl * 128) * CHN + c;
    float s = 0.f;
    for (int i = 0; i < 128; ++i) s += p[(size_t)i * CHN];
    atomicAdd(&pool[g * CHN + c], s);
}

__global__ __launch_bounds__(256) void k_head(
    const float* __restrict__ pool, const float* __restrict__ w1,
    const float* __restrict__ b1, const float* __restrict__ w2,
    const float* __restrict__ b2, const float* __restrict__ w3,
    const float* __restrict__ b3, float* __restrict__ out) {
    __shared__ float g1[16][64];
    __shared__ float g2[16][32];
    int t = threadIdx.x;
    for (int idx = t; idx < 16 * 64; idx += 256) {
        int g = idx >> 6, n = idx & 63;
        float s = b1[n];
        for (int k = 0; k < 128; ++k) s += pool[g * 128 + k] * w1[n * 128 + k];
        g1[g][n] = fmaxf(s, 0.f);
    }
    __syncthreads();
    for (int idx = t; idx < 16 * 32; idx += 256) {
        int g = idx >> 5, n = idx & 31;
        float s = b2[n];
        for (int k = 0; k < 64; ++k) s += g1[g][k] * w2[n * 64 + k];
        g2[g][n] = fmaxf(s, 0.f);
    }
    __syncthreads();
    if (t < 16) {
        float s = b3[0];
        for (int k = 0; k < 32; ++k) s += g2[t][k] * w3[k];
        out[t] = s;
    }
}

// ---------------- host ----------------

extern "C" void kernel_launch(void* const* d_in, const int* in_sizes, int n_in,
                              void* d_out, int out_size, void* d_ws, size_t ws_size,
                              hipStream_t stream) {
    (void)in_sizes; (void)n_in; (void)out_size; (void)ws_size;
    const float* x = (const float*)d_in[0];
    const float* edge_attr = (const float*)d_in[1];
    const int* edge_index = (const int*)d_in[2];
    const float* node_w = (const float*)d_in[4];
    const float* node_b = (const float*)d_in[5];
    const float* edge_w = (const float*)d_in[6];
    const float* edge_b = (const float*)d_in[7];
    const float* gine_w1 = (const float*)d_in[8];
    const float* gine_b1 = (const float*)d_in[9];
    const float* gine_w2 = (const float*)d_in[10];
    const float* gine_b2 = (const float*)d_in[11];
    const float* attn_in_w = (const float*)d_in[12];
    const float* attn_in_b = (const float*)d_in[13];
    const float* attn_out_w = (const float*)d_in[14];
    const float* attn_out_b = (const float*)d_in[15];
    const float* mlp_w1 = (const float*)d_in[16];
    const float* mlp_b1 = (const float*)d_in[17];
    const float* mlp_w2 = (const float*)d_in[18];
    const float* mlp_b2 = (const float*)d_in[19];
    const float* bn_g = (const float*)d_in[20];
    const float* bn_bb = (const float*)d_in[21];
    const float* bn_m = (const float*)d_in[22];
    const float* bn_v = (const float*)d_in[23];
    const float* head_w1 = (const float*)d_in[24];
    const float* head_b1 = (const float*)d_in[25];
    const float* head_w2 = (const float*)d_in[26];
    const float* head_b2 = (const float*)d_in[27];
    const float* head_w3 = (const float*)d_in[28];
    const float* head_b3 = (const float*)d_in[29];

    char* ws = (char*)d_ws;
    size_t off = 0;
    auto alloc = [&](size_t bytes) {
        size_t r = off;
        off = (off + bytes + 255) & ~(size_t)255;
        return r;
    };
    const size_t NC = (size_t)NODES * CHN;
    float* h_f32 = (float*)(ws + alloc(NC * 4));
    u16* h_hi = (u16*)(ws + alloc(NC * 2));
    u16* h_lo = (u16*)(ws + alloc(NC * 2));
    u16* x_hi = (u16*)(ws + alloc((size_t)NODES * 64 * 2));
    u16* x_lo = (u16*)(ws + alloc((size_t)NODES * 64 * 2));
    u16* zao_hi = (u16*)(ws + alloc(NC * 2));
    u16* zao_lo = (u16*)(ws + alloc(NC * 2));
    float* h1_f32 = (float*)(ws + alloc(NC * 4));
    u16* q_hi = (u16*)(ws + alloc(NC * 2));
    u16* q_lo = (u16*)(ws + alloc(NC * 2));
    u16* kk_hi = (u16*)(ws + alloc(NC * 2));
    u16* kk_lo = (u16*)(ws + alloc(NC * 2));
    u16* vt_hi = (u16*)(ws + alloc(NC * 2));
    float* pool = (float*)(ws + alloc(NG * CHN * 4));
    u16* node_w_hi = (u16*)(ws + alloc(CHN * 64 * 2));
    u16* node_w_lo = (u16*)(ws + alloc(CHN * 64 * 2));
    u16* gw1_hi = (u16*)(ws + alloc((size_t)NLAYER * CHN * CHN * 2));
    u16* gw1_lo = (u16*)(ws + alloc((size_t)NLAYER * CHN * CHN * 2));
    u16* gw2_hi = (u16*)(ws + alloc((size_t)NLAYER * CHN * CHN * 2));
    u16* gw2_lo = (u16*)(ws + alloc((size_t)NLAYER * CHN * CHN * 2));
    u16* aiw_hi = (u16*)(ws + alloc((size_t)NLAYER * 3 * CHN * CHN * 2));
    u16* aiw_lo = (u16*)(ws + alloc((size_t)NLAYER * 3 * CHN * CHN * 2));
    u16* aow_hi = (u16*)(ws + alloc((size_t)NLAYER * CHN * CHN * 2));
    u16* aow_lo = (u16*)(ws + alloc((size_t)NLAYER * CHN * CHN * 2));
    u16* mw1_hi = (u16*)(ws + alloc((size_t)NLAYER * 2 * CHN * CHN * 2));
    u16* mw1_lo = (u16*)(ws + alloc((size_t)NLAYER * 2 * CHN * CHN * 2));
    u16* mw2_hi = (u16*)(ws + alloc((size_t)NLAYER * 2 * CHN * CHN * 2));
    u16* mw2_lo = (u16*)(ws + alloc((size_t)NLAYER * 2 * CHN * CHN * 2));
    float* bn_scale = (float*)(ws + alloc(NLAYER * 3 * CHN * 4));
    float* bn_shift = (float*)(ws + alloc(NLAYER * 3 * CHN * 4));
    u32* counts = (u32*)(ws + alloc(NODES * 4));
    u32* offsets = (u32*)(ws + alloc((NODES + 1) * 4));
    u32* cursor = (u32*)(ws + alloc(NODES * 4));
    int* csr_src = (int*)(ws + alloc((size_t)NEDGE * 4));
    float* csr_a = (float*)(ws + alloc((size_t)NEDGE * 4));

    const int* e_src = edge_index;
    const int* e_dst = edge_index + NEDGE;

    {
        SplitJobs j;
        const float* srcs[8] = {x, node_w, gine_w1, gine_w2, attn_in_w,
                                attn_out_w, mlp_w1, mlp_w2};
        u16* his[8] = {x_hi, node_w_hi, gw1_hi, gw2_hi, aiw_hi, aow_hi, mw1_hi, mw2_hi};
        u16* los[8] = {x_lo, node_w_lo, gw1_lo, gw2_lo, aiw_lo, aow_lo, mw1_lo, mw2_lo};
        int ns[8] = {NODES * 64, CHN * 64, NLAYER * CHN * CHN, NLAYER * CHN * CHN,
                     NLAYER * 3 * CHN * CHN, NLAYER * CHN * CHN,
                     NLAYER * 2 * CHN * CHN, NLAYER * 2 * CHN * CHN};
        int cum = 0;
        for (int i = 0; i < 8; ++i) {
            j.src[i] = srcs[i]; j.hi[i] = his[i]; j.lo[i] = los[i];
            cum += ns[i] / 256;
            j.blk_end[i] = cum;
        }
        k_split8<<<dim3(cum), dim3(256), 0, stream>>>(j);
    }

    k_bnprep<<<dim3((NLAYER * 3 * CHN + 255) / 256), dim3(256), 0, stream>>>(
        bn_g, bn_bb, bn_m, bn_v, bn_scale, bn_shift);

    k_zero_u32<<<dim3(NODES / 256), dim3(256), 0, stream>>>(counts, NODES);
    k_count<<<dim3(NEDGE / 256), dim3(256), 0, stream>>>(e_dst, counts);
    k_scan<<<dim3(1), dim3(256), 0, stream>>>(counts, offsets, cursor);
    k_fill<<<dim3(NEDGE / 256), dim3(256), 0, stream>>>(e_src, e_dst, edge_attr,
                                                        cursor, csr_src, csr_a);

    // node projection: h = x @ node_w^T + node_b
    k_gemm<<<dim3(NODES / 64, CHN / 32), dim3(256), 0, stream>>>(
        x_hi, x_lo, node_w_hi, node_w_lo, node_b, h_f32, h_hi, h_lo, 64, CHN);

    for (int l = 0; l < NLAYER; ++l) {
        size_t wo = (size_t)l * CHN * CHN;
        const float* sc0 = bn_scale + (l * 3 + 0) * CHN;
        const float* sh0 = bn_shift + (l * 3 + 0) * CHN;
        const float* sc1 = bn_scale + (l * 3 + 1) * CHN;
        const float* sh1 = bn_shift + (l * 3 + 1) * CHN;
        const float* sc2 = bn_scale + (l * 3 + 2) * CHN;
        const float* sh2 = bn_shift + (l * 3 + 2) * CHN;

        k_agg<<<dim3(NODES), dim3(64), 0, stream>>>(h_hi, h_f32, offsets, csr_src,
                                                    csr_a, edge_w, edge_b,
                                                    zao_hi, zao_lo);
        k_gine<<<dim3(NODES / 32), dim3(256), 0, stream>>>(
            zao_hi, zao_lo, gw1_hi + wo, gw1_lo + wo, gine_b1 + l * CHN,
            gw2_hi + wo, gw2_lo + wo, gine_b2 + l * CHN, h_f32, sc0, sh0, h1_f32);
        k_qkv<<<dim3(NODES / 64, 12), dim3(256), 0, stream>>>(
            h_hi, h_lo, aiw_hi + wo * 3, aiw_lo + wo * 3, attn_in_b + l * 3 * CHN,
            q_hi, q_lo, kk_hi, kk_lo, vt_hi);
        k_attn<<<dim3(16 * NG * NHEAD), dim3(128), 0, stream>>>(
            q_hi, q_lo, kk_hi, kk_lo, vt_hi, zao_hi, zao_lo);
        k_outffn<<<dim3(NODES / 32), dim3(256), 0, stream>>>(
            zao_hi, zao_lo, aow_hi + wo, aow_lo + wo, attn_out_b + l * CHN,
            h_f32, sc1, sh1, h1_f32,
            mw1_hi + wo * 2, mw1_lo + wo * 2, mlp_b1 + l * 2 * CHN,
            mw2_hi + wo * 2, mw2_lo + wo * 2, mlp_b2 + l * CHN, sc2, sh2,
            h_f32, h_hi, h_lo);
    }

    k_zero_u32<<<dim3(NG * CHN / 256), dim3(256), 0, stream>>>((u32*)pool, NG * CHN);
    k_pool<<<dim3(NG, 8), dim3(128), 0, stream>>>(h_f32, pool);
    k_head<<<dim3(1), dim3(256), 0, stream>>>(pool, head_w1, head_b1, head_w2,
                                              head_b2, head_w3, head_b3,
                                              (float*)d_out);
}

// Round 12
// 725.042 us; speedup vs baseline: 1.5851x; 1.0627x over previous
//
#include <hip/hip_runtime.h>
#include <hip/hip_bf16.h>

typedef __attribute__((ext_vector_type(8))) short short8;
typedef __attribute__((ext_vector_type(4))) float f32x4;
typedef __attribute__((ext_vector_type(2))) unsigned int u32x2;
typedef unsigned short u16;
typedef unsigned int u32;
typedef unsigned long long u64;

#define NODES 16384
#define CHN 128
#define NEDGE 524288
#define NG 16
#define NPGC 1024
#define NHEAD 4
#define HDIM 32
#define NLAYER 4
#define CL 0.2550348281f   // log2(e)/sqrt(HDIM), folded into Q at QKV store

#if __has_builtin(__builtin_amdgcn_exp2f)
#define EXP2(x) __builtin_amdgcn_exp2f(x)
#else
#define EXP2(x) exp2f(x)
#endif

__device__ __forceinline__ float bf2f(u16 u) {
    union { u32 u; float f; } c; c.u = ((u32)u) << 16; return c.f;
}
__device__ __forceinline__ u16 f2bf(float f) {
    union { float f; u32 u; } c; c.f = f;
    u32 r = c.u + 0x7fffu + ((c.u >> 16) & 1u);
    return (u16)(r >> 16);
}
__device__ __forceinline__ void fsplit(float f, u16& hi, u16& lo) {
    u16 h = f2bf(f);
    hi = h;
    lo = f2bf(f - bf2f(h));
}
__device__ __forceinline__ u32 cvtpk_bf16(float a, float b) {
    u32 r;
    asm("v_cvt_pk_bf16_f32 %0, %1, %2" : "=v"(r) : "v"(a), "v"(b));
    return r;
}

#define MFMA16(a, b, c) __builtin_amdgcn_mfma_f32_16x16x32_bf16((a), (b), (c), 0, 0, 0)

__device__ __forceinline__ short8 ld_frag(const u16* p) {
    return *reinterpret_cast<const short8*>(p);
}

// ---------------- setup kernels ----------------

struct SplitJobs {
    const float* src[8];
    u16* hi[8];
    u16* lo[8];
    int blk_end[8];
};

__global__ void k_split8(SplitJobs jobs) {
    int b = blockIdx.x;
    int seg = 0;
    while (b >= jobs.blk_end[seg]) ++seg;
    int base = seg ? jobs.blk_end[seg - 1] : 0;
    int i = (b - base) * 256 + threadIdx.x;
    u16 h, l;
    fsplit(jobs.src[seg][i], h, l);
    jobs.hi[seg][i] = h;
    jobs.lo[seg][i] = l;
}

__global__ void k_bnprep(const float* __restrict__ g, const float* __restrict__ b,
                         const float* __restrict__ m, const float* __restrict__ v,
                         float* __restrict__ scale, float* __restrict__ shift) {
    int i = blockIdx.x * 256 + threadIdx.x;
    if (i < NLAYER * 3 * CHN) {
        float s = g[i] * rsqrtf(v[i] + 1e-5f);
        scale[i] = s;
        shift[i] = b[i] - m[i] * s;
    }
}

__global__ void k_zero_u32(u32* __restrict__ p, int n) {
    int i = blockIdx.x * 256 + threadIdx.x;
    if (i < n) p[i] = 0u;
}

__global__ void k_count(const int* __restrict__ dst, u32* __restrict__ counts) {
    int e = blockIdx.x * 256 + threadIdx.x;
    if (e < NEDGE) atomicAdd(&counts[dst[e]], 1u);
}

__global__ void k_scan(const u32* __restrict__ counts, u32* __restrict__ offsets,
                       u32* __restrict__ cursor) {
    __shared__ u32 part[256];
    int t = threadIdx.x;
    int base = t * 64;
    u32 s = 0;
    for (int i = 0; i < 64; ++i) s += counts[base + i];
    part[t] = s;
    __syncthreads();
    for (int off = 1; off < 256; off <<= 1) {
        u32 val = (t >= off) ? part[t - off] : 0u;
        __syncthreads();
        part[t] += val;
        __syncthreads();
    }
    u32 run = (t == 0) ? 0u : part[t - 1];
    for (int i = 0; i < 64; ++i) {
        offsets[base + i] = run;
        cursor[base + i] = run;
        run += counts[base + i];
    }
    if (t == 255) offsets[NODES] = run;
}

// combined (src, attr-bits) 8B store: halves scattered-write line traffic
__global__ void k_fill(const int* __restrict__ src, const int* __restrict__ dst,
                       const float* __restrict__ eattr, u32* __restrict__ cursor,
                       int2* __restrict__ csr_sa) {
    int e = blockIdx.x * 256 + threadIdx.x;
    if (e >= NEDGE) return;
    int d = dst[e];
    u32 p = atomicAdd(&cursor[d], 1u);
    csr_sa[p] = make_int2(src[e], __float_as_int(eattr[e]));
}

// ---- FAT kernel 1: GINE aggregation (blocks < NODES/4) ∥ QKV GEMM (rest) ----
// Both read only h; independent -> co-resident latency hiding.

__global__ __launch_bounds__(256) void k_aggqkv(
    // agg args
    const u16* __restrict__ h_hi, const float* __restrict__ h_f32,
    const u32* __restrict__ offsets, const int2* __restrict__ csr_sa,
    const float* __restrict__ ew, const float* __restrict__ eb,
    u16* __restrict__ z_hi, u16* __restrict__ z_lo,
    // qkv args
    const u16* __restrict__ h_lo, const u16* __restrict__ Whi,
    const u16* __restrict__ Wlo, const float* __restrict__ bias,
    u16* __restrict__ q_hi, u16* __restrict__ q_lo,
    u16* __restrict__ k_hi, u16* __restrict__ k_lo,
    u16* __restrict__ vt_hi) {
    int tid = threadIdx.x;
    int wave = tid >> 6, lane = tid & 63;
    if (blockIdx.x < NODES / 4) {
        // ---- aggregation: 4 nodes/block, one wave per node, 2 channels/lane ----
        int node = blockIdx.x * 4 + wave;
        int c0 = lane * 2;
        float w0 = ew[c0], w1 = ew[c0 + 1];
        float b0 = eb[c0], b1 = eb[c0 + 1];
        u32 beg = offsets[node], end = offsets[node + 1];
        float acc0 = 0.f, acc1 = 0.f;
        u32 n = end - beg;
        if (n) {
            int2 sa = csr_sa[beg];
            u32 ua = *reinterpret_cast<const u32*>(h_hi + (size_t)sa.x * CHN + c0);
            float aa = __int_as_float(sa.y);
            u32 j1 = (n > 1) ? beg + 1 : beg;
            int2 sb = csr_sa[j1];
            for (u32 i = 0; i < n; ++i) {
                u32 jn = beg + i + 2;
                jn = jn < end ? jn : end - 1;
                int2 sc2 = csr_sa[jn];
                u32 ub = *reinterpret_cast<const u32*>(h_hi + (size_t)sb.x * CHN + c0);
                float f0 = bf2f((u16)(ua & 0xffffu));
                float f1 = bf2f((u16)(ua >> 16));
                acc0 += fmaxf(f0 + aa * w0 + b0, 0.f);
                acc1 += fmaxf(f1 + aa * w1 + b1, 0.f);
                ua = ub; aa = __int_as_float(sb.y);
                sb = sc2;
            }
        }
        size_t idx = (size_t)node * CHN + c0;
        float z0 = h_f32[idx] + acc0;
        float z1v = h_f32[idx + 1] + acc1;
        u16 h, l;
        fsplit(z0, h, l); z_hi[idx] = h; z_lo[idx] = l;
        fsplit(z1v, h, l); z_hi[idx + 1] = h; z_lo[idx + 1] = l;
        return;
    }
    // ---- QKV GEMM; Q pre-scaled by CL ----
    const int K = 128;
    int id = blockIdx.x - NODES / 4;
    int bx = id & 255, ny = id >> 8;
    int lr = lane & 15, lg = lane >> 4;
    int r0 = bx * 64 + wave * 16;
    int nb = ny * 32;
    f32x4 acc[2] = {};
    size_t arow = (size_t)(r0 + lr) * K + lg * 8;
    for (int ks = 0; ks < K; ks += 32) {
        short8 ah = ld_frag(h_hi + arow + ks);
        short8 al = ld_frag(h_lo + arow + ks);
#pragma unroll
        for (int n = 0; n < 2; ++n) {
            size_t wrow = (size_t)(nb + n * 16 + lr) * K + ks + lg * 8;
            short8 wh = ld_frag(Whi + wrow);
            short8 wl = ld_frag(Wlo + wrow);
            acc[n] = MFMA16(ah, wh, acc[n]);
            acc[n] = MFMA16(al, wh, acc[n]);
            acc[n] = MFMA16(ah, wl, acc[n]);
        }
    }
#pragma unroll
    for (int n = 0; n < 2; ++n) {
        int col = nb + n * 16 + lr;
        int region = col >> 7;
        int c = col & 127;
        int hh = c >> 5, d = c & 31;
        float bs = bias[col];
#pragma unroll
        for (int r = 0; r < 4; ++r) {
            int row = r0 + lg * 4 + r;
            float v = acc[n][r] + bs;
            int g = row >> 10, p = row & 1023;
            size_t gh = (size_t)(g * NHEAD + hh);
            if (region == 0) {
                u16 vh, vl;
                fsplit(v * CL, vh, vl);
                size_t o = (gh * NPGC + p) * HDIM + d;
                q_hi[o] = vh; q_lo[o] = vl;
            } else if (region == 1) {
                u16 vh, vl;
                fsplit(v, vh, vl);
                size_t o = (gh * NPGC + p) * HDIM + d;
                k_hi[o] = vh; k_lo[o] = vl;
            } else {
                vt_hi[(gh * HDIM + d) * NPGC + p] = f2bf(v);
            }
        }
    }
}

// ------ split GEMM (16x32 wave tile) — used for node projection ------

__global__ __launch_bounds__(256) void k_gemm(
    const u16* __restrict__ Ahi, const u16* __restrict__ Alo,
    const u16* __restrict__ Whi, const u16* __restrict__ Wlo,
    const float* __restrict__ bias, float* __restrict__ out_f32,
    u16* __restrict__ out_hi, u16* __restrict__ out_lo, int K, int Nc) {
    int tid = threadIdx.x;
    int wave = tid >> 6, lane = tid & 63;
    int lr = lane & 15, lg = lane >> 4;
    int r0 = blockIdx.x * 64 + wave * 16;
    int nb = blockIdx.y * 32;
    f32x4 acc[2] = {};
    size_t arow = (size_t)(r0 + lr) * K + lg * 8;
    for (int ks = 0; ks < K; ks += 32) {
        short8 ah = ld_frag(Ahi + arow + ks);
        short8 al = ld_frag(Alo + arow + ks);
#pragma unroll
        for (int n = 0; n < 2; ++n) {
            size_t wrow = (size_t)(nb + n * 16 + lr) * K + ks + lg * 8;
            short8 wh = ld_frag(Whi + wrow);
            short8 wl = ld_frag(Wlo + wrow);
            acc[n] = MFMA16(ah, wh, acc[n]);
            acc[n] = MFMA16(al, wh, acc[n]);
            acc[n] = MFMA16(ah, wl, acc[n]);
        }
    }
#pragma unroll
    for (int n = 0; n < 2; ++n) {
        int col = nb + n * 16 + lr;
        float bs = bias[col];
#pragma unroll
        for (int r = 0; r < 4; ++r) {
            int row = r0 + lg * 4 + r;
            size_t oidx = (size_t)row * Nc + col;
            float v = acc[n][r] + bs;
            out_f32[oidx] = v;
            u16 hh, ll;
            fsplit(v, hh, ll);
            out_hi[oidx] = hh; out_lo[oidx] = ll;
        }
    }
}

// ---- FAT kernel 2: fused GINE MLP (blocks < 512) ∥ flash attention (rest) ----
// gine consumes z (from k_aggqkv agg half), attn consumes q/k/v (from qkv half).
// Both halves alias the same 17.4 KB LDS buffer.

__global__ __launch_bounds__(256) void k_gineattn(
    // gine args
    const u16* __restrict__ zhi, const u16* __restrict__ zlo,
    const u16* __restrict__ w1hi, const u16* __restrict__ w1lo,
    const float* __restrict__ b1,
    const u16* __restrict__ w2hi, const u16* __restrict__ w2lo,
    const float* __restrict__ b2, const float* __restrict__ resid,
    const float* __restrict__ bnsc, const float* __restrict__ bnsh,
    float* __restrict__ h1out,
    // attn args
    const u16* __restrict__ qhi, const u16* __restrict__ qlo,
    const u16* __restrict__ khi, const u16* __restrict__ klo,
    const u16* __restrict__ vthi,
    u16* __restrict__ aohi, u16* __restrict__ aolo) {
    __shared__ __align__(16) u16 smem[64][136];
    int tid = threadIdx.x;
    int wave = tid >> 6, lane = tid & 63;
    int lr = lane & 15, lg = lane >> 4;
    if (blockIdx.x < NODES / 32) {
        // ---------------- GINE MLP: 32 rows/block, 2 row-groups/wave ----------------
        int r0 = blockIdx.x * 32;
        int cb = wave * 32;
        {
            f32x4 acc[2][2] = {};
            size_t arow0 = (size_t)(r0 + lr) * CHN + lg * 8;
            size_t arow1 = (size_t)(r0 + 16 + lr) * CHN + lg * 8;
            for (int ks = 0; ks < CHN; ks += 32) {
                short8 ah0 = ld_frag(zhi + arow0 + ks);
                short8 al0 = ld_frag(zlo + arow0 + ks);
                short8 ah1 = ld_frag(zhi + arow1 + ks);
                short8 al1 = ld_frag(zlo + arow1 + ks);
#pragma unroll
                for (int n = 0; n < 2; ++n) {
                    size_t wrow = (size_t)(cb + n * 16 + lr) * CHN + ks + lg * 8;
                    short8 wh = ld_frag(w1hi + wrow);
                    short8 wl = ld_frag(w1lo + wrow);
                    acc[0][n] = MFMA16(ah0, wh, acc[0][n]);
                    acc[0][n] = MFMA16(al0, wh, acc[0][n]);
                    acc[0][n] = MFMA16(ah0, wl, acc[0][n]);
                    acc[1][n] = MFMA16(ah1, wh, acc[1][n]);
                    acc[1][n] = MFMA16(al1, wh, acc[1][n]);
                    acc[1][n] = MFMA16(ah1, wl, acc[1][n]);
                }
            }
#pragma unroll
            for (int rg = 0; rg < 2; ++rg)
#pragma unroll
                for (int n = 0; n < 2; ++n) {
                    int col = cb + n * 16 + lr;
                    float bs = b1[col];
#pragma unroll
                    for (int r = 0; r < 4; ++r) {
                        float v = fmaxf(acc[rg][n][r] + bs, 0.f);
                        u16 hh, ll;
                        fsplit(v, hh, ll);
                        int rl = rg * 16 + lg * 4 + r;
                        smem[rl][col] = hh;        // t_hi
                        smem[32 + rl][col] = ll;   // t_lo
                    }
                }
        }
        __syncthreads();
        {
            f32x4 acc[2][2] = {};
            for (int ks = 0; ks < CHN; ks += 32) {
                short8 ah0 = ld_frag(&smem[lr][ks + lg * 8]);
                short8 al0 = ld_frag(&smem[32 + lr][ks + lg * 8]);
                short8 ah1 = ld_frag(&smem[16 + lr][ks + lg * 8]);
                short8 al1 = ld_frag(&smem[48 + lr][ks + lg * 8]);
#pragma unroll
                for (int n = 0; n < 2; ++n) {
                    size_t wrow = (size_t)(cb + n * 16 + lr) * CHN + ks + lg * 8;
                    short8 wh = ld_frag(w2hi + wrow);
                    short8 wl = ld_frag(w2lo + wrow);
                    acc[0][n] = MFMA16(ah0, wh, acc[0][n]);
                    acc[0][n] = MFMA16(al0, wh, acc[0][n]);
                    acc[0][n] = MFMA16(ah0, wl, acc[0][n]);
                    acc[1][n] = MFMA16(ah1, wh, acc[1][n]);
                    acc[1][n] = MFMA16(al1, wh, acc[1][n]);
                    acc[1][n] = MFMA16(ah1, wl, acc[1][n]);
                }
            }
#pragma unroll
            for (int rg = 0; rg < 2; ++rg)
#pragma unroll
                for (int n = 0; n < 2; ++n) {
                    int col = cb + n * 16 + lr;
                    float bs = b2[col], sc = bnsc[col], sh = bnsh[col];
#pragma unroll
                    for (int r = 0; r < 4; ++r) {
                        int row = r0 + rg * 16 + lg * 4 + r;
                        size_t oidx = (size_t)row * CHN + col;
                        float v = acc[rg][n][r] + bs + resid[oidx];
                        h1out[oidx] = v * sc + sh;
                    }
                }
        }
        return;
    }
    // ---------------- attention: swapped QK^T, dual-stream, defer-max ----------------
    int id = blockIdx.x - NODES / 32;
    int gh = id & 63;           // id%8==gh%8 -> per-gh XCD locality (512 offset %8==0)
    int bx = id >> 6;           // 0..7
    int qA = bx * 128 + wave * 32;
    int qB = qA + 16;
    size_t base = (size_t)gh * NPGC * HDIM;
    size_t vbase = (size_t)gh * HDIM * NPGC;
    short8 qhA = ld_frag(qhi + base + (size_t)(qA + lr) * HDIM + lg * 8);
    short8 qlA = ld_frag(qlo + base + (size_t)(qA + lr) * HDIM + lg * 8);
    short8 qhB = ld_frag(qhi + base + (size_t)(qB + lr) * HDIM + lg * 8);
    short8 qlB = ld_frag(qlo + base + (size_t)(qB + lr) * HDIM + lg * 8);
    const u16* Kh = khi + base;
    const u16* Kl = klo + base;
    const u16* Vh = vthi + vbase;
    f32x4 o0A = {}, o1A = {}, o0B = {}, o1B = {};
    f32x4 lsA = {}, lsB = {};
    float mA = -1e30f, mB = -1e30f;
    const f32x4 zero = {};
    u16 (*plds)[136] = &smem[wave * 16];
    for (int kv = 0; kv < NPGC; kv += 128) {
        f32x4 sA[8], sB[8];
        __builtin_amdgcn_s_setprio(1);
#pragma unroll
        for (int f = 0; f < 8; ++f) {
            size_t kr = (size_t)(kv + f * 16 + lr) * HDIM + lg * 8;
            short8 kh = ld_frag(Kh + kr);
            short8 kl2 = ld_frag(Kl + kr);
            sA[f] = MFMA16(kh, qlA, MFMA16(kl2, qhA, MFMA16(kh, qhA, zero)));
            sB[f] = MFMA16(kh, qlB, MFMA16(kl2, qhB, MFMA16(kh, qhB, zero)));
        }
        __builtin_amdgcn_s_setprio(0);
        // softmax A: defer-max fast path
        {
            f32x4 mm = sA[0];
#pragma unroll
            for (int f = 1; f < 8; ++f)
#pragma unroll
                for (int i = 0; i < 4; ++i) mm[i] = fmaxf(mm[i], sA[f][i]);
            float mx = fmaxf(fmaxf(mm[0], mm[1]), fmaxf(mm[2], mm[3]));
            if (!__all(mx <= mA + 8.f)) {
                mx = fmaxf(mx, __shfl_xor(mx, 16));
                mx = fmaxf(mx, __shfl_xor(mx, 32));
                float mn = fmaxf(mA, mx);
                float corr = EXP2(mA - mn);
                mA = mn;
#pragma unroll
                for (int i = 0; i < 4; ++i) {
                    lsA[i] *= corr;
                    o0A[i] *= corr; o1A[i] *= corr;
                }
            }
#pragma unroll
            for (int f = 0; f < 8; ++f)
#pragma unroll
                for (int i = 0; i < 4; ++i) sA[f][i] = EXP2(sA[f][i] - mA);
            f32x4 s4 = sA[0];
#pragma unroll
            for (int f = 1; f < 8; ++f)
#pragma unroll
                for (int i = 0; i < 4; ++i) s4[i] += sA[f][i];
            lsA += s4;
#pragma unroll
            for (int f = 0; f < 8; ++f) {
                u32x2 wv;
                wv[0] = cvtpk_bf16(sA[f][0], sA[f][1]);
                wv[1] = cvtpk_bf16(sA[f][2], sA[f][3]);
                *reinterpret_cast<u32x2*>(&plds[lr][f * 16 + lg * 4]) = wv;
            }
        }
        // PV A (V frags kept for B)
        short8 vs0[4], vs1[4];
        __builtin_amdgcn_s_setprio(1);
#pragma unroll
        for (int kk = 0; kk < 4; ++kk) {
            short8 pf = ld_frag(&plds[lr][kk * 32 + lg * 8]);
            vs0[kk] = ld_frag(Vh + (size_t)lr * NPGC + kv + kk * 32 + lg * 8);
            vs1[kk] = ld_frag(Vh + (size_t)(16 + lr) * NPGC + kv + kk * 32 + lg * 8);
            o0A = MFMA16(vs0[kk], pf, o0A);
            o1A = MFMA16(vs1[kk], pf, o1A);
        }
        __builtin_amdgcn_s_setprio(0);
        // softmax B
        {
            f32x4 mm = sB[0];
#pragma unroll
            for (int f = 1; f < 8; ++f)
#pragma unroll
                for (int i = 0; i < 4; ++i) mm[i] = fmaxf(mm[i], sB[f][i]);
            float mx = fmaxf(fmaxf(mm[0], mm[1]), fmaxf(mm[2], mm[3]));
            if (!__all(mx <= mB + 8.f)) {
                mx = fmaxf(mx, __shfl_xor(mx, 16));
                mx = fmaxf(mx, __shfl_xor(mx, 32));
                float mn = fmaxf(mB, mx);
                float corr = EXP2(mB - mn);
                mB = mn;
#pragma unroll
                for (int i = 0; i < 4; ++i) {
                    lsB[i] *= corr;
                    o0B[i] *= corr; o1B[i] *= corr;
                }
            }
#pragma unroll
            for (int f = 0; f < 8; ++f)
#pragma unroll
                for (int i = 0; i < 4; ++i) sB[f][i] = EXP2(sB[f][i] - mB);
            f32x4 s4 = sB[0];
#pragma unroll
            for (int f = 1; f < 8; ++f)
#pragma unroll
                for (int i = 0; i < 4; ++i) s4[i] += sB[f][i];
            lsB += s4;
#pragma unroll
            for (int f = 0; f < 8; ++f) {
                u32x2 wv;
                wv[0] = cvtpk_bf16(sB[f][0], sB[f][1]);
                wv[1] = cvtpk_bf16(sB[f][2], sB[f][3]);
                *reinterpret_cast<u32x2*>(&plds[lr][f * 16 + lg * 4]) = wv;
            }
        }
        // PV B
        __builtin_amdgcn_s_setprio(1);
#pragma unroll
        for (int kk = 0; kk < 4; ++kk) {
            short8 pf = ld_frag(&plds[lr][kk * 32 + lg * 8]);
            o0B = MFMA16(vs0[kk], pf, o0B);
            o1B = MFMA16(vs1[kk], pf, o1B);
        }
        __builtin_amdgcn_s_setprio(0);
    }
    float lA = (lsA[0] + lsA[1]) + (lsA[2] + lsA[3]);
    lA += __shfl_xor(lA, 16);
    lA += __shfl_xor(lA, 32);
    float lB = (lsB[0] + lsB[1]) + (lsB[2] + lsB[3]);
    lB += __shfl_xor(lB, 16);
    lB += __shfl_xor(lB, 32);
    int g = gh >> 2, hh = gh & 3;
    {
        float inv = 1.f / lA;
        size_t obase = ((size_t)g * NPGC + qA + lr) * CHN + hh * HDIM;
        union { u16 u[4]; u64 v; } p0h, p0l, p1h, p1l;
#pragma unroll
        for (int i = 0; i < 4; ++i) {
            u16 a, b;
            fsplit(o0A[i] * inv, a, b); p0h.u[i] = a; p0l.u[i] = b;
            fsplit(o1A[i] * inv, a, b); p1h.u[i] = a; p1l.u[i] = b;
        }
        *reinterpret_cast<u64*>(aohi + obase + lg * 4) = p0h.v;
        *reinterpret_cast<u64*>(aolo + obase + lg * 4) = p0l.v;
        *reinterpret_cast<u64*>(aohi + obase + 16 + lg * 4) = p1h.v;
        *reinterpret_cast<u64*>(aolo + obase + 16 + lg * 4) = p1l.v;
    }
    {
        float inv = 1.f / lB;
        size_t obase = ((size_t)g * NPGC + qB + lr) * CHN + hh * HDIM;
        union { u16 u[4]; u64 v; } p0h, p0l, p1h, p1l;
#pragma unroll
        for (int i = 0; i < 4; ++i) {
            u16 a, b;
            fsplit(o0B[i] * inv, a, b); p0h.u[i] = a; p0l.u[i] = b;
            fsplit(o1B[i] * inv, a, b); p1h.u[i] = a; p1l.u[i] = b;
        }
        *reinterpret_cast<u64*>(aohi + obase + lg * 4) = p0h.v;
        *reinterpret_cast<u64*>(aolo + obase + lg * 4) = p0l.v;
        *reinterpret_cast<u64*>(aohi + obase + 16 + lg * 4) = p1h.v;
        *reinterpret_cast<u64*>(aolo + obase + 16 + lg * 4) = p1l.v;
    }
}

// ---- fused out-proj + FFN, 32 rows/block, weight frags shared across 2 row-groups ----

__global__ __launch_bounds__(256) void k_outffn(
    const u16* __restrict__ aoh, const u16* __restrict__ aol,
    const u16* __restrict__ awh, const u16* __restrict__ awl,
    const float* __restrict__ ab, const float* __restrict__ hres,
    const float* __restrict__ sc1, const float* __restrict__ sh1,
    const float* __restrict__ h1res,
    const u16* __restrict__ w1h, const u16* __restrict__ w1l,
    const float* __restrict__ b1,
    const u16* __restrict__ w2h, const u16* __restrict__ w2l,
    const float* __restrict__ b2,
    const float* __restrict__ sc2, const float* __restrict__ sh2,
    float* __restrict__ hf, u16* __restrict__ hhi, u16* __restrict__ hlo) {
    __shared__ __align__(16) u16 o_hi[32][136];
    __shared__ __align__(16) u16 o_lo[32][136];
    __shared__ __align__(16) u16 t_hi[32][264];
    __shared__ __align__(16) u16 t_lo[32][264];
    int tid = threadIdx.x;
    int wave = tid >> 6, lane = tid & 63;
    int lr = lane & 15, lg = lane >> 4;
    int r0 = blockIdx.x * 32;
    int cb = wave * 32;
    {
        f32x4 acc[2][2] = {};
        size_t arow0 = (size_t)(r0 + lr) * CHN + lg * 8;
        size_t arow1 = (size_t)(r0 + 16 + lr) * CHN + lg * 8;
        for (int ks = 0; ks < CHN; ks += 32) {
            short8 ah0 = ld_frag(aoh + arow0 + ks);
            short8 al0 = ld_frag(aol + arow0 + ks);
            short8 ah1 = ld_frag(aoh + arow1 + ks);
            short8 al1 = ld_frag(aol + arow1 + ks);
#pragma unroll
            for (int n = 0; n < 2; ++n) {
                size_t wrow = (size_t)(cb + n * 16 + lr) * CHN + ks + lg * 8;
                short8 wh = ld_frag(awh + wrow);
                short8 wl = ld_frag(awl + wrow);
                acc[0][n] = MFMA16(ah0, wh, acc[0][n]);
                acc[0][n] = MFMA16(al0, wh, acc[0][n]);
                acc[0][n] = MFMA16(ah0, wl, acc[0][n]);
                acc[1][n] = MFMA16(ah1, wh, acc[1][n]);
                acc[1][n] = MFMA16(al1, wh, acc[1][n]);
                acc[1][n] = MFMA16(ah1, wl, acc[1][n]);
            }
        }
#pragma unroll
        for (int rg = 0; rg < 2; ++rg)
#pragma unroll
            for (int n = 0; n < 2; ++n) {
                int col = cb + n * 16 + lr;
                float bs = ab[col], sc = sc1[col], sh = sh1[col];
#pragma unroll
                for (int r = 0; r < 4; ++r) {
                    int row = r0 + rg * 16 + lg * 4 + r;
                    int rl = rg * 16 + lg * 4 + r;
                    size_t oidx = (size_t)row * CHN + col;
                    float v = (acc[rg][n][r] + bs + hres[oidx]) * sc + sh + h1res[oidx];
                    u16 hh, ll;
                    fsplit(v, hh, ll);
                    o_hi[rl][col] = hh; o_lo[rl][col] = ll;
                }
            }
    }
    __syncthreads();
    {
        f32x4 acc[2][4] = {};
        int cbB = wave * 64;
        for (int ks = 0; ks < CHN; ks += 32) {
            short8 ah0 = ld_frag(&o_hi[lr][ks + lg * 8]);
            short8 al0 = ld_frag(&o_lo[lr][ks + lg * 8]);
            short8 ah1 = ld_frag(&o_hi[16 + lr][ks + lg * 8]);
            short8 al1 = ld_frag(&o_lo[16 + lr][ks + lg * 8]);
#pragma unroll
            for (int n = 0; n < 4; ++n) {
                size_t wrow = (size_t)(cbB + n * 16 + lr) * CHN + ks + lg * 8;
                short8 wh = ld_frag(w1h + wrow);
                short8 wl = ld_frag(w1l + wrow);
                acc[0][n] = MFMA16(ah0, wh, acc[0][n]);
                acc[0][n] = MFMA16(al0, wh, acc[0][n]);
                acc[0][n] = MFMA16(ah0, wl, acc[0][n]);
                acc[1][n] = MFMA16(ah1, wh, acc[1][n]);
                acc[1][n] = MFMA16(al1, wh, acc[1][n]);
                acc[1][n] = MFMA16(ah1, wl, acc[1][n]);
            }
        }
#pragma unroll
        for (int rg = 0; rg < 2; ++rg)
#pragma unroll
            for (int n = 0; n < 4; ++n) {
                int col = cbB + n * 16 + lr;
                float bs = b1[col];
#pragma unroll
                for (int r = 0; r < 4; ++r) {
                    float v = fmaxf(acc[rg][n][r] + bs, 0.f);
                    u16 hh, ll;
                    fsplit(v, hh, ll);
                    int rl = rg * 16 + lg * 4 + r;
                    t_hi[rl][col] = hh;
                    t_lo[rl][col] = ll;
                }
            }
    }
    __syncthreads();
    {
        f32x4 acc[2][2] = {};
        for (int ks = 0; ks < 2 * CHN; ks += 32) {
            short8 ah0 = ld_frag(&t_hi[lr][ks + lg * 8]);
            short8 al0 = ld_frag(&t_lo[lr][ks + lg * 8]);
            short8 ah1 = ld_frag(&t_hi[16 + lr][ks + lg * 8]);
            short8 al1 = ld_frag(&t_lo[16 + lr][ks + lg * 8]);
#pragma unroll
            for (int n = 0; n < 2; ++n) {
                size_t wrow = (size_t)(cb + n * 16 + lr) * 2 * CHN + ks + lg * 8;
                short8 wh = ld_frag(w2h + wrow);
                short8 wl = ld_frag(w2l + wrow);
                acc[0][n] = MFMA16(ah0, wh, acc[0][n]);
                acc[0][n] = MFMA16(al0, wh, acc[0][n]);
                acc[0][n] = MFMA16(ah0, wl, acc[0][n]);
                acc[1][n] = MFMA16(ah1, wh, acc[1][n]);
                acc[1][n] = MFMA16(al1, wh, acc[1][n]);
                acc[1][n] = MFMA16(ah1, wl, acc[1][n]);
            }
        }
#pragma unroll
        for (int rg = 0; rg < 2; ++rg)
#pragma unroll
            for (int n = 0; n < 2; ++n) {
                int col = cb + n * 16 + lr;
                float bs = b2[col], sc = sc2[col], sh = sh2[col];
#pragma unroll
                for (int r = 0; r < 4; ++r) {
                    int row = r0 + rg * 16 + lg * 4 + r;
                    int rl = rg * 16 + lg * 4 + r;
                    size_t oidx = (size_t)row * CHN + col;
                    float ores = bf2f(o_hi[rl][col]) + bf2f(o_lo[rl][col]);
                    float v = (acc[rg][n][r] + bs + ores) * sc + sh;
                    hf[oidx] = v;
                    u16 hh, ll;
                    fsplit(v, hh, ll);
                    hhi[oidx] = hh; hlo[oidx] = ll;
                }
            }
    }
}

// ---------------- pooling + head MLP ----------------

__global__ __launch_bounds__(128) void k_pool(const float* __restrict__ h,
                                              float* __restrict__ pool) {
    int g = blockIdx.x, sl = blockIdx.y, c = threadIdx.x;
    const float* p = h + ((size_t)g * NPGC + sl * 128) * CHN + c;
    float s = 0.f;
    for (int i = 0; i < 128; ++i) s += p[(size_t)i * CHN];
    atomicAdd(&pool[g * CHN + c], s);
}

__global__ __launch_bounds__(256) void k_head(
    const float* __restrict__ pool, const float* __restrict__ w1,
    const float* __restrict__ b1, const float* __restrict__ w2,
    const float* __restrict__ b2, const float* __restrict__ w3,
    const float* __restrict__ b3, float* __restrict__ out) {
    __shared__ float g1[16][64];
    __shared__ float g2[16][32];
    int t = threadIdx.x;
    for (int idx = t; idx < 16 * 64; idx += 256) {
        int g = idx >> 6, n = idx & 63;
        float s = b1[n];
        for (int k = 0; k < 128; ++k) s += pool[g * 128 + k] * w1[n * 128 + k];
        g1[g][n] = fmaxf(s, 0.f);
    }
    __syncthreads();
    for (int idx = t; idx < 16 * 32; idx += 256) {
        int g = idx >> 5, n = idx & 31;
        float s = b2[n];
        for (int k = 0; k < 64; ++k) s += g1[g][k] * w2[n * 64 + k];
        g2[g][n] = fmaxf(s, 0.f);
    }
    __syncthreads();
    if (t < 16) {
        float s = b3[0];
        for (int k = 0; k < 32; ++k) s += g2[t][k] * w3[k];
        out[t] = s;
    }
}

// ---------------- host ----------------

extern "C" void kernel_launch(void* const* d_in, const int* in_sizes, int n_in,
                              void* d_out, int out_size, void* d_ws, size_t ws_size,
                              hipStream_t stream) {
    (void)in_sizes; (void)n_in; (void)out_size; (void)ws_size;
    const float* x = (const float*)d_in[0];
    const float* edge_attr = (const float*)d_in[1];
    const int* edge_index = (const int*)d_in[2];
    const float* node_w = (const float*)d_in[4];
    const float* node_b = (const float*)d_in[5];
    const float* edge_w = (const float*)d_in[6];
    const float* edge_b = (const float*)d_in[7];
    const float* gine_w1 = (const float*)d_in[8];
    const float* gine_b1 = (const float*)d_in[9];
    const float* gine_w2 = (const float*)d_in[10];
    const float* gine_b2 = (const float*)d_in[11];
    const float* attn_in_w = (const float*)d_in[12];
    const float* attn_in_b = (const float*)d_in[13];
    const float* attn_out_w = (const float*)d_in[14];
    const float* attn_out_b = (const float*)d_in[15];
    const float* mlp_w1 = (const float*)d_in[16];
    const float* mlp_b1 = (const float*)d_in[17];
    const float* mlp_w2 = (const float*)d_in[18];
    const float* mlp_b2 = (const float*)d_in[19];
    const float* bn_g = (const float*)d_in[20];
    const float* bn_bb = (const float*)d_in[21];
    const float* bn_m = (const float*)d_in[22];
    const float* bn_v = (const float*)d_in[23];
    const float* head_w1 = (const float*)d_in[24];
    const float* head_b1 = (const float*)d_in[25];
    const float* head_w2 = (const float*)d_in[26];
    const float* head_b2 = (const float*)d_in[27];
    const float* head_w3 = (const float*)d_in[28];
    const float* head_b3 = (const float*)d_in[29];

    char* ws = (char*)d_ws;
    size_t off = 0;
    auto alloc = [&](size_t bytes) {
        size_t r = off;
        off = (off + bytes + 255) & ~(size_t)255;
        return r;
    };
    const size_t NC = (size_t)NODES * CHN;
    float* h_f32 = (float*)(ws + alloc(NC * 4));
    u16* h_hi = (u16*)(ws + alloc(NC * 2));
    u16* h_lo = (u16*)(ws + alloc(NC * 2));
    u16* x_hi = (u16*)(ws + alloc((size_t)NODES * 64 * 2));
    u16* x_lo = (u16*)(ws + alloc((size_t)NODES * 64 * 2));
    u16* zao_hi = (u16*)(ws + alloc(NC * 2));
    u16* zao_lo = (u16*)(ws + alloc(NC * 2));
    float* h1_f32 = (float*)(ws + alloc(NC * 4));
    u16* q_hi = (u16*)(ws + alloc(NC * 2));
    u16* q_lo = (u16*)(ws + alloc(NC * 2));
    u16* kk_hi = (u16*)(ws + alloc(NC * 2));
    u16* kk_lo = (u16*)(ws + alloc(NC * 2));
    u16* vt_hi = (u16*)(ws + alloc(NC * 2));
    float* pool = (float*)(ws + alloc(NG * CHN * 4));
    u16* node_w_hi = (u16*)(ws + alloc(CHN * 64 * 2));
    u16* node_w_lo = (u16*)(ws + alloc(CHN * 64 * 2));
    u16* gw1_hi = (u16*)(ws + alloc((size_t)NLAYER * CHN * CHN * 2));
    u16* gw1_lo = (u16*)(ws + alloc((size_t)NLAYER * CHN * CHN * 2));
    u16* gw2_hi = (u16*)(ws + alloc((size_t)NLAYER * CHN * CHN * 2));
    u16* gw2_lo = (u16*)(ws + alloc((size_t)NLAYER * CHN * CHN * 2));
    u16* aiw_hi = (u16*)(ws + alloc((size_t)NLAYER * 3 * CHN * CHN * 2));
    u16* aiw_lo = (u16*)(ws + alloc((size_t)NLAYER * 3 * CHN * CHN * 2));
    u16* aow_hi = (u16*)(ws + alloc((size_t)NLAYER * CHN * CHN * 2));
    u16* aow_lo = (u16*)(ws + alloc((size_t)NLAYER * CHN * CHN * 2));
    u16* mw1_hi = (u16*)(ws + alloc((size_t)NLAYER * 2 * CHN * CHN * 2));
    u16* mw1_lo = (u16*)(ws + alloc((size_t)NLAYER * 2 * CHN * CHN * 2));
    u16* mw2_hi = (u16*)(ws + alloc((size_t)NLAYER * 2 * CHN * CHN * 2));
    u16* mw2_lo = (u16*)(ws + alloc((size_t)NLAYER * 2 * CHN * CHN * 2));
    float* bn_scale = (float*)(ws + alloc(NLAYER * 3 * CHN * 4));
    float* bn_shift = (float*)(ws + alloc(NLAYER * 3 * CHN * 4));
    u32* counts = (u32*)(ws + alloc(NODES * 4));
    u32* offsets = (u32*)(ws + alloc((NODES + 1) * 4));
    u32* cursor = (u32*)(ws + alloc(NODES * 4));
    int2* csr_sa = (int2*)(ws + alloc((size_t)NEDGE * 8));

    const int* e_src = edge_index;
    const int* e_dst = edge_index + NEDGE;

    {
        SplitJobs j;
        const float* srcs[8] = {x, node_w, gine_w1, gine_w2, attn_in_w,
                                attn_out_w, mlp_w1, mlp_w2};
        u16* his[8] = {x_hi, node_w_hi, gw1_hi, gw2_hi, aiw_hi, aow_hi, mw1_hi, mw2_hi};
        u16* los[8] = {x_lo, node_w_lo, gw1_lo, gw2_lo, aiw_lo, aow_lo, mw1_lo, mw2_lo};
        int ns[8] = {NODES * 64, CHN * 64, NLAYER * CHN * CHN, NLAYER * CHN * CHN,
                     NLAYER * 3 * CHN * CHN, NLAYER * CHN * CHN,
                     NLAYER * 2 * CHN * CHN, NLAYER * 2 * CHN * CHN};
        int cum = 0;
        for (int i = 0; i < 8; ++i) {
            j.src[i] = srcs[i]; j.hi[i] = his[i]; j.lo[i] = los[i];
            cum += ns[i] / 256;
            j.blk_end[i] = cum;
        }
        k_split8<<<dim3(cum), dim3(256), 0, stream>>>(j);
    }

    k_bnprep<<<dim3((NLAYER * 3 * CHN + 255) / 256), dim3(256), 0, stream>>>(
        bn_g, bn_bb, bn_m, bn_v, bn_scale, bn_shift);

    k_zero_u32<<<dim3(NODES / 256), dim3(256), 0, stream>>>(counts, NODES);
    k_count<<<dim3(NEDGE / 256), dim3(256), 0, stream>>>(e_dst, counts);
    k_scan<<<dim3(1), dim3(256), 0, stream>>>(counts, offsets, cursor);
    k_fill<<<dim3(NEDGE / 256), dim3(256), 0, stream>>>(e_src, e_dst, edge_attr,
                                                        cursor, csr_sa);

    // node projection: h = x @ node_w^T + node_b
    k_gemm<<<dim3(NODES / 64, CHN / 32), dim3(256), 0, stream>>>(
        x_hi, x_lo, node_w_hi, node_w_lo, node_b, h_f32, h_hi, h_lo, 64, CHN);

    for (int l = 0; l < NLAYER; ++l) {
        size_t wo = (size_t)l * CHN * CHN;
        const float* sc0 = bn_scale + (l * 3 + 0) * CHN;
        const float* sh0 = bn_shift + (l * 3 + 0) * CHN;
        const float* sc1 = bn_scale + (l * 3 + 1) * CHN;
        const float* sh1 = bn_shift + (l * 3 + 1) * CHN;
        const float* sc2 = bn_scale + (l * 3 + 2) * CHN;
        const float* sh2 = bn_shift + (l * 3 + 2) * CHN;

        // agg (4096 blocks) ∥ qkv (3072 blocks)
        k_aggqkv<<<dim3(NODES / 4 + 3072), dim3(256), 0, stream>>>(
            h_hi, h_f32, offsets, csr_sa, edge_w, edge_b, zao_hi, zao_lo,
            h_lo, aiw_hi + wo * 3, aiw_lo + wo * 3, attn_in_b + l * 3 * CHN,
            q_hi, q_lo, kk_hi, kk_lo, vt_hi);
        // gine (512 blocks) ∥ attn (512 blocks)
        k_gineattn<<<dim3(NODES / 32 + 512), dim3(256), 0, stream>>>(
            zao_hi, zao_lo, gw1_hi + wo, gw1_lo + wo, gine_b1 + l * CHN,
            gw2_hi + wo, gw2_lo + wo, gine_b2 + l * CHN, h_f32, sc0, sh0, h1_f32,
            q_hi, q_lo, kk_hi, kk_lo, vt_hi, zao_hi, zao_lo);
        // out-proj + FFN
        k_outffn<<<dim3(NODES / 32), dim3(256), 0, stream>>>(
            zao_hi, zao_lo, aow_hi + wo, aow_lo + wo, attn_out_b + l * CHN,
            h_f32, sc1, sh1, h1_f32,
            mw1_hi + wo * 2, mw1_lo + wo * 2, mlp_b1 + l * 2 * CHN,
            mw2_hi + wo * 2, mw2_lo + wo * 2, mlp_b2 + l * CHN, sc2, sh2,
            h_f32, h_hi, h_lo);
    }

    k_zero_u32<<<dim3(NG * CHN / 256), dim3(256), 0, stream>>>((u32*)pool, NG * CHN);
    k_pool<<<dim3(NG, 8), dim3(128), 0, stream>>>(h_f32, pool);
    k_head<<<dim3(1), dim3(256), 0, stream>>>(pool, head_w1, head_b1, head_w2,
                                              head_b2, head_w3, head_b3,
                                              (float*)d_out);
}

// Round 13
// 688.696 us; speedup vs baseline: 1.6688x; 1.0528x over previous
//
#include <hip/hip_runtime.h>
#include <hip/hip_bf16.h>

typedef __attribute__((ext_vector_type(8))) short short8;
typedef __attribute__((ext_vector_type(4))) float f32x4;
typedef __attribute__((ext_vector_type(2))) unsigned int u32x2;
typedef unsigned short u16;
typedef unsigned int u32;
typedef unsigned long long u64;

#define NODES 16384
#define CHN 128
#define NEDGE 524288
#define NG 16
#define NPGC 1024
#define NHEAD 4
#define HDIM 32
#define NLAYER 4
#define CL 0.2550348281f   // log2(e)/sqrt(HDIM), folded into Q at QKV store

#if __has_builtin(__builtin_amdgcn_exp2f)
#define EXP2(x) __builtin_amdgcn_exp2f(x)
#else
#define EXP2(x) exp2f(x)
#endif

__device__ __forceinline__ float bf2f(u16 u) {
    union { u32 u; float f; } c; c.u = ((u32)u) << 16; return c.f;
}
__device__ __forceinline__ u16 f2bf(float f) {
    union { float f; u32 u; } c; c.f = f;
    u32 r = c.u + 0x7fffu + ((c.u >> 16) & 1u);
    return (u16)(r >> 16);
}
__device__ __forceinline__ void fsplit(float f, u16& hi, u16& lo) {
    u16 h = f2bf(f);
    hi = h;
    lo = f2bf(f - bf2f(h));
}
__device__ __forceinline__ u32 cvtpk_bf16(float a, float b) {
    u32 r;
    asm("v_cvt_pk_bf16_f32 %0, %1, %2" : "=v"(r) : "v"(a), "v"(b));
    return r;
}

#define MFMA16(a, b, c) __builtin_amdgcn_mfma_f32_16x16x32_bf16((a), (b), (c), 0, 0, 0)

__device__ __forceinline__ short8 ld_frag(const u16* p) {
    return *reinterpret_cast<const short8*>(p);
}

// ---------------- setup kernels ----------------

struct SplitJobs {
    const float* src[8];
    u16* hi[8];
    u16* lo[8];
    int blk_end[8];
};

__global__ void k_split8(SplitJobs jobs) {
    int b = blockIdx.x;
    int seg = 0;
    while (b >= jobs.blk_end[seg]) ++seg;
    int base = seg ? jobs.blk_end[seg - 1] : 0;
    int i = (b - base) * 256 + threadIdx.x;
    u16 h, l;
    fsplit(jobs.src[seg][i], h, l);
    jobs.hi[seg][i] = h;
    jobs.lo[seg][i] = l;
}

__global__ void k_bnprep(const float* __restrict__ g, const float* __restrict__ b,
                         const float* __restrict__ m, const float* __restrict__ v,
                         float* __restrict__ scale, float* __restrict__ shift) {
    int i = blockIdx.x * 256 + threadIdx.x;
    if (i < NLAYER * 3 * CHN) {
        float s = g[i] * rsqrtf(v[i] + 1e-5f);
        scale[i] = s;
        shift[i] = b[i] - m[i] * s;
    }
}

__global__ void k_zero_u32(u32* __restrict__ p, int n) {
    int i = blockIdx.x * 256 + threadIdx.x;
    if (i < n) p[i] = 0u;
}

__global__ void k_count(const int* __restrict__ dst, u32* __restrict__ counts) {
    int e = blockIdx.x * 256 + threadIdx.x;
    if (e < NEDGE) atomicAdd(&counts[dst[e]], 1u);
}

__global__ void k_scan(const u32* __restrict__ counts, u32* __restrict__ offsets,
                       u32* __restrict__ cursor) {
    __shared__ u32 part[256];
    int t = threadIdx.x;
    int base = t * 64;
    u32 s = 0;
    for (int i = 0; i < 64; ++i) s += counts[base + i];
    part[t] = s;
    __syncthreads();
    for (int off = 1; off < 256; off <<= 1) {
        u32 val = (t >= off) ? part[t - off] : 0u;
        __syncthreads();
        part[t] += val;
        __syncthreads();
    }
    u32 run = (t == 0) ? 0u : part[t - 1];
    for (int i = 0; i < 64; ++i) {
        offsets[base + i] = run;
        cursor[base + i] = run;
        run += counts[base + i];
    }
    if (t == 255) offsets[NODES] = run;
}

// combined (src, attr-bits) 8B store: halves scattered-write line traffic
__global__ void k_fill(const int* __restrict__ src, const int* __restrict__ dst,
                       const float* __restrict__ eattr, u32* __restrict__ cursor,
                       int2* __restrict__ csr_sa) {
    int e = blockIdx.x * 256 + threadIdx.x;
    if (e >= NEDGE) return;
    int d = dst[e];
    u32 p = atomicAdd(&cursor[d], 1u);
    csr_sa[p] = make_int2(src[e], __float_as_int(eattr[e]));
}

// ---- FAT kernel 1: GINE aggregation (blocks < NODES/4) ∥ QKV GEMM (rest) ----
// agg: 8-wide unrolled gather pipeline (8 independent h-row loads in flight).

__global__ __launch_bounds__(256) void k_aggqkv(
    // agg args
    const u16* __restrict__ h_hi, const float* __restrict__ h_f32,
    const u32* __restrict__ offsets, const int2* __restrict__ csr_sa,
    const float* __restrict__ ew, const float* __restrict__ eb,
    u16* __restrict__ z_hi, u16* __restrict__ z_lo,
    // qkv args
    const u16* __restrict__ h_lo, const u16* __restrict__ Whi,
    const u16* __restrict__ Wlo, const float* __restrict__ bias,
    u16* __restrict__ q_hi, u16* __restrict__ q_lo,
    u16* __restrict__ k_hi, u16* __restrict__ k_lo,
    u16* __restrict__ vt_hi) {
    int tid = threadIdx.x;
    int wave = tid >> 6, lane = tid & 63;
    if (blockIdx.x < NODES / 4) {
        // ---- aggregation: 4 nodes/block, one wave per node, 2 channels/lane ----
        int node = blockIdx.x * 4 + wave;
        int c0 = lane * 2;
        float w0 = ew[c0], w1 = ew[c0 + 1];
        float b0 = eb[c0], b1 = eb[c0 + 1];
        u32 beg = offsets[node], end = offsets[node + 1];
        float acc0 = 0.f, acc1 = 0.f;
        u32 i = beg;
        // 8-wide unrolled main loop: 8 independent gathers in flight
        for (; i + 8 <= end; i += 8) {
            int2 es[8];
            u32 us[8];
#pragma unroll
            for (int j = 0; j < 8; ++j) es[j] = csr_sa[i + j];
#pragma unroll
            for (int j = 0; j < 8; ++j)
                us[j] = *reinterpret_cast<const u32*>(
                    h_hi + (size_t)es[j].x * CHN + c0);
#pragma unroll
            for (int j = 0; j < 8; ++j) {
                float a = __int_as_float(es[j].y);
                float f0 = bf2f((u16)(us[j] & 0xffffu));
                float f1 = bf2f((u16)(us[j] >> 16));
                acc0 += fmaxf(f0 + a * w0 + b0, 0.f);
                acc1 += fmaxf(f1 + a * w1 + b1, 0.f);
            }
        }
        for (; i < end; ++i) {
            int2 e = csr_sa[i];
            u32 u = *reinterpret_cast<const u32*>(h_hi + (size_t)e.x * CHN + c0);
            float a = __int_as_float(e.y);
            float f0 = bf2f((u16)(u & 0xffffu));
            float f1 = bf2f((u16)(u >> 16));
            acc0 += fmaxf(f0 + a * w0 + b0, 0.f);
            acc1 += fmaxf(f1 + a * w1 + b1, 0.f);
        }
        size_t idx = (size_t)node * CHN + c0;
        float z0 = h_f32[idx] + acc0;
        float z1v = h_f32[idx + 1] + acc1;
        u16 h, l;
        fsplit(z0, h, l); z_hi[idx] = h; z_lo[idx] = l;
        fsplit(z1v, h, l); z_hi[idx + 1] = h; z_lo[idx + 1] = l;
        return;
    }
    // ---- QKV GEMM; Q pre-scaled by CL ----
    const int K = 128;
    int id = blockIdx.x - NODES / 4;
    int bx = id & 255, ny = id >> 8;
    int lr = lane & 15, lg = lane >> 4;
    int r0 = bx * 64 + wave * 16;
    int nb = ny * 32;
    f32x4 acc[2] = {};
    size_t arow = (size_t)(r0 + lr) * K + lg * 8;
    for (int ks = 0; ks < K; ks += 32) {
        short8 ah = ld_frag(h_hi + arow + ks);
        short8 al = ld_frag(h_lo + arow + ks);
#pragma unroll
        for (int n = 0; n < 2; ++n) {
            size_t wrow = (size_t)(nb + n * 16 + lr) * K + ks + lg * 8;
            short8 wh = ld_frag(Whi + wrow);
            short8 wl = ld_frag(Wlo + wrow);
            acc[n] = MFMA16(ah, wh, acc[n]);
            acc[n] = MFMA16(al, wh, acc[n]);
            acc[n] = MFMA16(ah, wl, acc[n]);
        }
    }
#pragma unroll
    for (int n = 0; n < 2; ++n) {
        int col = nb + n * 16 + lr;
        int region = col >> 7;
        int c = col & 127;
        int hh = c >> 5, d = c & 31;
        float bs = bias[col];
#pragma unroll
        for (int r = 0; r < 4; ++r) {
            int row = r0 + lg * 4 + r;
            float v = acc[n][r] + bs;
            int g = row >> 10, p = row & 1023;
            size_t gh = (size_t)(g * NHEAD + hh);
            if (region == 0) {
                u16 vh, vl;
                fsplit(v * CL, vh, vl);
                size_t o = (gh * NPGC + p) * HDIM + d;
                q_hi[o] = vh; q_lo[o] = vl;
            } else if (region == 1) {
                u16 vh, vl;
                fsplit(v, vh, vl);
                size_t o = (gh * NPGC + p) * HDIM + d;
                k_hi[o] = vh; k_lo[o] = vl;
            } else {
                vt_hi[(gh * HDIM + d) * NPGC + p] = f2bf(v);
            }
        }
    }
}

// ------ split GEMM (16x32 wave tile) — used for node projection ------

__global__ __launch_bounds__(256) void k_gemm(
    const u16* __restrict__ Ahi, const u16* __restrict__ Alo,
    const u16* __restrict__ Whi, const u16* __restrict__ Wlo,
    const float* __restrict__ bias, float* __restrict__ out_f32,
    u16* __restrict__ out_hi, u16* __restrict__ out_lo, int K, int Nc) {
    int tid = threadIdx.x;
    int wave = tid >> 6, lane = tid & 63;
    int lr = lane & 15, lg = lane >> 4;
    int r0 = blockIdx.x * 64 + wave * 16;
    int nb = blockIdx.y * 32;
    f32x4 acc[2] = {};
    size_t arow = (size_t)(r0 + lr) * K + lg * 8;
    for (int ks = 0; ks < K; ks += 32) {
        short8 ah = ld_frag(Ahi + arow + ks);
        short8 al = ld_frag(Alo + arow + ks);
#pragma unroll
        for (int n = 0; n < 2; ++n) {
            size_t wrow = (size_t)(nb + n * 16 + lr) * K + ks + lg * 8;
            short8 wh = ld_frag(Whi + wrow);
            short8 wl = ld_frag(Wlo + wrow);
            acc[n] = MFMA16(ah, wh, acc[n]);
            acc[n] = MFMA16(al, wh, acc[n]);
            acc[n] = MFMA16(ah, wl, acc[n]);
        }
    }
#pragma unroll
    for (int n = 0; n < 2; ++n) {
        int col = nb + n * 16 + lr;
        float bs = bias[col];
#pragma unroll
        for (int r = 0; r < 4; ++r) {
            int row = r0 + lg * 4 + r;
            size_t oidx = (size_t)row * Nc + col;
            float v = acc[n][r] + bs;
            out_f32[oidx] = v;
            u16 hh, ll;
            fsplit(v, hh, ll);
            out_hi[oidx] = hh; out_lo[oidx] = ll;
        }
    }
}

// ---- FAT kernel 2: fused GINE MLP (blocks < 512) ∥ flash attention (rest) ----

__global__ __launch_bounds__(256) void k_gineattn(
    // gine args
    const u16* __restrict__ zhi, const u16* __restrict__ zlo,
    const u16* __restrict__ w1hi, const u16* __restrict__ w1lo,
    const float* __restrict__ b1,
    const u16* __restrict__ w2hi, const u16* __restrict__ w2lo,
    const float* __restrict__ b2, const float* __restrict__ resid,
    const float* __restrict__ bnsc, const float* __restrict__ bnsh,
    float* __restrict__ h1out,
    // attn args
    const u16* __restrict__ qhi, const u16* __restrict__ qlo,
    const u16* __restrict__ khi, const u16* __restrict__ klo,
    const u16* __restrict__ vthi,
    u16* __restrict__ aohi, u16* __restrict__ aolo) {
    __shared__ __align__(16) u16 smem[64][136];
    int tid = threadIdx.x;
    int wave = tid >> 6, lane = tid & 63;
    int lr = lane & 15, lg = lane >> 4;
    if (blockIdx.x < NODES / 32) {
        // ---------------- GINE MLP: 32 rows/block, 2 row-groups/wave ----------------
        int r0 = blockIdx.x * 32;
        int cb = wave * 32;
        {
            f32x4 acc[2][2] = {};
            size_t arow0 = (size_t)(r0 + lr) * CHN + lg * 8;
            size_t arow1 = (size_t)(r0 + 16 + lr) * CHN + lg * 8;
            for (int ks = 0; ks < CHN; ks += 32) {
                short8 ah0 = ld_frag(zhi + arow0 + ks);
                short8 al0 = ld_frag(zlo + arow0 + ks);
                short8 ah1 = ld_frag(zhi + arow1 + ks);
                short8 al1 = ld_frag(zlo + arow1 + ks);
#pragma unroll
                for (int n = 0; n < 2; ++n) {
                    size_t wrow = (size_t)(cb + n * 16 + lr) * CHN + ks + lg * 8;
                    short8 wh = ld_frag(w1hi + wrow);
                    short8 wl = ld_frag(w1lo + wrow);
                    acc[0][n] = MFMA16(ah0, wh, acc[0][n]);
                    acc[0][n] = MFMA16(al0, wh, acc[0][n]);
                    acc[0][n] = MFMA16(ah0, wl, acc[0][n]);
                    acc[1][n] = MFMA16(ah1, wh, acc[1][n]);
                    acc[1][n] = MFMA16(al1, wh, acc[1][n]);
                    acc[1][n] = MFMA16(ah1, wl, acc[1][n]);
                }
            }
#pragma unroll
            for (int rg = 0; rg < 2; ++rg)
#pragma unroll
                for (int n = 0; n < 2; ++n) {
                    int col = cb + n * 16 + lr;
                    float bs = b1[col];
#pragma unroll
                    for (int r = 0; r < 4; ++r) {
                        float v = fmaxf(acc[rg][n][r] + bs, 0.f);
                        u16 hh, ll;
                        fsplit(v, hh, ll);
                        int rl = rg * 16 + lg * 4 + r;
                        smem[rl][col] = hh;        // t_hi
                        smem[32 + rl][col] = ll;   // t_lo
                    }
                }
        }
        __syncthreads();
        {
            f32x4 acc[2][2] = {};
            for (int ks = 0; ks < CHN; ks += 32) {
                short8 ah0 = ld_frag(&smem[lr][ks + lg * 8]);
                short8 al0 = ld_frag(&smem[32 + lr][ks + lg * 8]);
                short8 ah1 = ld_frag(&smem[16 + lr][ks + lg * 8]);
                short8 al1 = ld_frag(&smem[48 + lr][ks + lg * 8]);
#pragma unroll
                for (int n = 0; n < 2; ++n) {
                    size_t wrow = (size_t)(cb + n * 16 + lr) * CHN + ks + lg * 8;
                    short8 wh = ld_frag(w2hi + wrow);
                    short8 wl = ld_frag(w2lo + wrow);
                    acc[0][n] = MFMA16(ah0, wh, acc[0][n]);
                    acc[0][n] = MFMA16(al0, wh, acc[0][n]);
                    acc[0][n] = MFMA16(ah0, wl, acc[0][n]);
                    acc[1][n] = MFMA16(ah1, wh, acc[1][n]);
                    acc[1][n] = MFMA16(al1, wh, acc[1][n]);
                    acc[1][n] = MFMA16(ah1, wl, acc[1][n]);
                }
            }
#pragma unroll
            for (int rg = 0; rg < 2; ++rg)
#pragma unroll
                for (int n = 0; n < 2; ++n) {
                    int col = cb + n * 16 + lr;
                    float bs = b2[col], sc = bnsc[col], sh = bnsh[col];
#pragma unroll
                    for (int r = 0; r < 4; ++r) {
                        int row = r0 + rg * 16 + lg * 4 + r;
                        size_t oidx = (size_t)row * CHN + col;
                        float v = acc[rg][n][r] + bs + resid[oidx];
                        h1out[oidx] = v * sc + sh;
                    }
                }
        }
        return;
    }
    // ---------------- attention: swapped QK^T, dual-stream, defer-max ----------------
    int id = blockIdx.x - NODES / 32;
    int gh = id & 63;           // id%8==gh%8 -> per-gh XCD locality (512 offset %8==0)
    int bx = id >> 6;           // 0..7
    int qA = bx * 128 + wave * 32;
    int qB = qA + 16;
    size_t base = (size_t)gh * NPGC * HDIM;
    size_t vbase = (size_t)gh * HDIM * NPGC;
    short8 qhA = ld_frag(qhi + base + (size_t)(qA + lr) * HDIM + lg * 8);
    short8 qlA = ld_frag(qlo + base + (size_t)(qA + lr) * HDIM + lg * 8);
    short8 qhB = ld_frag(qhi + base + (size_t)(qB + lr) * HDIM + lg * 8);
    short8 qlB = ld_frag(qlo + base + (size_t)(qB + lr) * HDIM + lg * 8);
    const u16* Kh = khi + base;
    const u16* Kl = klo + base;
    const u16* Vh = vthi + vbase;
    f32x4 o0A = {}, o1A = {}, o0B = {}, o1B = {};
    f32x4 lsA = {}, lsB = {};
    float mA = -1e30f, mB = -1e30f;
    const f32x4 zero = {};
    u16 (*plds)[136] = &smem[wave * 16];
    for (int kv = 0; kv < NPGC; kv += 128) {
        f32x4 sA[8], sB[8];
        __builtin_amdgcn_s_setprio(1);
#pragma unroll
        for (int f = 0; f < 8; ++f) {
            size_t kr = (size_t)(kv + f * 16 + lr) * HDIM + lg * 8;
            short8 kh = ld_frag(Kh + kr);
            short8 kl2 = ld_frag(Kl + kr);
            sA[f] = MFMA16(kh, qlA, MFMA16(kl2, qhA, MFMA16(kh, qhA, zero)));
            sB[f] = MFMA16(kh, qlB, MFMA16(kl2, qhB, MFMA16(kh, qhB, zero)));
        }
        __builtin_amdgcn_s_setprio(0);
        // softmax A: defer-max fast path
        {
            f32x4 mm = sA[0];
#pragma unroll
            for (int f = 1; f < 8; ++f)
#pragma unroll
                for (int i = 0; i < 4; ++i) mm[i] = fmaxf(mm[i], sA[f][i]);
            float mx = fmaxf(fmaxf(mm[0], mm[1]), fmaxf(mm[2], mm[3]));
            if (!__all(mx <= mA + 8.f)) {
                mx = fmaxf(mx, __shfl_xor(mx, 16));
                mx = fmaxf(mx, __shfl_xor(mx, 32));
                float mn = fmaxf(mA, mx);
                float corr = EXP2(mA - mn);
                mA = mn;
#pragma unroll
                for (int i = 0; i < 4; ++i) {
                    lsA[i] *= corr;
                    o0A[i] *= corr; o1A[i] *= corr;
                }
            }
#pragma unroll
            for (int f = 0; f < 8; ++f)
#pragma unroll
                for (int i = 0; i < 4; ++i) sA[f][i] = EXP2(sA[f][i] - mA);
            f32x4 s4 = sA[0];
#pragma unroll
            for (int f = 1; f < 8; ++f)
#pragma unroll
                for (int i = 0; i < 4; ++i) s4[i] += sA[f][i];
            lsA += s4;
#pragma unroll
            for (int f = 0; f < 8; ++f) {
                u32x2 wv;
                wv[0] = cvtpk_bf16(sA[f][0], sA[f][1]);
                wv[1] = cvtpk_bf16(sA[f][2], sA[f][3]);
                *reinterpret_cast<u32x2*>(&plds[lr][f * 16 + lg * 4]) = wv;
            }
        }
        // PV A (V frags kept for B)
        short8 vs0[4], vs1[4];
        __builtin_amdgcn_s_setprio(1);
#pragma unroll
        for (int kk = 0; kk < 4; ++kk) {
            short8 pf = ld_frag(&plds[lr][kk * 32 + lg * 8]);
            vs0[kk] = ld_frag(Vh + (size_t)lr * NPGC + kv + kk * 32 + lg * 8);
            vs1[kk] = ld_frag(Vh + (size_t)(16 + lr) * NPGC + kv + kk * 32 + lg * 8);
            o0A = MFMA16(vs0[kk], pf, o0A);
            o1A = MFMA16(vs1[kk], pf, o1A);
        }
        __builtin_amdgcn_s_setprio(0);
        // softmax B
        {
            f32x4 mm = sB[0];
#pragma unroll
            for (int f = 1; f < 8; ++f)
#pragma unroll
                for (int i = 0; i < 4; ++i) mm[i] = fmaxf(mm[i], sB[f][i]);
            float mx = fmaxf(fmaxf(mm[0], mm[1]), fmaxf(mm[2], mm[3]));
            if (!__all(mx <= mB + 8.f)) {
                mx = fmaxf(mx, __shfl_xor(mx, 16));
                mx = fmaxf(mx, __shfl_xor(mx, 32));
                float mn = fmaxf(mB, mx);
                float corr = EXP2(mB - mn);
                mB = mn;
#pragma unroll
                for (int i = 0; i < 4; ++i) {
                    lsB[i] *= corr;
                    o0B[i] *= corr; o1B[i] *= corr;
                }
            }
#pragma unroll
            for (int f = 0; f < 8; ++f)
#pragma unroll
                for (int i = 0; i < 4; ++i) sB[f][i] = EXP2(sB[f][i] - mB);
            f32x4 s4 = sB[0];
#pragma unroll
            for (int f = 1; f < 8; ++f)
#pragma unroll
                for (int i = 0; i < 4; ++i) s4[i] += sB[f][i];
            lsB += s4;
#pragma unroll
            for (int f = 0; f < 8; ++f) {
                u32x2 wv;
                wv[0] = cvtpk_bf16(sB[f][0], sB[f][1]);
                wv[1] = cvtpk_bf16(sB[f][2], sB[f][3]);
                *reinterpret_cast<u32x2*>(&plds[lr][f * 16 + lg * 4]) = wv;
            }
        }
        // PV B
        __builtin_amdgcn_s_setprio(1);
#pragma unroll
        for (int kk = 0; kk < 4; ++kk) {
            short8 pf = ld_frag(&plds[lr][kk * 32 + lg * 8]);
            o0B = MFMA16(vs0[kk], pf, o0B);
            o1B = MFMA16(vs1[kk], pf, o1B);
        }
        __builtin_amdgcn_s_setprio(0);
    }
    float lA = (lsA[0] + lsA[1]) + (lsA[2] + lsA[3]);
    lA += __shfl_xor(lA, 16);
    lA += __shfl_xor(lA, 32);
    float lB = (lsB[0] + lsB[1]) + (lsB[2] + lsB[3]);
    lB += __shfl_xor(lB, 16);
    lB += __shfl_xor(lB, 32);
    int g = gh >> 2, hh = gh & 3;
    {
        float inv = 1.f / lA;
        size_t obase = ((size_t)g * NPGC + qA + lr) * CHN + hh * HDIM;
        union { u16 u[4]; u64 v; } p0h, p0l, p1h, p1l;
#pragma unroll
        for (int i = 0; i < 4; ++i) {
            u16 a, b;
            fsplit(o0A[i] * inv, a, b); p0h.u[i] = a; p0l.u[i] = b;
            fsplit(o1A[i] * inv, a, b); p1h.u[i] = a; p1l.u[i] = b;
        }
        *reinterpret_cast<u64*>(aohi + obase + lg * 4) = p0h.v;
        *reinterpret_cast<u64*>(aolo + obase + lg * 4) = p0l.v;
        *reinterpret_cast<u64*>(aohi + obase + 16 + lg * 4) = p1h.v;
        *reinterpret_cast<u64*>(aolo + obase + 16 + lg * 4) = p1l.v;
    }
    {
        float inv = 1.f / lB;
        size_t obase = ((size_t)g * NPGC + qB + lr) * CHN + hh * HDIM;
        union { u16 u[4]; u64 v; } p0h, p0l, p1h, p1l;
#pragma unroll
        for (int i = 0; i < 4; ++i) {
            u16 a, b;
            fsplit(o0B[i] * inv, a, b); p0h.u[i] = a; p0l.u[i] = b;
            fsplit(o1B[i] * inv, a, b); p1h.u[i] = a; p1l.u[i] = b;
        }
        *reinterpret_cast<u64*>(aohi + obase + lg * 4) = p0h.v;
        *reinterpret_cast<u64*>(aolo + obase + lg * 4) = p0l.v;
        *reinterpret_cast<u64*>(aohi + obase + 16 + lg * 4) = p1h.v;
        *reinterpret_cast<u64*>(aolo + obase + 16 + lg * 4) = p1l.v;
    }
}

// ---- fused out-proj + FFN, 32 rows/block, weight frags shared across 2 row-groups ----

__global__ __launch_bounds__(256) void k_outffn(
    const u16* __restrict__ aoh, const u16* __restrict__ aol,
    const u16* __restrict__ awh, const u16* __restrict__ awl,
    const float* __restrict__ ab, const float* __restrict__ hres,
    const float* __restrict__ sc1, const float* __restrict__ sh1,
    const float* __restrict__ h1res,
    const u16* __restrict__ w1h, const u16* __restrict__ w1l,
    const float* __restrict__ b1,
    const u16* __restrict__ w2h, const u16* __restrict__ w2l,
    const float* __restrict__ b2,
    const float* __restrict__ sc2, const float* __restrict__ sh2,
    float* __restrict__ hf, u16* __restrict__ hhi, u16* __restrict__ hlo) {
    __shared__ __align__(16) u16 o_hi[32][136];
    __shared__ __align__(16) u16 o_lo[32][136];
    __shared__ __align__(16) u16 t_hi[32][264];
    __shared__ __align__(16) u16 t_lo[32][264];
    int tid = threadIdx.x;
    int wave = tid >> 6, lane = tid & 63;
    int lr = lane & 15, lg = lane >> 4;
    int r0 = blockIdx.x * 32;
    int cb = wave * 32;
    {
        f32x4 acc[2][2] = {};
        size_t arow0 = (size_t)(r0 + lr) * CHN + lg * 8;
        size_t arow1 = (size_t)(r0 + 16 + lr) * CHN + lg * 8;
        for (int ks = 0; ks < CHN; ks += 32) {
            short8 ah0 = ld_frag(aoh + arow0 + ks);
            short8 al0 = ld_frag(aol + arow0 + ks);
            short8 ah1 = ld_frag(aoh + arow1 + ks);
            short8 al1 = ld_frag(aol + arow1 + ks);
#pragma unroll
            for (int n = 0; n < 2; ++n) {
                size_t wrow = (size_t)(cb + n * 16 + lr) * CHN + ks + lg * 8;
                short8 wh = ld_frag(awh + wrow);
                short8 wl = ld_frag(awl + wrow);
                acc[0][n] = MFMA16(ah0, wh, acc[0][n]);
                acc[0][n] = MFMA16(al0, wh, acc[0][n]);
                acc[0][n] = MFMA16(ah0, wl, acc[0][n]);
                acc[1][n] = MFMA16(ah1, wh, acc[1][n]);
                acc[1][n] = MFMA16(al1, wh, acc[1][n]);
                acc[1][n] = MFMA16(ah1, wl, acc[1][n]);
            }
        }
#pragma unroll
        for (int rg = 0; rg < 2; ++rg)
#pragma unroll
            for (int n = 0; n < 2; ++n) {
                int col = cb + n * 16 + lr;
                float bs = ab[col], sc = sc1[col], sh = sh1[col];
#pragma unroll
                for (int r = 0; r < 4; ++r) {
                    int row = r0 + rg * 16 + lg * 4 + r;
                    int rl = rg * 16 + lg * 4 + r;
                    size_t oidx = (size_t)row * CHN + col;
                    float v = (acc[rg][n][r] + bs + hres[oidx]) * sc + sh + h1res[oidx];
                    u16 hh, ll;
                    fsplit(v, hh, ll);
                    o_hi[rl][col] = hh; o_lo[rl][col] = ll;
                }
            }
    }
    __syncthreads();
    {
        f32x4 acc[2][4] = {};
        int cbB = wave * 64;
        for (int ks = 0; ks < CHN; ks += 32) {
            short8 ah0 = ld_frag(&o_hi[lr][ks + lg * 8]);
            short8 al0 = ld_frag(&o_lo[lr][ks + lg * 8]);
            short8 ah1 = ld_frag(&o_hi[16 + lr][ks + lg * 8]);
            short8 al1 = ld_frag(&o_lo[16 + lr][ks + lg * 8]);
#pragma unroll
            for (int n = 0; n < 4; ++n) {
                size_t wrow = (size_t)(cbB + n * 16 + lr) * CHN + ks + lg * 8;
                short8 wh = ld_frag(w1h + wrow);
                short8 wl = ld_frag(w1l + wrow);
                acc[0][n] = MFMA16(ah0, wh, acc[0][n]);
                acc[0][n] = MFMA16(al0, wh, acc[0][n]);
                acc[0][n] = MFMA16(ah0, wl, acc[0][n]);
                acc[1][n] = MFMA16(ah1, wh, acc[1][n]);
                acc[1][n] = MFMA16(al1, wh, acc[1][n]);
                acc[1][n] = MFMA16(ah1, wl, acc[1][n]);
            }
        }
#pragma unroll
        for (int rg = 0; rg < 2; ++rg)
#pragma unroll
            for (int n = 0; n < 4; ++n) {
                int col = cbB + n * 16 + lr;
                float bs = b1[col];
#pragma unroll
                for (int r = 0; r < 4; ++r) {
                    float v = fmaxf(acc[rg][n][r] + bs, 0.f);
                    u16 hh, ll;
                    fsplit(v, hh, ll);
                    int rl = rg * 16 + lg * 4 + r;
                    t_hi[rl][col] = hh;
                    t_lo[rl][col] = ll;
                }
            }
    }
    __syncthreads();
    {
        f32x4 acc[2][2] = {};
        for (int ks = 0; ks < 2 * CHN; ks += 32) {
            short8 ah0 = ld_frag(&t_hi[lr][ks + lg * 8]);
            short8 al0 = ld_frag(&t_lo[lr][ks + lg * 8]);
            short8 ah1 = ld_frag(&t_hi[16 + lr][ks + lg * 8]);
            short8 al1 = ld_frag(&t_lo[16 + lr][ks + lg * 8]);
#pragma unroll
            for (int n = 0; n < 2; ++n) {
                size_t wrow = (size_t)(cb + n * 16 + lr) * 2 * CHN + ks + lg * 8;
                short8 wh = ld_frag(w2h + wrow);
                short8 wl = ld_frag(w2l + wrow);
                acc[0][n] = MFMA16(ah0, wh, acc[0][n]);
                acc[0][n] = MFMA16(al0, wh, acc[0][n]);
                acc[0][n] = MFMA16(ah0, wl, acc[0][n]);
                acc[1][n] = MFMA16(ah1, wh, acc[1][n]);
                acc[1][n] = MFMA16(al1, wh, acc[1][n]);
                acc[1][n] = MFMA16(ah1, wl, acc[1][n]);
            }
        }
#pragma unroll
        for (int rg = 0; rg < 2; ++rg)
#pragma unroll
            for (int n = 0; n < 2; ++n) {
                int col = cb + n * 16 + lr;
                float bs = b2[col], sc = sc2[col], sh = sh2[col];
#pragma unroll
                for (int r = 0; r < 4; ++r) {
                    int row = r0 + rg * 16 + lg * 4 + r;
                    int rl = rg * 16 + lg * 4 + r;
                    size_t oidx = (size_t)row * CHN + col;
                    float ores = bf2f(o_hi[rl][col]) + bf2f(o_lo[rl][col]);
                    float v = (acc[rg][n][r] + bs + ores) * sc + sh;
                    hf[oidx] = v;
                    u16 hh, ll;
                    fsplit(v, hh, ll);
                    hhi[oidx] = hh; hlo[oidx] = ll;
                }
            }
    }
}

// ---------------- pooling + head MLP ----------------

__global__ __launch_bounds__(128) void k_pool(const float* __restrict__ h,
                                              float* __restrict__ pool) {
    int g = blockIdx.x, sl = blockIdx.y, c = threadIdx.x;
    const float* p = h + ((size_t)g * NPGC + sl * 128) * CHN + c;
    float s = 0.f;
    for (int i = 0; i < 128; ++i) s += p[(size_t)i * CHN];
    atomicAdd(&pool[g * CHN + c], s);
}

__global__ __launch_bounds__(256) void k_head(
    const float* __restrict__ pool, const float* __restrict__ w1,
    const float* __restrict__ b1, const float* __restrict__ w2,
    const float* __restrict__ b2, const float* __restrict__ w3,
    const float* __restrict__ b3, float* __restrict__ out) {
    __shared__ float g1[16][64];
    __shared__ float g2[16][32];
    int t = threadIdx.x;
    for (int idx = t; idx < 16 * 64; idx += 256) {
        int g = idx >> 6, n = idx & 63;
        float s = b1[n];
        for (int k = 0; k < 128; ++k) s += pool[g * 128 + k] * w1[n * 128 + k];
        g1[g][n] = fmaxf(s, 0.f);
    }
    __syncthreads();
    for (int idx = t; idx < 16 * 32; idx += 256) {
        int g = idx >> 5, n = idx & 31;
        float s = b2[n];
        for (int k = 0; k < 64; ++k) s += g1[g][k] * w2[n * 64 + k];
        g2[g][n] = fmaxf(s, 0.f);
    }
    __syncthreads();
    if (t < 16) {
        float s = b3[0];
        for (int k = 0; k < 32; ++k) s += g2[t][k] * w3[k];
        out[t] = s;
    }
}

// ---------------- host ----------------

extern "C" void kernel_launch(void* const* d_in, const int* in_sizes, int n_in,
                              void* d_out, int out_size, void* d_ws, size_t ws_size,
                              hipStream_t stream) {
    (void)in_sizes; (void)n_in; (void)out_size; (void)ws_size;
    const float* x = (const float*)d_in[0];
    const float* edge_attr = (const float*)d_in[1];
    const int* edge_index = (const int*)d_in[2];
    const float* node_w = (const float*)d_in[4];
    const float* node_b = (const float*)d_in[5];
    const float* edge_w = (const float*)d_in[6];
    const float* edge_b = (const float*)d_in[7];
    const float* gine_w1 = (const float*)d_in[8];
    const float* gine_b1 = (const float*)d_in[9];
    const float* gine_w2 = (const float*)d_in[10];
    const float* gine_b2 = (const float*)d_in[11];
    const float* attn_in_w = (const float*)d_in[12];
    const float* attn_in_b = (const float*)d_in[13];
    const float* attn_out_w = (const float*)d_in[14];
    const float* attn_out_b = (const float*)d_in[15];
    const float* mlp_w1 = (const float*)d_in[16];
    const float* mlp_b1 = (const float*)d_in[17];
    const float* mlp_w2 = (const float*)d_in[18];
    const float* mlp_b2 = (const float*)d_in[19];
    const float* bn_g = (const float*)d_in[20];
    const float* bn_bb = (const float*)d_in[21];
    const float* bn_m = (const float*)d_in[22];
    const float* bn_v = (const float*)d_in[23];
    const float* head_w1 = (const float*)d_in[24];
    const float* head_b1 = (const float*)d_in[25];
    const float* head_w2 = (const float*)d_in[26];
    const float* head_b2 = (const float*)d_in[27];
    const float* head_w3 = (const float*)d_in[28];
    const float* head_b3 = (const float*)d_in[29];

    char* ws = (char*)d_ws;
    size_t off = 0;
    auto alloc = [&](size_t bytes) {
        size_t r = off;
        off = (off + bytes + 255) & ~(size_t)255;
        return r;
    };
    const size_t NC = (size_t)NODES * CHN;
    float* h_f32 = (float*)(ws + alloc(NC * 4));
    u16* h_hi = (u16*)(ws + alloc(NC * 2));
    u16* h_lo = (u16*)(ws + alloc(NC * 2));
    u16* x_hi = (u16*)(ws + alloc((size_t)NODES * 64 * 2));
    u16* x_lo = (u16*)(ws + alloc((size_t)NODES * 64 * 2));
    u16* zao_hi = (u16*)(ws + alloc(NC * 2));
    u16* zao_lo = (u16*)(ws + alloc(NC * 2));
    float* h1_f32 = (float*)(ws + alloc(NC * 4));
    u16* q_hi = (u16*)(ws + alloc(NC * 2));
    u16* q_lo = (u16*)(ws + alloc(NC * 2));
    u16* kk_hi = (u16*)(ws + alloc(NC * 2));
    u16* kk_lo = (u16*)(ws + alloc(NC * 2));
    u16* vt_hi = (u16*)(ws + alloc(NC * 2));
    float* pool = (float*)(ws + alloc(NG * CHN * 4));
    u16* node_w_hi = (u16*)(ws + alloc(CHN * 64 * 2));
    u16* node_w_lo = (u16*)(ws + alloc(CHN * 64 * 2));
    u16* gw1_hi = (u16*)(ws + alloc((size_t)NLAYER * CHN * CHN * 2));
    u16* gw1_lo = (u16*)(ws + alloc((size_t)NLAYER * CHN * CHN * 2));
    u16* gw2_hi = (u16*)(ws + alloc((size_t)NLAYER * CHN * CHN * 2));
    u16* gw2_lo = (u16*)(ws + alloc((size_t)NLAYER * CHN * CHN * 2));
    u16* aiw_hi = (u16*)(ws + alloc((size_t)NLAYER * 3 * CHN * CHN * 2));
    u16* aiw_lo = (u16*)(ws + alloc((size_t)NLAYER * 3 * CHN * CHN * 2));
    u16* aow_hi = (u16*)(ws + alloc((size_t)NLAYER * CHN * CHN * 2));
    u16* aow_lo = (u16*)(ws + alloc((size_t)NLAYER * CHN * CHN * 2));
    u16* mw1_hi = (u16*)(ws + alloc((size_t)NLAYER * 2 * CHN * CHN * 2));
    u16* mw1_lo = (u16*)(ws + alloc((size_t)NLAYER * 2 * CHN * CHN * 2));
    u16* mw2_hi = (u16*)(ws + alloc((size_t)NLAYER * 2 * CHN * CHN * 2));
    u16* mw2_lo = (u16*)(ws + alloc((size_t)NLAYER * 2 * CHN * CHN * 2));
    float* bn_scale = (float*)(ws + alloc(NLAYER * 3 * CHN * 4));
    float* bn_shift = (float*)(ws + alloc(NLAYER * 3 * CHN * 4));
    u32* counts = (u32*)(ws + alloc(NODES * 4));
    u32* offsets = (u32*)(ws + alloc((NODES + 1) * 4));
    u32* cursor = (u32*)(ws + alloc(NODES * 4));
    int2* csr_sa = (int2*)(ws + alloc((size_t)NEDGE * 8));

    const int* e_src = edge_index;
    const int* e_dst = edge_index + NEDGE;

    {
        SplitJobs j;
        const float* srcs[8] = {x, node_w, gine_w1, gine_w2, attn_in_w,
                                attn_out_w, mlp_w1, mlp_w2};
        u16* his[8] = {x_hi, node_w_hi, gw1_hi, gw2_hi, aiw_hi, aow_hi, mw1_hi, mw2_hi};
        u16* los[8] = {x_lo, node_w_lo, gw1_lo, gw2_lo, aiw_lo, aow_lo, mw1_lo, mw2_lo};
        int ns[8] = {NODES * 64, CHN * 64, NLAYER * CHN * CHN, NLAYER * CHN * CHN,
                     NLAYER * 3 * CHN * CHN, NLAYER * CHN * CHN,
                     NLAYER * 2 * CHN * CHN, NLAYER * 2 * CHN * CHN};
        int cum = 0;
        for (int i = 0; i < 8; ++i) {
            j.src[i] = srcs[i]; j.hi[i] = his[i]; j.lo[i] = los[i];
            cum += ns[i] / 256;
            j.blk_end[i] = cum;
        }
        k_split8<<<dim3(cum), dim3(256), 0, stream>>>(j);
    }

    k_bnprep<<<dim3((NLAYER * 3 * CHN + 255) / 256), dim3(256), 0, stream>>>(
        bn_g, bn_bb, bn_m, bn_v, bn_scale, bn_shift);

    k_zero_u32<<<dim3(NODES / 256), dim3(256), 0, stream>>>(counts, NODES);
    k_count<<<dim3(NEDGE / 256), dim3(256), 0, stream>>>(e_dst, counts);
    k_scan<<<dim3(1), dim3(256), 0, stream>>>(counts, offsets, cursor);
    k_fill<<<dim3(NEDGE / 256), dim3(256), 0, stream>>>(e_src, e_dst, edge_attr,
                                                        cursor, csr_sa);

    // node projection: h = x @ node_w^T + node_b
    k_gemm<<<dim3(NODES / 64, CHN / 32), dim3(256), 0, stream>>>(
        x_hi, x_lo, node_w_hi, node_w_lo, node_b, h_f32, h_hi, h_lo, 64, CHN);

    for (int l = 0; l < NLAYER; ++l) {
        size_t wo = (size_t)l * CHN * CHN;
        const float* sc0 = bn_scale + (l * 3 + 0) * CHN;
        const float* sh0 = bn_shift + (l * 3 + 0) * CHN;
        const float* sc1 = bn_scale + (l * 3 + 1) * CHN;
        const float* sh1 = bn_shift + (l * 3 + 1) * CHN;
        const float* sc2 = bn_scale + (l * 3 + 2) * CHN;
        const float* sh2 = bn_shift + (l * 3 + 2) * CHN;

        // agg (4096 blocks) ∥ qkv (3072 blocks)
        k_aggqkv<<<dim3(NODES / 4 + 3072), dim3(256), 0, stream>>>(
            h_hi, h_f32, offsets, csr_sa, edge_w, edge_b, zao_hi, zao_lo,
            h_lo, aiw_hi + wo * 3, aiw_lo + wo * 3, attn_in_b + l * 3 * CHN,
            q_hi, q_lo, kk_hi, kk_lo, vt_hi);
        // gine (512 blocks) ∥ attn (512 blocks)
        k_gineattn<<<dim3(NODES / 32 + 512), dim3(256), 0, stream>>>(
            zao_hi, zao_lo, gw1_hi + wo, gw1_lo + wo, gine_b1 + l * CHN,
            gw2_hi + wo, gw2_lo + wo, gine_b2 + l * CHN, h_f32, sc0, sh0, h1_f32,
            q_hi, q_lo, kk_hi, kk_lo, vt_hi, zao_hi, zao_lo);
        // out-proj + FFN
        k_outffn<<<dim3(NODES / 32), dim3(256), 0, stream>>>(
            zao_hi, zao_lo, aow_hi + wo, aow_lo + wo, attn_out_b + l * CHN,
            h_f32, sc1, sh1, h1_f32,
            mw1_hi + wo * 2, mw1_lo + wo * 2, mlp_b1 + l * 2 * CHN,
            mw2_hi + wo * 2, mw2_lo + wo * 2, mlp_b2 + l * CHN, sc2, sh2,
            h_f32, h_hi, h_lo);
    }

    k_zero_u32<<<dim3(NG * CHN / 256), dim3(256), 0, stream>>>((u32*)pool, NG * CHN);
    k_pool<<<dim3(NG, 8), dim3(128), 0, stream>>>(h_f32, pool);
    k_head<<<dim3(1), dim3(256), 0, stream>>>(pool, head_w1, head_b1, head_w2,
                                              head_b2, head_w3, head_b3,
                                              (float*)d_out);
}